// Round 3
// baseline (4455.904 us; speedup 1.0000x reference)
//
#include <hip/hip_runtime.h>
#include <cstdint>
#include <cstddef>

static constexpr int kNS = 100000;
static constexpr int kNC = 512;
static constexpr int kES = 3200000;
static constexpr int kEC = 16384;

static constexpr int kNB = (kNS + 63) / 64;   // 1563 coarse buckets (64 nodes each)
static constexpr int kNB8 = kNB * 8;          // sub-bucketed counters
static constexpr int kEBLK = (kES + 4095) / 4096;  // 782 edge-chunk blocks

typedef __attribute__((ext_vector_type(8))) short short8;
typedef __attribute__((ext_vector_type(4))) float f32x4;

__device__ __forceinline__ unsigned short f2bf(float f) {
  union { float f; unsigned u; } v; v.f = f;
  unsigned u = v.u;
  unsigned r = (u + 0x7fffu + ((u >> 16) & 1u)) >> 16;
  return (unsigned short)r;
}
__device__ __forceinline__ float bflo(unsigned v) { return __uint_as_float(v << 16); }
__device__ __forceinline__ float bfhi(unsigned v) { return __uint_as_float(v & 0xffff0000u); }
__device__ __forceinline__ float bf2f(unsigned short s) { return __uint_as_float(((unsigned)s) << 16); }

// ---------------- sample graph: bucketed edge grouping ----------------
// Pass A: per-node degree + per-(bucket, blockIdx&7) counts via LDS histogram.
__global__ __launch_bounds__(256) void k_passA(const int* __restrict__ col, int E,
                                               int* __restrict__ deg, int* __restrict__ counts) {
  __shared__ int hist[kNB];
  int t = threadIdx.x, bid = blockIdx.x;
  for (int j = t; j < kNB; j += 256) hist[j] = 0;
  __syncthreads();
  int base = bid * 4096;
  for (int i = 0; i < 16; i++) {
    int e = base + i * 256 + t;
    if (e < E) {
      int c = col[e];
      atomicAdd(&deg[c], 1);
      atomicAdd(&hist[c >> 6], 1);
    }
  }
  __syncthreads();
  int sub = bid & 7;
  for (int j = t; j < kNB; j += 256) {
    int v = hist[j];
    if (v) atomicAdd(&counts[j * 8 + sub], v);
  }
}

// exclusive scan of n flat counters -> starts[n+1], cursor copy
__global__ void k_scan_flat(const int* __restrict__ cnt, int n, int* __restrict__ starts,
                            int* __restrict__ cursor) {
  __shared__ int s[256];
  int t = threadIdx.x;
  int run = 0;
  for (int base = 0; base < n; base += 256) {
    int i = base + t;
    int v = (i < n) ? cnt[i] : 0;
    s[t] = v;
    __syncthreads();
    for (int o = 1; o < 256; o <<= 1) {
      int x = (t >= o) ? s[t - o] : 0;
      __syncthreads();
      s[t] += x;
      __syncthreads();
    }
    if (i < n) {
      int ex = run + s[t] - v;
      starts[i] = ex;
      cursor[i] = ex;
    }
    int tot = s[255];
    __syncthreads();
    run += tot;
  }
  if (t == 0) starts[n] = run;
}

// Pass B: append packed (row<<6 | col&63) into bucket segments.
__global__ __launch_bounds__(256) void k_passB(const int* __restrict__ row, const int* __restrict__ col,
                                               int E, int* __restrict__ cursor, unsigned* __restrict__ edg) {
  int t = threadIdx.x, bid = blockIdx.x;
  int sub = bid & 7;
  int base = bid * 4096;
  for (int i = 0; i < 16; i++) {
    int e = base + i * 256 + t;
    if (e < E) {
      int c = col[e], r = row[e];
      int pos = atomicAdd(&cursor[(c >> 6) * 8 + sub], 1);
      edg[pos] = ((unsigned)r << 6) | (unsigned)(c & 63);
    }
  }
}

// LDS-accumulator aggregation: one block per 64-node bucket.
template <int F>
__global__ __launch_bounds__(256) void k_agg_lds(const unsigned short* __restrict__ hs,
                                                 const unsigned* __restrict__ edg,
                                                 const int* __restrict__ starts, const float* __restrict__ dis,
                                                 const float* __restrict__ bias, unsigned short* __restrict__ out,
                                                 int N) {
  __shared__ float acc[64 * F];
  int b = blockIdx.x, t = threadIdx.x;
  int g0 = b * 64;
  for (int idx = t; idx < 64 * F; idx += 256) {
    int c = idx / F, f = idx & (F - 1);
    int g = g0 + c;
    acc[idx] = (g < N) ? bf2f(hs[(size_t)g * F + f]) : 0.f;  // self loop
  }
  __syncthreads();
  int s0 = starts[b * 8], s1 = starts[b * 8 + 8];
  int lane = t & 63, w = t >> 6;
  for (int i = s0 + w; i < s1; i += 4) {
    unsigned ew = edg[i];
    int r = (int)(ew >> 6), lc = (int)(ew & 63u);
    const unsigned short* hp = hs + (size_t)r * F;
    if (F == 128) {
      float v0 = bf2f(hp[lane]);
      float v1 = bf2f(hp[64 + lane]);
      atomicAdd(&acc[lc * 128 + lane], v0);
      atomicAdd(&acc[lc * 128 + 64 + lane], v1);
    } else {
      atomicAdd(&acc[lc * 64 + lane], bf2f(hp[lane]));
    }
  }
  __syncthreads();
  for (int idx = t; idx < 64 * (F / 2); idx += 256) {
    int c = idx / (F / 2), h = idx % (F / 2);
    int f2 = h * 2;
    int g = g0 + c;
    if (g < N) {
      float d = dis[g];
      float o0 = fmaxf(fmaf(d, acc[c * F + f2], bias[f2]), 0.f);
      float o1 = fmaxf(fmaf(d, acc[c * F + f2 + 1], bias[f2 + 1]), 0.f);
      *(unsigned*)(out + (size_t)g * F + f2) = (unsigned)f2bf(o0) | ((unsigned)f2bf(o1) << 16);
    }
  }
}

// ---------------- cluster graph: small CSR path (unchanged) ----------------
__global__ void k_hist(const int* __restrict__ col, int E, int* __restrict__ cnt) {
  int i = blockIdx.x * blockDim.x + threadIdx.x;
  if (i < E) atomicAdd(&cnt[col[i]], 1);
}

__global__ void k_dis(const int* __restrict__ cnt, int N, float* __restrict__ dis) {
  int i = blockIdx.x * blockDim.x + threadIdx.x;
  if (i < N) dis[i] = rsqrtf((float)(cnt[i] + 1));
}

__global__ void k_scan1(const int* __restrict__ cnt, int N, int* __restrict__ starts, int* __restrict__ bsum) {
  __shared__ int s[256];
  int t = threadIdx.x;
  int i = blockIdx.x * 256 + t;
  int v = (i < N) ? cnt[i] : 0;
  s[t] = v;
  __syncthreads();
  for (int o = 1; o < 256; o <<= 1) {
    int x = (t >= o) ? s[t - o] : 0;
    __syncthreads();
    s[t] += x;
    __syncthreads();
  }
  if (i < N) starts[i] = s[t] - v;
  if (t == 255) bsum[blockIdx.x] = s[255];
}

__global__ void k_scan2(int* __restrict__ bsum, int nb) {
  __shared__ int s[256];
  int t = threadIdx.x;
  int run = 0;
  for (int base = 0; base < nb; base += 256) {
    int i = base + t;
    int v = (i < nb) ? bsum[i] : 0;
    s[t] = v;
    __syncthreads();
    for (int o = 1; o < 256; o <<= 1) {
      int x = (t >= o) ? s[t - o] : 0;
      __syncthreads();
      s[t] += x;
      __syncthreads();
    }
    if (i < nb) bsum[i] = run + s[t] - v;
    int tot = s[255];
    __syncthreads();
    run += tot;
  }
}

__global__ void k_scan3(int* __restrict__ starts, int* __restrict__ cursor, const int* __restrict__ bsum, int N) {
  int i = blockIdx.x * 256 + threadIdx.x;
  if (i < N) {
    int v = starts[i] + bsum[blockIdx.x];
    starts[i] = v;
    cursor[i] = v;
  }
}

__global__ void k_scatter(const int* __restrict__ row, const int* __restrict__ col, int E,
                          int* __restrict__ cursor, int* __restrict__ srow) {
  int i = blockIdx.x * blockDim.x + threadIdx.x;
  if (i < E) {
    int pos = atomicAdd(&cursor[col[i]], 1);
    srow[pos] = row[i];
  }
}

template <int F>
__global__ __launch_bounds__(256) void k_agg_bf(const unsigned short* __restrict__ hs,
                                                const int* __restrict__ starts, const int* __restrict__ cnt,
                                                const int* __restrict__ srow, const float* __restrict__ dis,
                                                const float* __restrict__ b, unsigned short* __restrict__ out, int N) {
  constexpr int LPN = F / 2;
  int t = threadIdx.x;
  int c = blockIdx.x * (256 / LPN) + t / LPN;
  if (c >= N) return;
  int fi = (t % LPN) * 2;
  unsigned v = *(const unsigned*)(hs + (size_t)c * F + fi);
  float ax = bflo(v), ay = bfhi(v);
  int s0 = starts[c], n = cnt[c];
  const int* sp = srow + s0;
  for (int e = 0; e < n; e++) {
    unsigned vv = *(const unsigned*)(hs + (size_t)sp[e] * F + fi);
    ax += bflo(vv);
    ay += bfhi(vv);
  }
  float d = dis[c];
  float ox = fmaxf(fmaf(d, ax, b[fi]), 0.f);
  float oy = fmaxf(fmaf(d, ay, b[fi + 1]), 0.f);
  *(unsigned*)(out + (size_t)c * F + fi) = (unsigned)f2bf(ox) | ((unsigned)f2bf(oy) << 16);
}

// ---------------- layer-1 linear: hs[N,64](bf16) = (x[N,7] @ W[7,64]) * dis[row] ----------------
__global__ __launch_bounds__(256) void k_lin7(const float* __restrict__ x, const float* __restrict__ W,
                                              const float* __restrict__ dis, unsigned short* __restrict__ hs, int N) {
  __shared__ float Ws[7 * 64];
  int t = threadIdx.x;
  for (int j = t; j < 7 * 64; j += 256) Ws[j] = W[j];
  __syncthreads();
  int idx = blockIdx.x * 256 + t;
  if (idx < N * 32) {
    int r = idx >> 5, c2 = (idx & 31) * 2;
    const float* xr = x + (size_t)r * 7;
    float a0 = 0.f, a1 = 0.f;
#pragma unroll
    for (int k = 0; k < 7; k++) {
      float xv = xr[k];
      a0 = fmaf(xv, Ws[k * 64 + c2], a0);
      a1 = fmaf(xv, Ws[k * 64 + c2 + 1], a1);
    }
    float d = dis[r];
    unsigned pk = (unsigned)f2bf(a0 * d) | ((unsigned)f2bf(a1 * d) << 16);
    *(unsigned*)(hs + (size_t)r * 64 + c2) = pk;
  }
}

// ---------------- layer-2 linear: hs2[N,128](bf16) = (xin[N,64](bf16) @ W[64,128]) * dis[row] ----------------
__global__ __launch_bounds__(256) void k_lin64x128(const unsigned short* __restrict__ xin, const float* __restrict__ W,
                                                   const float* __restrict__ dis, unsigned short* __restrict__ hs, int N) {
  __shared__ float Ws[64 * 128];
  __shared__ float xs[8][64];
  int t = threadIdx.x;
  for (int j = t; j < 64 * 128; j += 256) Ws[j] = W[j];
  int r0 = blockIdx.x * 8;
  for (int j = t; j < 8 * 64; j += 256) {
    int r = j >> 6, k = j & 63;
    int gr = r0 + r;
    xs[r][k] = (gr < N) ? bf2f(xin[(size_t)gr * 64 + k]) : 0.f;
  }
  __syncthreads();
  int c = t & 127;
  int rb = (t >> 7) * 4;
  float acc[4] = {0.f, 0.f, 0.f, 0.f};
  for (int k = 0; k < 64; k++) {
    float w = Ws[k * 128 + c];
#pragma unroll
    for (int rr = 0; rr < 4; rr++) acc[rr] = fmaf(xs[rb + rr][k], w, acc[rr]);
  }
#pragma unroll
  for (int rr = 0; rr < 4; rr++) {
    int gr = r0 + rb + rr;
    if (gr < N) hs[(size_t)gr * 128 + c] = f2bf(acc[rr] * dis[gr]);
  }
}

// ---------------- B-operand fragment packers ----------------
__global__ void k_pack_b_bf16src(const unsigned short* __restrict__ src, short* __restrict__ dst, int K) {
  int e = blockIdx.x * 256 + threadIdx.x;
  if (e >= K * 128) return;
  int k = e >> 7, n = e & 127;
  int frag = (k >> 5) * 8 + (n >> 4);
  int l = (n & 15) | (((k >> 3) & 3) << 4);
  int j = k & 7;
  dst[(size_t)frag * 512 + l * 8 + j] = (short)src[e];
}
__global__ void k_pack_b_f32src(const float* __restrict__ src, short* __restrict__ dst, int K) {
  int e = blockIdx.x * 256 + threadIdx.x;
  if (e >= K * 128) return;
  int k = e >> 7, n = e & 127;
  int frag = (k >> 5) * 8 + (n >> 4);
  int l = (n & 15) | (((k >> 3) & 3) << 4);
  int j = k & 7;
  dst[(size_t)frag * 512 + l * 8 + j] = (short)f2bf(src[e]);
}

__device__ __forceinline__ short8 zero8() {
  short8 z;
#pragma unroll
  for (int j = 0; j < 8; j++) z[j] = 0;
  return z;
}

__device__ __forceinline__ short8 load_a_f32(const float* p, bool ok) {
  short8 r;
  if (ok) {
    float4 v0 = *(const float4*)p;
    float4 v1 = *(const float4*)(p + 4);
    r[0] = (short)f2bf(v0.x); r[1] = (short)f2bf(v0.y); r[2] = (short)f2bf(v0.z); r[3] = (short)f2bf(v0.w);
    r[4] = (short)f2bf(v1.x); r[5] = (short)f2bf(v1.y); r[6] = (short)f2bf(v1.z); r[7] = (short)f2bf(v1.w);
  } else {
    r = zero8();
  }
  return r;
}

// ---------------- GEMM1 (MFMA): xcdec[M,128](bf16) = Q[M,512](fp32) @ Bq ----------------
__global__ __launch_bounds__(256) void k_gemm_q_mfma(const float* __restrict__ Q, const short* __restrict__ Bp,
                                                     unsigned short* __restrict__ outb, int M) {
  int t = threadIdx.x;
  int lane = t & 63;
  int wid = t >> 6;
  int m0 = blockIdx.x * 128 + wid * 32;
  int mrow = lane & 15;
  int kg = lane >> 4;
  f32x4 acc[2][8];
#pragma unroll
  for (int mi = 0; mi < 2; mi++)
#pragma unroll
    for (int nf = 0; nf < 8; nf++) acc[mi][nf] = (f32x4){0.f, 0.f, 0.f, 0.f};
  int r0 = m0 + mrow, r1 = m0 + 16 + mrow;
  bool ok0 = r0 < M, ok1 = r1 < M;
  const float* a0p = Q + (size_t)r0 * 512 + kg * 8;
  const float* a1p = Q + (size_t)r1 * 512 + kg * 8;
  const short* bl = Bp + lane * 8;
  for (int ks = 0; ks < 16; ks++) {
    short8 a0 = load_a_f32(a0p + ks * 32, ok0);
    short8 a1 = load_a_f32(a1p + ks * 32, ok1);
    const short* bb = bl + (ks << 12);
#pragma unroll
    for (int nf = 0; nf < 8; nf++) {
      short8 b = *(const short8*)(bb + (nf << 9));
      acc[0][nf] = __builtin_amdgcn_mfma_f32_16x16x32_bf16(a0, b, acc[0][nf], 0, 0, 0);
      acc[1][nf] = __builtin_amdgcn_mfma_f32_16x16x32_bf16(a1, b, acc[1][nf], 0, 0, 0);
    }
  }
  int col = lane & 15;
  int g = lane >> 4;
#pragma unroll
  for (int mi = 0; mi < 2; mi++)
#pragma unroll
    for (int nf = 0; nf < 8; nf++)
#pragma unroll
      for (int r = 0; r < 4; r++) {
        int row = m0 + mi * 16 + g * 4 + r;
        if (row < M) outb[(size_t)row * 128 + nf * 16 + col] = f2bf(acc[mi][nf][r]);
      }
}

// ---------------- GEMM2 (MFMA) + gate epilogue ----------------
__global__ __launch_bounds__(256) void k_gemm_fuse_mfma(const unsigned short* __restrict__ Xs,
                                                        const unsigned short* __restrict__ Xc,
                                                        const short* __restrict__ A1p, const float* __restrict__ ab1,
                                                        const float* __restrict__ A2, const float* __restrict__ ab2,
                                                        float* __restrict__ fused, int M) {
  int t = threadIdx.x;
  int lane = t & 63;
  int wid = t >> 6;
  int m0 = blockIdx.x * 128 + wid * 32;
  int mrow = lane & 15;
  int kg = lane >> 4;
  f32x4 acc[2][8];
#pragma unroll
  for (int mi = 0; mi < 2; mi++)
#pragma unroll
    for (int nf = 0; nf < 8; nf++) acc[mi][nf] = (f32x4){0.f, 0.f, 0.f, 0.f};
  int r0 = m0 + mrow, r1 = m0 + 16 + mrow;
  bool ok0 = r0 < M, ok1 = r1 < M;
  const short* bl = A1p + lane * 8;
  for (int ks = 0; ks < 8; ks++) {
    const unsigned short* src = (ks < 4) ? Xs : Xc;
    int kb = (ks & 3) * 32 + kg * 8;
    short8 a0 = ok0 ? *(const short8*)(src + (size_t)r0 * 128 + kb) : zero8();
    short8 a1 = ok1 ? *(const short8*)(src + (size_t)r1 * 128 + kb) : zero8();
    const short* bb = bl + (ks << 12);
#pragma unroll
    for (int nf = 0; nf < 8; nf++) {
      short8 b = *(const short8*)(bb + (nf << 9));
      acc[0][nf] = __builtin_amdgcn_mfma_f32_16x16x32_bf16(a0, b, acc[0][nf], 0, 0, 0);
      acc[1][nf] = __builtin_amdgcn_mfma_f32_16x16x32_bf16(a1, b, acc[1][nf], 0, 0, 0);
    }
  }
  int col16 = lane & 15;
  int g = lane >> 4;
  float bias[8], w20[8], w21[8];
#pragma unroll
  for (int nf = 0; nf < 8; nf++) {
    int cc = nf * 16 + col16;
    bias[nf] = ab1[cc];
    w20[nf] = A2[2 * cc];
    w21[nf] = A2[2 * cc + 1];
  }
  float b20 = ab2[0], b21 = ab2[1];
#pragma unroll
  for (int mi = 0; mi < 2; mi++) {
#pragma unroll
    for (int r = 0; r < 4; r++) {
      float u0 = 0.f, u1 = 0.f;
#pragma unroll
      for (int nf = 0; nf < 8; nf++) {
        float tv = fmaxf(acc[mi][nf][r] + bias[nf], 0.f);
        u0 = fmaf(tv, w20[nf], u0);
        u1 = fmaf(tv, w21[nf], u1);
      }
#pragma unroll
      for (int off = 1; off < 16; off <<= 1) {
        u0 += __shfl_xor(u0, off);
        u1 += __shfl_xor(u1, off);
      }
      int row = m0 + mi * 16 + g * 4 + r;
      if (row < M) {
        float ua = u0 + b20, ub = u1 + b21;
        float mx = fmaxf(ua, ub);
        float e0 = __expf(ua - mx), e1 = __expf(ub - mx);
        float inv = 1.f / (e0 + e1);
        float w0 = e0 * inv, w1 = e1 * inv;
        int p = col16;
        const unsigned short* xsp = Xs + (size_t)row * 128 + p * 8;
        const unsigned short* xcp = Xc + (size_t)row * 128 + p * 8;
        float* op = fused + (size_t)row * 128 + p * 8;
        float4 o0, o1;
        unsigned sx0 = *(const unsigned*)(xsp + 0), sx1 = *(const unsigned*)(xsp + 2);
        unsigned sx2 = *(const unsigned*)(xsp + 4), sx3 = *(const unsigned*)(xsp + 6);
        unsigned cx0 = *(const unsigned*)(xcp + 0), cx1 = *(const unsigned*)(xcp + 2);
        unsigned cx2 = *(const unsigned*)(xcp + 4), cx3 = *(const unsigned*)(xcp + 6);
        o0.x = w0 * bflo(sx0) + w1 * bflo(cx0);
        o0.y = w0 * bfhi(sx0) + w1 * bfhi(cx0);
        o0.z = w0 * bflo(sx1) + w1 * bflo(cx1);
        o0.w = w0 * bfhi(sx1) + w1 * bfhi(cx1);
        o1.x = w0 * bflo(sx2) + w1 * bflo(cx2);
        o1.y = w0 * bfhi(sx2) + w1 * bfhi(cx2);
        o1.z = w0 * bflo(sx3) + w1 * bflo(cx3);
        o1.w = w0 * bfhi(sx3) + w1 * bfhi(cx3);
        *(float4*)op = o0;
        *(float4*)(op + 4) = o1;
      }
    }
  }
}

// ---------------- heads ----------------
__global__ __launch_bounds__(256) void k_final(const float* __restrict__ fused, const float* __restrict__ Wcls,
                                               const float* __restrict__ bcls, const float* __restrict__ D1,
                                               const float* __restrict__ db1, const float* __restrict__ D2,
                                               const float* __restrict__ db2, float* __restrict__ cls_out,
                                               float* __restrict__ dom_out, int M) {
  __shared__ float D1s[128 * 64];
  __shared__ float Ws[128 * 9];
  __shared__ float D2s[64 * 2];
  __shared__ float fr[16][128];
  __shared__ float hh[16][64];
  int t = threadIdx.x;
  for (int j = t; j < 128 * 64; j += 256) D1s[j] = D1[j];
  for (int j = t; j < 128 * 9; j += 256) Ws[j] = Wcls[j];
  if (t < 128) D2s[t] = D2[t];
  int r0 = blockIdx.x * 16;
  for (int j = t; j < 16 * 128; j += 256) {
    int r = j >> 7, k = j & 127;
    int gr = r0 + r;
    fr[r][k] = (gr < M) ? fused[(size_t)gr * 128 + k] : 0.f;
  }
  __syncthreads();
#pragma unroll
  for (int q = 0; q < 4; q++) {
    int j = t + q * 256;
    int r = j >> 6, h = j & 63;
    float a = db1[h];
    for (int k = 0; k < 128; k++) a = fmaf(fr[r][k], D1s[k * 64 + h], a);
    hh[r][h] = fmaxf(a, 0.f);
  }
  if (t < 144) {
    int r = t / 9, c = t % 9;
    float a = bcls[c];
    for (int k = 0; k < 128; k++) a = fmaf(fr[r][k], Ws[k * 9 + c], a);
    int gr = r0 + r;
    if (gr < M) cls_out[(size_t)gr * 9 + c] = a;
  }
  __syncthreads();
  if (t < 32) {
    int r = t >> 1, j = t & 1;
    float a = db2[j];
    for (int h = 0; h < 64; h++) a = fmaf(hh[r][h], D2s[h * 2 + j], a);
    int gr = r0 + r;
    if (gr < M) dom_out[(size_t)gr * 2 + j] = a;
  }
}

extern "C" void kernel_launch(void* const* d_in, const int* in_sizes, int n_in,
                              void* d_out, int out_size, void* d_ws, size_t ws_size,
                              hipStream_t stream) {
  const float* x_s = (const float*)d_in[0];
  const float* x_c = (const float*)d_in[1];
  const float* Q = (const float*)d_in[2];
  const int* eis = (const int*)d_in[3];
  const int* eic = (const int*)d_in[4];
  const float* W1s = (const float*)d_in[5];
  const float* b1s = (const float*)d_in[6];
  const float* W2s = (const float*)d_in[7];
  const float* b2s = (const float*)d_in[8];
  const float* W1c = (const float*)d_in[9];
  const float* b1c = (const float*)d_in[10];
  const float* W2c = (const float*)d_in[11];
  const float* b2c = (const float*)d_in[12];
  const float* A1 = (const float*)d_in[13];
  const float* ab1 = (const float*)d_in[14];
  const float* A2 = (const float*)d_in[15];
  const float* ab2 = (const float*)d_in[16];
  const float* Wcls = (const float*)d_in[17];
  const float* bcls = (const float*)d_in[18];
  const float* D1 = (const float*)d_in[19];
  const float* db1 = (const float*)d_in[20];
  const float* D2 = (const float*)d_in[21];
  const float* db2 = (const float*)d_in[22];

  float* out_cls = (float*)d_out;
  float* out_dom = out_cls + (size_t)kNS * 9;
  float* out_fus = out_dom + (size_t)kNS * 2;

  char* p = (char*)d_ws;
  auto alloc = [&](size_t bytes) -> void* {
    void* r = (void*)p;
    p += (bytes + 255) & ~(size_t)255;
    return r;
  };
  // sample graph
  int* deg_s = (int*)alloc((size_t)kNS * 4);
  float* dis_s = (float*)alloc((size_t)kNS * 4);
  int* counts_s = (int*)alloc((size_t)kNB8 * 4);
  int* starts_s = (int*)alloc((size_t)(kNB8 + 1) * 4);
  int* cursor_s = (int*)alloc((size_t)kNB8 * 4);
  unsigned* edg_s = (unsigned*)alloc((size_t)kES * 4);
  // cluster graph
  int* deg_c = (int*)alloc((size_t)kNC * 4);
  int* cstarts_c = (int*)alloc((size_t)kNC * 4);
  int* cursor_c = (int*)alloc((size_t)kNC * 4);
  int* bsum_c = (int*)alloc(512 * 4);
  float* dis_c = (float*)alloc((size_t)kNC * 4);
  int* srow_c = (int*)alloc((size_t)kEC * 4);
  // feature buffers (bf16)
  unsigned short* hc1b = (unsigned short*)alloc((size_t)kNC * 64 * 2);
  unsigned short* xc1b = (unsigned short*)alloc((size_t)kNC * 64 * 2);
  unsigned short* hc2b = (unsigned short*)alloc((size_t)kNC * 128 * 2);
  unsigned short* xc2b = (unsigned short*)alloc((size_t)kNC * 128 * 2);
  unsigned short* hs1b = (unsigned short*)alloc((size_t)kNS * 64 * 2);
  unsigned short* xs1b = (unsigned short*)alloc((size_t)kNS * 64 * 2);
  unsigned short* hs2b = (unsigned short*)alloc((size_t)kNS * 128 * 2);
  unsigned short* xs2b = (unsigned short*)alloc((size_t)kNS * 128 * 2);
  unsigned short* xcdb = (unsigned short*)alloc((size_t)kNS * 128 * 2);
  short* Bq = (short*)alloc((size_t)512 * 128 * 2);
  short* A1p = (short*)alloc((size_t)256 * 128 * 2);
  (void)ws_size; (void)in_sizes; (void)n_in; (void)out_size;

  hipMemsetAsync(deg_s, 0, (size_t)kNS * 4, stream);
  hipMemsetAsync(counts_s, 0, (size_t)kNB8 * 4, stream);
  hipMemsetAsync(deg_c, 0, (size_t)kNC * 4, stream);

  const int nbC = (kNC + 255) / 256;

  // sample-graph bucketed grouping
  k_passA<<<kEBLK, 256, 0, stream>>>(eis + kES, kES, deg_s, counts_s);
  k_dis<<<(kNS + 255) / 256, 256, 0, stream>>>(deg_s, kNS, dis_s);
  k_scan_flat<<<1, 256, 0, stream>>>(counts_s, kNB8, starts_s, cursor_s);
  k_passB<<<kEBLK, 256, 0, stream>>>(eis, eis + kES, kES, cursor_s, edg_s);

  // cluster-graph CSR
  k_hist<<<(kEC + 255) / 256, 256, 0, stream>>>(eic + kEC, kEC, deg_c);
  k_dis<<<nbC, 256, 0, stream>>>(deg_c, kNC, dis_c);
  k_scan1<<<nbC, 256, 0, stream>>>(deg_c, kNC, cstarts_c, bsum_c);
  k_scan2<<<1, 256, 0, stream>>>(bsum_c, nbC);
  k_scan3<<<nbC, 256, 0, stream>>>(cstarts_c, cursor_c, bsum_c, kNC);
  k_scatter<<<(kEC + 255) / 256, 256, 0, stream>>>(eic, eic + kEC, kEC, cursor_c, srow_c);

  // pack A1 (independent)
  k_pack_b_f32src<<<(256 * 128 + 255) / 256, 256, 0, stream>>>(A1, A1p, 256);

  // cluster branch
  k_lin7<<<(kNC * 32 + 255) / 256, 256, 0, stream>>>(x_c, W1c, dis_c, hc1b, kNC);
  k_agg_bf<64><<<(kNC + 7) / 8, 256, 0, stream>>>(hc1b, cstarts_c, deg_c, srow_c, dis_c, b1c, xc1b, kNC);
  k_lin64x128<<<(kNC + 7) / 8, 256, 0, stream>>>(xc1b, W2c, dis_c, hc2b, kNC);
  k_agg_bf<128><<<(kNC + 3) / 4, 256, 0, stream>>>(hc2b, cstarts_c, deg_c, srow_c, dis_c, b2c, xc2b, kNC);
  k_pack_b_bf16src<<<(512 * 128 + 255) / 256, 256, 0, stream>>>(xc2b, Bq, 512);

  // sample branch
  k_lin7<<<(kNS * 32 + 255) / 256, 256, 0, stream>>>(x_s, W1s, dis_s, hs1b, kNS);
  k_agg_lds<64><<<kNB, 256, 0, stream>>>(hs1b, edg_s, starts_s, dis_s, b1s, xs1b, kNS);
  k_lin64x128<<<(kNS + 7) / 8, 256, 0, stream>>>(xs1b, W2s, dis_s, hs2b, kNS);
  k_agg_lds<128><<<kNB, 256, 0, stream>>>(hs2b, edg_s, starts_s, dis_s, b2s, xs2b, kNS);

  // decode + fusion gate + heads
  k_gemm_q_mfma<<<(kNS + 127) / 128, 256, 0, stream>>>(Q, Bq, xcdb, kNS);
  k_gemm_fuse_mfma<<<(kNS + 127) / 128, 256, 0, stream>>>(xs2b, xcdb, A1p, ab1, A2, ab2, out_fus, kNS);
  k_final<<<(kNS + 15) / 16, 256, 0, stream>>>(out_fus, Wcls, bcls, D1, db1, D2, db2, out_cls, out_dom, kNS);
}

// Round 4
// 852.883 us; speedup vs baseline: 5.2245x; 5.2245x over previous
//
#include <hip/hip_runtime.h>
#include <cstdint>
#include <cstddef>

static constexpr int kNS = 100000;
static constexpr int kNC = 512;
static constexpr int kES = 3200000;
static constexpr int kEC = 16384;

static constexpr int kNB = (kNS + 63) / 64;        // 1563 coarse buckets (64 nodes each)
static constexpr int kNB8 = kNB * 8;               // sub-bucketed counters
static constexpr int kEBLK = (kES + 4095) / 4096;  // 782 edge-chunk blocks

typedef __attribute__((ext_vector_type(8))) short short8;
typedef __attribute__((ext_vector_type(4))) float f32x4;

__device__ __forceinline__ unsigned short f2bf(float f) {
  union { float f; unsigned u; } v; v.f = f;
  unsigned u = v.u;
  unsigned r = (u + 0x7fffu + ((u >> 16) & 1u)) >> 16;
  return (unsigned short)r;
}
__device__ __forceinline__ float bflo(unsigned v) { return __uint_as_float(v << 16); }
__device__ __forceinline__ float bfhi(unsigned v) { return __uint_as_float(v & 0xffff0000u); }
__device__ __forceinline__ float bf2f(unsigned short s) { return __uint_as_float(((unsigned)s) << 16); }

// ---------------- sample graph: bucket histogram (no per-node atomics) ----------------
__global__ __launch_bounds__(256) void k_passA(const int* __restrict__ col, int E,
                                               int* __restrict__ counts) {
  __shared__ int hist[kNB];
  int t = threadIdx.x, bid = blockIdx.x;
  for (int j = t; j < kNB; j += 256) hist[j] = 0;
  __syncthreads();
  int base = bid * 4096;
  for (int i = 0; i < 16; i++) {
    int e = base + i * 256 + t;
    if (e < E) atomicAdd(&hist[col[e] >> 6], 1);
  }
  __syncthreads();
  int sub = bid & 7;
  for (int j = t; j < kNB; j += 256) {
    int v = hist[j];
    if (v) atomicAdd(&counts[j * 8 + sub], v);
  }
}

// exclusive scan of n flat counters -> starts[n+1], cursor copy
__global__ void k_scan_flat(const int* __restrict__ cnt, int n, int* __restrict__ starts,
                            int* __restrict__ cursor) {
  __shared__ int s[256];
  int t = threadIdx.x;
  int run = 0;
  for (int base = 0; base < n; base += 256) {
    int i = base + t;
    int v = (i < n) ? cnt[i] : 0;
    s[t] = v;
    __syncthreads();
    for (int o = 1; o < 256; o <<= 1) {
      int x = (t >= o) ? s[t - o] : 0;
      __syncthreads();
      s[t] += x;
      __syncthreads();
    }
    if (i < n) {
      int ex = run + s[t] - v;
      starts[i] = ex;
      cursor[i] = ex;
    }
    int tot = s[255];
    __syncthreads();
    run += tot;
  }
  if (t == 0) starts[n] = run;
}

// Pass B: append packed (row<<6 | col&63) into (bucket, sub) segments — hot ~1KB cursor windows.
__global__ __launch_bounds__(256) void k_passB(const int* __restrict__ row, const int* __restrict__ col,
                                               int E, int* __restrict__ cursor, unsigned* __restrict__ edg) {
  int t = threadIdx.x, bid = blockIdx.x;
  int sub = bid & 7;
  int base = bid * 4096;
  for (int i = 0; i < 16; i++) {
    int e = base + i * 256 + t;
    if (e < E) {
      int c = col[e], r = row[e];
      int pos = atomicAdd(&cursor[(c >> 6) * 8 + sub], 1);
      edg[pos] = ((unsigned)r << 6) | (unsigned)(c & 63);
    }
  }
}

// Pass C: per-bucket re-sort into exact per-node CSR; also emits per-node degree + starts.
// All reads/writes within the bucket's contiguous ~8KB segment (L2-hot).
__global__ __launch_bounds__(256) void k_passC(const unsigned* __restrict__ edg,
                                               const int* __restrict__ bstarts,
                                               int* __restrict__ deg, int* __restrict__ nstarts,
                                               int* __restrict__ srow, int N) {
  __shared__ int ldeg[64];
  __shared__ int lcur[64];
  int b = blockIdx.x, t = threadIdx.x;
  int s0 = bstarts[b * 8], s1 = bstarts[b * 8 + 8];
  if (t < 64) ldeg[t] = 0;
  __syncthreads();
  for (int i = s0 + t; i < s1; i += 256) atomicAdd(&ldeg[edg[i] & 63u], 1);
  __syncthreads();
  if (t < 64) {
    int own = ldeg[t];
    int incl = own;
#pragma unroll
    for (int off = 1; off < 64; off <<= 1) {
      int o = __shfl_up(incl, off);
      if (t >= off) incl += o;
    }
    int st = s0 + incl - own;
    lcur[t] = st;
    int g = b * 64 + t;
    if (g < N) {
      deg[g] = own;
      nstarts[g] = st;
    }
  }
  __syncthreads();
  for (int i = s0 + t; i < s1; i += 256) {
    unsigned ew = edg[i];
    int pos = atomicAdd(&lcur[ew & 63u], 1);
    srow[pos] = (int)(ew >> 6);
  }
}

// ---------------- cluster graph: small CSR path ----------------
__global__ void k_hist(const int* __restrict__ col, int E, int* __restrict__ cnt) {
  int i = blockIdx.x * blockDim.x + threadIdx.x;
  if (i < E) atomicAdd(&cnt[col[i]], 1);
}

__global__ void k_dis(const int* __restrict__ cnt, int N, float* __restrict__ dis) {
  int i = blockIdx.x * blockDim.x + threadIdx.x;
  if (i < N) dis[i] = rsqrtf((float)(cnt[i] + 1));
}

__global__ void k_scan1(const int* __restrict__ cnt, int N, int* __restrict__ starts, int* __restrict__ bsum) {
  __shared__ int s[256];
  int t = threadIdx.x;
  int i = blockIdx.x * 256 + t;
  int v = (i < N) ? cnt[i] : 0;
  s[t] = v;
  __syncthreads();
  for (int o = 1; o < 256; o <<= 1) {
    int x = (t >= o) ? s[t - o] : 0;
    __syncthreads();
    s[t] += x;
    __syncthreads();
  }
  if (i < N) starts[i] = s[t] - v;
  if (t == 255) bsum[blockIdx.x] = s[255];
}

__global__ void k_scan2(int* __restrict__ bsum, int nb) {
  __shared__ int s[256];
  int t = threadIdx.x;
  int run = 0;
  for (int base = 0; base < nb; base += 256) {
    int i = base + t;
    int v = (i < nb) ? bsum[i] : 0;
    s[t] = v;
    __syncthreads();
    for (int o = 1; o < 256; o <<= 1) {
      int x = (t >= o) ? s[t - o] : 0;
      __syncthreads();
      s[t] += x;
      __syncthreads();
    }
    if (i < nb) bsum[i] = run + s[t] - v;
    int tot = s[255];
    __syncthreads();
    run += tot;
  }
}

__global__ void k_scan3(int* __restrict__ starts, int* __restrict__ cursor, const int* __restrict__ bsum, int N) {
  int i = blockIdx.x * 256 + threadIdx.x;
  if (i < N) {
    int v = starts[i] + bsum[blockIdx.x];
    starts[i] = v;
    cursor[i] = v;
  }
}

__global__ void k_scatter(const int* __restrict__ row, const int* __restrict__ col, int E,
                          int* __restrict__ cursor, int* __restrict__ srow) {
  int i = blockIdx.x * blockDim.x + threadIdx.x;
  if (i < E) {
    int pos = atomicAdd(&cursor[col[i]], 1);
    srow[pos] = row[i];
  }
}

// ---------------- aggregation (bf16 in/out): out[c] = relu(dis[c]*(hs[c]+sum hs[r]) + b) ----------------
template <int F>
__global__ __launch_bounds__(256) void k_agg_bf(const unsigned short* __restrict__ hs,
                                                const int* __restrict__ starts, const int* __restrict__ cnt,
                                                const int* __restrict__ srow, const float* __restrict__ dis,
                                                const float* __restrict__ b, unsigned short* __restrict__ out, int N) {
  constexpr int LPN = F / 2;
  int t = threadIdx.x;
  int c = blockIdx.x * (256 / LPN) + t / LPN;
  if (c >= N) return;
  int fi = (t % LPN) * 2;
  unsigned v = *(const unsigned*)(hs + (size_t)c * F + fi);
  float ax = bflo(v), ay = bfhi(v);
  int s0 = starts[c], n = cnt[c];
  const int* sp = srow + s0;
  int e = 0;
  for (; e + 4 <= n; e += 4) {
    int r0 = sp[e], r1 = sp[e + 1], r2 = sp[e + 2], r3 = sp[e + 3];
    unsigned v0 = *(const unsigned*)(hs + (size_t)r0 * F + fi);
    unsigned v1 = *(const unsigned*)(hs + (size_t)r1 * F + fi);
    unsigned v2 = *(const unsigned*)(hs + (size_t)r2 * F + fi);
    unsigned v3 = *(const unsigned*)(hs + (size_t)r3 * F + fi);
    ax += bflo(v0) + bflo(v1) + bflo(v2) + bflo(v3);
    ay += bfhi(v0) + bfhi(v1) + bfhi(v2) + bfhi(v3);
  }
  for (; e < n; e++) {
    unsigned vv = *(const unsigned*)(hs + (size_t)sp[e] * F + fi);
    ax += bflo(vv);
    ay += bfhi(vv);
  }
  float d = dis[c];
  float ox = fmaxf(fmaf(d, ax, b[fi]), 0.f);
  float oy = fmaxf(fmaf(d, ay, b[fi + 1]), 0.f);
  *(unsigned*)(out + (size_t)c * F + fi) = (unsigned)f2bf(ox) | ((unsigned)f2bf(oy) << 16);
}

// ---------------- layer-1 linear: hs[N,64](bf16) = (x[N,7] @ W[7,64]) * dis[row] ----------------
__global__ __launch_bounds__(256) void k_lin7(const float* __restrict__ x, const float* __restrict__ W,
                                              const float* __restrict__ dis, unsigned short* __restrict__ hs, int N) {
  __shared__ float Ws[7 * 64];
  int t = threadIdx.x;
  for (int j = t; j < 7 * 64; j += 256) Ws[j] = W[j];
  __syncthreads();
  int idx = blockIdx.x * 256 + t;
  if (idx < N * 32) {
    int r = idx >> 5, c2 = (idx & 31) * 2;
    const float* xr = x + (size_t)r * 7;
    float a0 = 0.f, a1 = 0.f;
#pragma unroll
    for (int k = 0; k < 7; k++) {
      float xv = xr[k];
      a0 = fmaf(xv, Ws[k * 64 + c2], a0);
      a1 = fmaf(xv, Ws[k * 64 + c2 + 1], a1);
    }
    float d = dis[r];
    unsigned pk = (unsigned)f2bf(a0 * d) | ((unsigned)f2bf(a1 * d) << 16);
    *(unsigned*)(hs + (size_t)r * 64 + c2) = pk;
  }
}

// ---------------- layer-2 linear: 32 rows/block: hs2[N,128] = (xin[N,64] @ W[64,128]) * dis ----------------
__global__ __launch_bounds__(256) void k_lin64x128(const unsigned short* __restrict__ xin, const float* __restrict__ W,
                                                   const float* __restrict__ dis, unsigned short* __restrict__ hs, int N) {
  __shared__ float Ws[64 * 128];
  __shared__ float xs[32][64];
  int t = threadIdx.x;
  for (int j = t; j < 64 * 128; j += 256) Ws[j] = W[j];
  int r0 = blockIdx.x * 32;
  for (int j = t; j < 32 * 64; j += 256) {
    int r = j >> 6, k = j & 63;
    int gr = r0 + r;
    xs[r][k] = (gr < N) ? bf2f(xin[(size_t)gr * 64 + k]) : 0.f;
  }
  __syncthreads();
  int c = t & 63;            // cols c and c+64
  int rb = (t >> 6) * 8;     // 4 groups x 8 rows
  float a0[8], a1[8];
#pragma unroll
  for (int rr = 0; rr < 8; rr++) { a0[rr] = 0.f; a1[rr] = 0.f; }
  for (int k = 0; k < 64; k++) {
    float w0 = Ws[k * 128 + c];
    float w1 = Ws[k * 128 + c + 64];
#pragma unroll
    for (int rr = 0; rr < 8; rr++) {
      float xv = xs[rb + rr][k];
      a0[rr] = fmaf(xv, w0, a0[rr]);
      a1[rr] = fmaf(xv, w1, a1[rr]);
    }
  }
#pragma unroll
  for (int rr = 0; rr < 8; rr++) {
    int gr = r0 + rb + rr;
    if (gr < N) {
      float d = dis[gr];
      hs[(size_t)gr * 128 + c] = f2bf(a0[rr] * d);
      hs[(size_t)gr * 128 + c + 64] = f2bf(a1[rr] * d);
    }
  }
}

// ---------------- B-operand fragment packers ----------------
__global__ void k_pack_b_bf16src(const unsigned short* __restrict__ src, short* __restrict__ dst, int K) {
  int e = blockIdx.x * 256 + threadIdx.x;
  if (e >= K * 128) return;
  int k = e >> 7, n = e & 127;
  int frag = (k >> 5) * 8 + (n >> 4);
  int l = (n & 15) | (((k >> 3) & 3) << 4);
  int j = k & 7;
  dst[(size_t)frag * 512 + l * 8 + j] = (short)src[e];
}
__global__ void k_pack_b_f32src(const float* __restrict__ src, short* __restrict__ dst, int K) {
  int e = blockIdx.x * 256 + threadIdx.x;
  if (e >= K * 128) return;
  int k = e >> 7, n = e & 127;
  int frag = (k >> 5) * 8 + (n >> 4);
  int l = (n & 15) | (((k >> 3) & 3) << 4);
  int j = k & 7;
  dst[(size_t)frag * 512 + l * 8 + j] = (short)f2bf(src[e]);
}

__device__ __forceinline__ short8 zero8() {
  short8 z;
#pragma unroll
  for (int j = 0; j < 8; j++) z[j] = 0;
  return z;
}

__device__ __forceinline__ short8 load_a_f32(const float* p, bool ok) {
  short8 r;
  if (ok) {
    float4 v0 = *(const float4*)p;
    float4 v1 = *(const float4*)(p + 4);
    r[0] = (short)f2bf(v0.x); r[1] = (short)f2bf(v0.y); r[2] = (short)f2bf(v0.z); r[3] = (short)f2bf(v0.w);
    r[4] = (short)f2bf(v1.x); r[5] = (short)f2bf(v1.y); r[6] = (short)f2bf(v1.z); r[7] = (short)f2bf(v1.w);
  } else {
    r = zero8();
  }
  return r;
}

// ---------------- GEMM1 (MFMA): xcdec[M,128](bf16) = Q[M,512](fp32) @ Bq ----------------
__global__ __launch_bounds__(256) void k_gemm_q_mfma(const float* __restrict__ Q, const short* __restrict__ Bp,
                                                     unsigned short* __restrict__ outb, int M) {
  int t = threadIdx.x;
  int lane = t & 63;
  int wid = t >> 6;
  int m0 = blockIdx.x * 128 + wid * 32;
  int mrow = lane & 15;
  int kg = lane >> 4;
  f32x4 acc[2][8];
#pragma unroll
  for (int mi = 0; mi < 2; mi++)
#pragma unroll
    for (int nf = 0; nf < 8; nf++) acc[mi][nf] = (f32x4){0.f, 0.f, 0.f, 0.f};
  int r0 = m0 + mrow, r1 = m0 + 16 + mrow;
  bool ok0 = r0 < M, ok1 = r1 < M;
  const float* a0p = Q + (size_t)r0 * 512 + kg * 8;
  const float* a1p = Q + (size_t)r1 * 512 + kg * 8;
  const short* bl = Bp + lane * 8;
  for (int ks = 0; ks < 16; ks++) {
    short8 a0 = load_a_f32(a0p + ks * 32, ok0);
    short8 a1 = load_a_f32(a1p + ks * 32, ok1);
    const short* bb = bl + (ks << 12);
#pragma unroll
    for (int nf = 0; nf < 8; nf++) {
      short8 b = *(const short8*)(bb + (nf << 9));
      acc[0][nf] = __builtin_amdgcn_mfma_f32_16x16x32_bf16(a0, b, acc[0][nf], 0, 0, 0);
      acc[1][nf] = __builtin_amdgcn_mfma_f32_16x16x32_bf16(a1, b, acc[1][nf], 0, 0, 0);
    }
  }
  int col = lane & 15;
  int g = lane >> 4;
#pragma unroll
  for (int mi = 0; mi < 2; mi++)
#pragma unroll
    for (int nf = 0; nf < 8; nf++)
#pragma unroll
      for (int r = 0; r < 4; r++) {
        int row = m0 + mi * 16 + g * 4 + r;
        if (row < M) outb[(size_t)row * 128 + nf * 16 + col] = f2bf(acc[mi][nf][r]);
      }
}

// ---------------- GEMM2 (MFMA) + gate epilogue ----------------
__global__ __launch_bounds__(256) void k_gemm_fuse_mfma(const unsigned short* __restrict__ Xs,
                                                        const unsigned short* __restrict__ Xc,
                                                        const short* __restrict__ A1p, const float* __restrict__ ab1,
                                                        const float* __restrict__ A2, const float* __restrict__ ab2,
                                                        float* __restrict__ fused, int M) {
  int t = threadIdx.x;
  int lane = t & 63;
  int wid = t >> 6;
  int m0 = blockIdx.x * 128 + wid * 32;
  int mrow = lane & 15;
  int kg = lane >> 4;
  f32x4 acc[2][8];
#pragma unroll
  for (int mi = 0; mi < 2; mi++)
#pragma unroll
    for (int nf = 0; nf < 8; nf++) acc[mi][nf] = (f32x4){0.f, 0.f, 0.f, 0.f};
  int r0 = m0 + mrow, r1 = m0 + 16 + mrow;
  bool ok0 = r0 < M, ok1 = r1 < M;
  const short* bl = A1p + lane * 8;
  for (int ks = 0; ks < 8; ks++) {
    const unsigned short* src = (ks < 4) ? Xs : Xc;
    int kb = (ks & 3) * 32 + kg * 8;
    short8 a0 = ok0 ? *(const short8*)(src + (size_t)r0 * 128 + kb) : zero8();
    short8 a1 = ok1 ? *(const short8*)(src + (size_t)r1 * 128 + kb) : zero8();
    const short* bb = bl + (ks << 12);
#pragma unroll
    for (int nf = 0; nf < 8; nf++) {
      short8 b = *(const short8*)(bb + (nf << 9));
      acc[0][nf] = __builtin_amdgcn_mfma_f32_16x16x32_bf16(a0, b, acc[0][nf], 0, 0, 0);
      acc[1][nf] = __builtin_amdgcn_mfma_f32_16x16x32_bf16(a1, b, acc[1][nf], 0, 0, 0);
    }
  }
  int col16 = lane & 15;
  int g = lane >> 4;
  float bias[8], w20[8], w21[8];
#pragma unroll
  for (int nf = 0; nf < 8; nf++) {
    int cc = nf * 16 + col16;
    bias[nf] = ab1[cc];
    w20[nf] = A2[2 * cc];
    w21[nf] = A2[2 * cc + 1];
  }
  float b20 = ab2[0], b21 = ab2[1];
#pragma unroll
  for (int mi = 0; mi < 2; mi++) {
#pragma unroll
    for (int r = 0; r < 4; r++) {
      float u0 = 0.f, u1 = 0.f;
#pragma unroll
      for (int nf = 0; nf < 8; nf++) {
        float tv = fmaxf(acc[mi][nf][r] + bias[nf], 0.f);
        u0 = fmaf(tv, w20[nf], u0);
        u1 = fmaf(tv, w21[nf], u1);
      }
#pragma unroll
      for (int off = 1; off < 16; off <<= 1) {
        u0 += __shfl_xor(u0, off);
        u1 += __shfl_xor(u1, off);
      }
      int row = m0 + mi * 16 + g * 4 + r;
      if (row < M) {
        float ua = u0 + b20, ub = u1 + b21;
        float mx = fmaxf(ua, ub);
        float e0 = __expf(ua - mx), e1 = __expf(ub - mx);
        float inv = 1.f / (e0 + e1);
        float w0 = e0 * inv, w1 = e1 * inv;
        int p = col16;
        const unsigned short* xsp = Xs + (size_t)row * 128 + p * 8;
        const unsigned short* xcp = Xc + (size_t)row * 128 + p * 8;
        float* op = fused + (size_t)row * 128 + p * 8;
        float4 o0, o1;
        unsigned sx0 = *(const unsigned*)(xsp + 0), sx1 = *(const unsigned*)(xsp + 2);
        unsigned sx2 = *(const unsigned*)(xsp + 4), sx3 = *(const unsigned*)(xsp + 6);
        unsigned cx0 = *(const unsigned*)(xcp + 0), cx1 = *(const unsigned*)(xcp + 2);
        unsigned cx2 = *(const unsigned*)(xcp + 4), cx3 = *(const unsigned*)(xcp + 6);
        o0.x = w0 * bflo(sx0) + w1 * bflo(cx0);
        o0.y = w0 * bfhi(sx0) + w1 * bfhi(cx0);
        o0.z = w0 * bflo(sx1) + w1 * bflo(cx1);
        o0.w = w0 * bfhi(sx1) + w1 * bfhi(cx1);
        o1.x = w0 * bflo(sx2) + w1 * bflo(cx2);
        o1.y = w0 * bfhi(sx2) + w1 * bfhi(cx2);
        o1.z = w0 * bflo(sx3) + w1 * bflo(cx3);
        o1.w = w0 * bfhi(sx3) + w1 * bfhi(cx3);
        *(float4*)op = o0;
        *(float4*)(op + 4) = o1;
      }
    }
  }
}

// ---------------- heads ----------------
__global__ __launch_bounds__(256) void k_final(const float* __restrict__ fused, const float* __restrict__ Wcls,
                                               const float* __restrict__ bcls, const float* __restrict__ D1,
                                               const float* __restrict__ db1, const float* __restrict__ D2,
                                               const float* __restrict__ db2, float* __restrict__ cls_out,
                                               float* __restrict__ dom_out, int M) {
  __shared__ float D1s[128 * 64];
  __shared__ float Ws[128 * 9];
  __shared__ float D2s[64 * 2];
  __shared__ float fr[16][128];
  __shared__ float hh[16][64];
  int t = threadIdx.x;
  for (int j = t; j < 128 * 64; j += 256) D1s[j] = D1[j];
  for (int j = t; j < 128 * 9; j += 256) Ws[j] = Wcls[j];
  if (t < 128) D2s[t] = D2[t];
  int r0 = blockIdx.x * 16;
  for (int j = t; j < 16 * 128; j += 256) {
    int r = j >> 7, k = j & 127;
    int gr = r0 + r;
    fr[r][k] = (gr < M) ? fused[(size_t)gr * 128 + k] : 0.f;
  }
  __syncthreads();
#pragma unroll
  for (int q = 0; q < 4; q++) {
    int j = t + q * 256;
    int r = j >> 6, h = j & 63;
    float a = db1[h];
    for (int k = 0; k < 128; k++) a = fmaf(fr[r][k], D1s[k * 64 + h], a);
    hh[r][h] = fmaxf(a, 0.f);
  }
  if (t < 144) {
    int r = t / 9, c = t % 9;
    float a = bcls[c];
    for (int k = 0; k < 128; k++) a = fmaf(fr[r][k], Ws[k * 9 + c], a);
    int gr = r0 + r;
    if (gr < M) cls_out[(size_t)gr * 9 + c] = a;
  }
  __syncthreads();
  if (t < 32) {
    int r = t >> 1, j = t & 1;
    float a = db2[j];
    for (int h = 0; h < 64; h++) a = fmaf(hh[r][h], D2s[h * 2 + j], a);
    int gr = r0 + r;
    if (gr < M) dom_out[(size_t)gr * 2 + j] = a;
  }
}

extern "C" void kernel_launch(void* const* d_in, const int* in_sizes, int n_in,
                              void* d_out, int out_size, void* d_ws, size_t ws_size,
                              hipStream_t stream) {
  const float* x_s = (const float*)d_in[0];
  const float* x_c = (const float*)d_in[1];
  const float* Q = (const float*)d_in[2];
  const int* eis = (const int*)d_in[3];
  const int* eic = (const int*)d_in[4];
  const float* W1s = (const float*)d_in[5];
  const float* b1s = (const float*)d_in[6];
  const float* W2s = (const float*)d_in[7];
  const float* b2s = (const float*)d_in[8];
  const float* W1c = (const float*)d_in[9];
  const float* b1c = (const float*)d_in[10];
  const float* W2c = (const float*)d_in[11];
  const float* b2c = (const float*)d_in[12];
  const float* A1 = (const float*)d_in[13];
  const float* ab1 = (const float*)d_in[14];
  const float* A2 = (const float*)d_in[15];
  const float* ab2 = (const float*)d_in[16];
  const float* Wcls = (const float*)d_in[17];
  const float* bcls = (const float*)d_in[18];
  const float* D1 = (const float*)d_in[19];
  const float* db1 = (const float*)d_in[20];
  const float* D2 = (const float*)d_in[21];
  const float* db2 = (const float*)d_in[22];

  float* out_cls = (float*)d_out;
  float* out_dom = out_cls + (size_t)kNS * 9;
  float* out_fus = out_dom + (size_t)kNS * 2;

  char* p = (char*)d_ws;
  auto alloc = [&](size_t bytes) -> void* {
    void* r = (void*)p;
    p += (bytes + 255) & ~(size_t)255;
    return r;
  };
  // sample graph
  int* deg_s = (int*)alloc((size_t)kNS * 4);
  float* dis_s = (float*)alloc((size_t)kNS * 4);
  int* nstarts_s = (int*)alloc((size_t)kNS * 4);
  int* counts_s = (int*)alloc((size_t)kNB8 * 4);
  int* bstarts_s = (int*)alloc((size_t)(kNB8 + 1) * 4);
  int* bcursor_s = (int*)alloc((size_t)kNB8 * 4);
  // cluster graph
  int* deg_c = (int*)alloc((size_t)kNC * 4);
  int* cstarts_c = (int*)alloc((size_t)kNC * 4);
  int* cursor_c = (int*)alloc((size_t)kNC * 4);
  int* bsum_c = (int*)alloc(512 * 4);
  float* dis_c = (float*)alloc((size_t)kNC * 4);
  int* srow_c = (int*)alloc((size_t)kEC * 4);
  // feature buffers (bf16)
  unsigned short* hc1b = (unsigned short*)alloc((size_t)kNC * 64 * 2);
  unsigned short* xc1b = (unsigned short*)alloc((size_t)kNC * 64 * 2);
  unsigned short* hc2b = (unsigned short*)alloc((size_t)kNC * 128 * 2);
  unsigned short* xc2b = (unsigned short*)alloc((size_t)kNC * 128 * 2);
  unsigned short* hs1b = (unsigned short*)alloc((size_t)kNS * 64 * 2);
  unsigned short* xs1b = (unsigned short*)alloc((size_t)kNS * 64 * 2);
  unsigned short* hs2b = (unsigned short*)alloc((size_t)kNS * 128 * 2);
  unsigned short* xs2b = (unsigned short*)alloc((size_t)kNS * 128 * 2);
  unsigned short* xcdb = (unsigned short*)alloc((size_t)kNS * 128 * 2);
  short* Bq = (short*)alloc((size_t)512 * 128 * 2);
  short* A1p = (short*)alloc((size_t)256 * 128 * 2);
  // aliases (lifetimes are disjoint along the stream order):
  //  edg_s (packed bucket-grouped edges) lives from passB to passC; hs2b written later.
  //  srow_s (final CSR rows) lives from passC to agg128; xcdb written later (gemm_q).
  unsigned* edg_s = (unsigned*)hs2b;  // 12.8MB <= 25.6MB
  int* srow_s = (int*)xcdb;           // 12.8MB <= 25.6MB
  (void)ws_size; (void)in_sizes; (void)n_in; (void)out_size;

  hipMemsetAsync(counts_s, 0, (size_t)kNB8 * 4, stream);
  hipMemsetAsync(deg_c, 0, (size_t)kNC * 4, stream);

  const int nbC = (kNC + 255) / 256;

  // sample-graph grouping: bucket histogram -> scan -> bucket append -> per-node re-sort
  k_passA<<<kEBLK, 256, 0, stream>>>(eis + kES, kES, counts_s);
  k_scan_flat<<<1, 256, 0, stream>>>(counts_s, kNB8, bstarts_s, bcursor_s);
  k_passB<<<kEBLK, 256, 0, stream>>>(eis, eis + kES, kES, bcursor_s, edg_s);
  k_passC<<<kNB, 256, 0, stream>>>(edg_s, bstarts_s, deg_s, nstarts_s, srow_s, kNS);
  k_dis<<<(kNS + 255) / 256, 256, 0, stream>>>(deg_s, kNS, dis_s);

  // cluster-graph CSR
  k_hist<<<(kEC + 255) / 256, 256, 0, stream>>>(eic + kEC, kEC, deg_c);
  k_dis<<<nbC, 256, 0, stream>>>(deg_c, kNC, dis_c);
  k_scan1<<<nbC, 256, 0, stream>>>(deg_c, kNC, cstarts_c, bsum_c);
  k_scan2<<<1, 256, 0, stream>>>(bsum_c, nbC);
  k_scan3<<<nbC, 256, 0, stream>>>(cstarts_c, cursor_c, bsum_c, kNC);
  k_scatter<<<(kEC + 255) / 256, 256, 0, stream>>>(eic, eic + kEC, kEC, cursor_c, srow_c);

  // pack A1 (independent)
  k_pack_b_f32src<<<(256 * 128 + 255) / 256, 256, 0, stream>>>(A1, A1p, 256);

  // cluster branch
  k_lin7<<<(kNC * 32 + 255) / 256, 256, 0, stream>>>(x_c, W1c, dis_c, hc1b, kNC);
  k_agg_bf<64><<<(kNC + 7) / 8, 256, 0, stream>>>(hc1b, cstarts_c, deg_c, srow_c, dis_c, b1c, xc1b, kNC);
  k_lin64x128<<<(kNC + 31) / 32, 256, 0, stream>>>(xc1b, W2c, dis_c, hc2b, kNC);
  k_agg_bf<128><<<(kNC + 3) / 4, 256, 0, stream>>>(hc2b, cstarts_c, deg_c, srow_c, dis_c, b2c, xc2b, kNC);
  k_pack_b_bf16src<<<(512 * 128 + 255) / 256, 256, 0, stream>>>(xc2b, Bq, 512);

  // sample branch
  k_lin7<<<(kNS * 32 + 255) / 256, 256, 0, stream>>>(x_s, W1s, dis_s, hs1b, kNS);
  k_agg_bf<64><<<(kNS + 7) / 8, 256, 0, stream>>>(hs1b, nstarts_s, deg_s, srow_s, dis_s, b1s, xs1b, kNS);
  k_lin64x128<<<(kNS + 31) / 32, 256, 0, stream>>>(xs1b, W2s, dis_s, hs2b, kNS);
  k_agg_bf<128><<<(kNS + 3) / 4, 256, 0, stream>>>(hs2b, nstarts_s, deg_s, srow_s, dis_s, b2s, xs2b, kNS);

  // decode + fusion gate + heads
  k_gemm_q_mfma<<<(kNS + 127) / 128, 256, 0, stream>>>(Q, Bq, xcdb, kNS);
  k_gemm_fuse_mfma<<<(kNS + 127) / 128, 256, 0, stream>>>(xs2b, xcdb, A1p, ab1, A2, ab2, out_fus, kNS);
  k_final<<<(kNS + 15) / 16, 256, 0, stream>>>(out_fus, Wcls, bcls, D1, db1, D2, db2, out_cls, out_dom, kNS);
}

// Round 5
// 735.838 us; speedup vs baseline: 6.0556x; 1.1591x over previous
//
#include <hip/hip_runtime.h>
#include <cstdint>
#include <cstddef>

static constexpr int kNS = 100000;
static constexpr int kNC = 512;
static constexpr int kES = 3200000;
static constexpr int kEC = 16384;

static constexpr int kNB = (kNS + 63) / 64;        // 1563 coarse buckets (64 nodes each)
static constexpr int kNB8 = kNB * 8;               // sub-bucketed counters
static constexpr int kCHUNK = 8192;                // edges per block in passA/passB
static constexpr int kNBLK = (kES + kCHUNK - 1) / kCHUNK;  // 391 blocks

typedef __attribute__((ext_vector_type(8))) short short8;
typedef __attribute__((ext_vector_type(4))) float f32x4;

__device__ __forceinline__ unsigned short f2bf(float f) {
  union { float f; unsigned u; } v; v.f = f;
  unsigned u = v.u;
  unsigned r = (u + 0x7fffu + ((u >> 16) & 1u)) >> 16;
  return (unsigned short)r;
}
__device__ __forceinline__ float bflo(unsigned v) { return __uint_as_float(v << 16); }
__device__ __forceinline__ float bfhi(unsigned v) { return __uint_as_float(v & 0xffff0000u); }
__device__ __forceinline__ float bf2f(unsigned short s) { return __uint_as_float(((unsigned)s) << 16); }

// ---------------- sample graph: bucket histogram (1 global atomic per touched bucket) ----------------
__global__ __launch_bounds__(256) void k_passA(const int* __restrict__ col, int E,
                                               int* __restrict__ counts) {
  __shared__ int hist[kNB];
  int t = threadIdx.x, bid = blockIdx.x;
  for (int j = t; j < kNB; j += 256) hist[j] = 0;
  __syncthreads();
  int base = bid * kCHUNK;
#pragma unroll 4
  for (int i = 0; i < kCHUNK / 256; i++) {
    int e = base + i * 256 + t;
    if (e < E) atomicAdd(&hist[col[e] >> 6], 1);
  }
  __syncthreads();
  int sub = bid & 7;
  for (int j = t; j < kNB; j += 256) {
    int v = hist[j];
    if (v) atomicAdd(&counts[j * 8 + sub], v);
  }
}

// exclusive scan of n flat counters -> starts[n+1], cursor copy
__global__ void k_scan_flat(const int* __restrict__ cnt, int n, int* __restrict__ starts,
                            int* __restrict__ cursor) {
  __shared__ int s[256];
  int t = threadIdx.x;
  int run = 0;
  for (int base = 0; base < n; base += 256) {
    int i = base + t;
    int v = (i < n) ? cnt[i] : 0;
    s[t] = v;
    __syncthreads();
    for (int o = 1; o < 256; o <<= 1) {
      int x = (t >= o) ? s[t - o] : 0;
      __syncthreads();
      s[t] += x;
      __syncthreads();
    }
    if (i < n) {
      int ex = run + s[t] - v;
      starts[i] = ex;
      cursor[i] = ex;
    }
    int tot = s[255];
    __syncthreads();
    run += tot;
  }
  if (t == 0) starts[n] = run;
}

// Pass B: LDS-hist -> per-bucket range reservation (1 global atomic each) -> LDS-cursor append.
__global__ __launch_bounds__(256) void k_passB(const int* __restrict__ row, const int* __restrict__ col,
                                               int E, int* __restrict__ cursor, unsigned* __restrict__ edg) {
  __shared__ int hist[kNB];
  int t = threadIdx.x, bid = blockIdx.x;
  int sub = bid & 7;
  for (int j = t; j < kNB; j += 256) hist[j] = 0;
  __syncthreads();
  int base = bid * kCHUNK;
#pragma unroll 4
  for (int i = 0; i < kCHUNK / 256; i++) {
    int e = base + i * 256 + t;
    if (e < E) atomicAdd(&hist[col[e] >> 6], 1);
  }
  __syncthreads();
  for (int j = t; j < kNB; j += 256) {
    int v = hist[j];
    hist[j] = v ? atomicAdd(&cursor[j * 8 + sub], v) : 0;  // hist[j] becomes this block's run start
  }
  __syncthreads();
#pragma unroll 4
  for (int i = 0; i < kCHUNK / 256; i++) {
    int e = base + i * 256 + t;
    if (e < E) {
      int c = col[e];
      int pos = atomicAdd(&hist[c >> 6], 1);  // LDS-only cursor
      edg[pos] = ((unsigned)row[e] << 6) | (unsigned)(c & 63);
    }
  }
}

// Pass C: per-bucket re-sort into exact per-node CSR; emits per-node degree + starts + dis.
__global__ __launch_bounds__(256) void k_passC(const unsigned* __restrict__ edg,
                                               const int* __restrict__ bstarts,
                                               int* __restrict__ deg, int* __restrict__ nstarts,
                                               float* __restrict__ dis,
                                               int* __restrict__ srow, int N) {
  __shared__ int ldeg[64];
  __shared__ int lcur[64];
  int b = blockIdx.x, t = threadIdx.x;
  int s0 = bstarts[b * 8], s1 = bstarts[b * 8 + 8];
  if (t < 64) ldeg[t] = 0;
  __syncthreads();
  for (int i = s0 + t; i < s1; i += 256) atomicAdd(&ldeg[edg[i] & 63u], 1);
  __syncthreads();
  if (t < 64) {
    int own = ldeg[t];
    int incl = own;
#pragma unroll
    for (int off = 1; off < 64; off <<= 1) {
      int o = __shfl_up(incl, off);
      if (t >= off) incl += o;
    }
    int st = s0 + incl - own;
    lcur[t] = st;
    int g = b * 64 + t;
    if (g < N) {
      deg[g] = own;
      nstarts[g] = st;
      dis[g] = rsqrtf((float)(own + 1));
    }
  }
  __syncthreads();
  for (int i = s0 + t; i < s1; i += 256) {
    unsigned ew = edg[i];
    int pos = atomicAdd(&lcur[ew & 63u], 1);
    srow[pos] = (int)(ew >> 6);
  }
}

// ---------------- cluster graph: small CSR path ----------------
__global__ void k_hist(const int* __restrict__ col, int E, int* __restrict__ cnt) {
  int i = blockIdx.x * blockDim.x + threadIdx.x;
  if (i < E) atomicAdd(&cnt[col[i]], 1);
}

__global__ void k_dis(const int* __restrict__ cnt, int N, float* __restrict__ dis) {
  int i = blockIdx.x * blockDim.x + threadIdx.x;
  if (i < N) dis[i] = rsqrtf((float)(cnt[i] + 1));
}

__global__ void k_scan1(const int* __restrict__ cnt, int N, int* __restrict__ starts, int* __restrict__ bsum) {
  __shared__ int s[256];
  int t = threadIdx.x;
  int i = blockIdx.x * 256 + t;
  int v = (i < N) ? cnt[i] : 0;
  s[t] = v;
  __syncthreads();
  for (int o = 1; o < 256; o <<= 1) {
    int x = (t >= o) ? s[t - o] : 0;
    __syncthreads();
    s[t] += x;
    __syncthreads();
  }
  if (i < N) starts[i] = s[t] - v;
  if (t == 255) bsum[blockIdx.x] = s[255];
}

__global__ void k_scan2(int* __restrict__ bsum, int nb) {
  __shared__ int s[256];
  int t = threadIdx.x;
  int run = 0;
  for (int base = 0; base < nb; base += 256) {
    int i = base + t;
    int v = (i < nb) ? bsum[i] : 0;
    s[t] = v;
    __syncthreads();
    for (int o = 1; o < 256; o <<= 1) {
      int x = (t >= o) ? s[t - o] : 0;
      __syncthreads();
      s[t] += x;
      __syncthreads();
    }
    if (i < nb) bsum[i] = run + s[t] - v;
    int tot = s[255];
    __syncthreads();
    run += tot;
  }
}

__global__ void k_scan3(int* __restrict__ starts, int* __restrict__ cursor, const int* __restrict__ bsum, int N) {
  int i = blockIdx.x * 256 + threadIdx.x;
  if (i < N) {
    int v = starts[i] + bsum[blockIdx.x];
    starts[i] = v;
    cursor[i] = v;
  }
}

__global__ void k_scatter(const int* __restrict__ row, const int* __restrict__ col, int E,
                          int* __restrict__ cursor, int* __restrict__ srow) {
  int i = blockIdx.x * blockDim.x + threadIdx.x;
  if (i < E) {
    int pos = atomicAdd(&cursor[col[i]], 1);
    srow[pos] = row[i];
  }
}

// ---------------- aggregation (bf16 in/out): out[c] = relu(dis[c]*(hs[c]+sum hs[r]) + b) ----------------
template <int F>
__global__ __launch_bounds__(256) void k_agg_bf(const unsigned short* __restrict__ hs,
                                                const int* __restrict__ starts, const int* __restrict__ cnt,
                                                const int* __restrict__ srow, const float* __restrict__ dis,
                                                const float* __restrict__ b, unsigned short* __restrict__ out, int N) {
  constexpr int LPN = F / 2;
  int t = threadIdx.x;
  int c = blockIdx.x * (256 / LPN) + t / LPN;
  if (c >= N) return;
  int fi = (t % LPN) * 2;
  unsigned v = *(const unsigned*)(hs + (size_t)c * F + fi);
  float ax = bflo(v), ay = bfhi(v);
  int s0 = starts[c], n = cnt[c];
  const int* sp = srow + s0;
  int e = 0;
  for (; e + 4 <= n; e += 4) {
    int r0 = sp[e], r1 = sp[e + 1], r2 = sp[e + 2], r3 = sp[e + 3];
    unsigned v0 = *(const unsigned*)(hs + (size_t)r0 * F + fi);
    unsigned v1 = *(const unsigned*)(hs + (size_t)r1 * F + fi);
    unsigned v2 = *(const unsigned*)(hs + (size_t)r2 * F + fi);
    unsigned v3 = *(const unsigned*)(hs + (size_t)r3 * F + fi);
    ax += bflo(v0) + bflo(v1) + bflo(v2) + bflo(v3);
    ay += bfhi(v0) + bfhi(v1) + bfhi(v2) + bfhi(v3);
  }
  for (; e < n; e++) {
    unsigned vv = *(const unsigned*)(hs + (size_t)sp[e] * F + fi);
    ax += bflo(vv);
    ay += bfhi(vv);
  }
  float d = dis[c];
  float ox = fmaxf(fmaf(d, ax, b[fi]), 0.f);
  float oy = fmaxf(fmaf(d, ay, b[fi + 1]), 0.f);
  *(unsigned*)(out + (size_t)c * F + fi) = (unsigned)f2bf(ox) | ((unsigned)f2bf(oy) << 16);
}

// ---------------- layer-1 linear: hs[N,64](bf16) = (x[N,7] @ W[7,64]) * dis[row] ----------------
__global__ __launch_bounds__(256) void k_lin7(const float* __restrict__ x, const float* __restrict__ W,
                                              const float* __restrict__ dis, unsigned short* __restrict__ hs, int N) {
  __shared__ float Ws[7 * 64];
  int t = threadIdx.x;
  for (int j = t; j < 7 * 64; j += 256) Ws[j] = W[j];
  __syncthreads();
  int idx = blockIdx.x * 256 + t;
  if (idx < N * 32) {
    int r = idx >> 5, c2 = (idx & 31) * 2;
    const float* xr = x + (size_t)r * 7;
    float a0 = 0.f, a1 = 0.f;
#pragma unroll
    for (int k = 0; k < 7; k++) {
      float xv = xr[k];
      a0 = fmaf(xv, Ws[k * 64 + c2], a0);
      a1 = fmaf(xv, Ws[k * 64 + c2 + 1], a1);
    }
    float d = dis[r];
    unsigned pk = (unsigned)f2bf(a0 * d) | ((unsigned)f2bf(a1 * d) << 16);
    *(unsigned*)(hs + (size_t)r * 64 + c2) = pk;
  }
}

// ---------------- layer-2 linear: 32 rows/block: hs2[N,128] = (xin[N,64] @ W[64,128]) * dis ----------------
__global__ __launch_bounds__(256) void k_lin64x128(const unsigned short* __restrict__ xin, const float* __restrict__ W,
                                                   const float* __restrict__ dis, unsigned short* __restrict__ hs, int N) {
  __shared__ float Ws[64 * 128];
  __shared__ float xs[32][64];
  int t = threadIdx.x;
  for (int j = t; j < 64 * 128; j += 256) Ws[j] = W[j];
  int r0 = blockIdx.x * 32;
  for (int j = t; j < 32 * 64; j += 256) {
    int r = j >> 6, k = j & 63;
    int gr = r0 + r;
    xs[r][k] = (gr < N) ? bf2f(xin[(size_t)gr * 64 + k]) : 0.f;
  }
  __syncthreads();
  int c = t & 63;            // cols c and c+64
  int rb = (t >> 6) * 8;     // 4 groups x 8 rows
  float a0[8], a1[8];
#pragma unroll
  for (int rr = 0; rr < 8; rr++) { a0[rr] = 0.f; a1[rr] = 0.f; }
  for (int k = 0; k < 64; k++) {
    float w0 = Ws[k * 128 + c];
    float w1 = Ws[k * 128 + c + 64];
#pragma unroll
    for (int rr = 0; rr < 8; rr++) {
      float xv = xs[rb + rr][k];
      a0[rr] = fmaf(xv, w0, a0[rr]);
      a1[rr] = fmaf(xv, w1, a1[rr]);
    }
  }
#pragma unroll
  for (int rr = 0; rr < 8; rr++) {
    int gr = r0 + rb + rr;
    if (gr < N) {
      float d = dis[gr];
      hs[(size_t)gr * 128 + c] = f2bf(a0[rr] * d);
      hs[(size_t)gr * 128 + c + 64] = f2bf(a1[rr] * d);
    }
  }
}

// ---------------- B-operand fragment packers ----------------
__global__ void k_pack_b_bf16src(const unsigned short* __restrict__ src, short* __restrict__ dst, int K) {
  int e = blockIdx.x * 256 + threadIdx.x;
  if (e >= K * 128) return;
  int k = e >> 7, n = e & 127;
  int frag = (k >> 5) * 8 + (n >> 4);
  int l = (n & 15) | (((k >> 3) & 3) << 4);
  int j = k & 7;
  dst[(size_t)frag * 512 + l * 8 + j] = (short)src[e];
}
__global__ void k_pack_b_f32src(const float* __restrict__ src, short* __restrict__ dst, int K) {
  int e = blockIdx.x * 256 + threadIdx.x;
  if (e >= K * 128) return;
  int k = e >> 7, n = e & 127;
  int frag = (k >> 5) * 8 + (n >> 4);
  int l = (n & 15) | (((k >> 3) & 3) << 4);
  int j = k & 7;
  dst[(size_t)frag * 512 + l * 8 + j] = (short)f2bf(src[e]);
}

__device__ __forceinline__ short8 zero8() {
  short8 z;
#pragma unroll
  for (int j = 0; j < 8; j++) z[j] = 0;
  return z;
}

__device__ __forceinline__ short8 load_a_f32(const float* p, bool ok) {
  short8 r;
  if (ok) {
    float4 v0 = *(const float4*)p;
    float4 v1 = *(const float4*)(p + 4);
    r[0] = (short)f2bf(v0.x); r[1] = (short)f2bf(v0.y); r[2] = (short)f2bf(v0.z); r[3] = (short)f2bf(v0.w);
    r[4] = (short)f2bf(v1.x); r[5] = (short)f2bf(v1.y); r[6] = (short)f2bf(v1.z); r[7] = (short)f2bf(v1.w);
  } else {
    r = zero8();
  }
  return r;
}

// ---------------- GEMM1 (MFMA): xcdec[M,128](bf16) = Q[M,512](fp32) @ Bq ----------------
__global__ __launch_bounds__(256) void k_gemm_q_mfma(const float* __restrict__ Q, const short* __restrict__ Bp,
                                                     unsigned short* __restrict__ outb, int M) {
  int t = threadIdx.x;
  int lane = t & 63;
  int wid = t >> 6;
  int m0 = blockIdx.x * 128 + wid * 32;
  int mrow = lane & 15;
  int kg = lane >> 4;
  f32x4 acc[2][8];
#pragma unroll
  for (int mi = 0; mi < 2; mi++)
#pragma unroll
    for (int nf = 0; nf < 8; nf++) acc[mi][nf] = (f32x4){0.f, 0.f, 0.f, 0.f};
  int r0 = m0 + mrow, r1 = m0 + 16 + mrow;
  bool ok0 = r0 < M, ok1 = r1 < M;
  const float* a0p = Q + (size_t)r0 * 512 + kg * 8;
  const float* a1p = Q + (size_t)r1 * 512 + kg * 8;
  const short* bl = Bp + lane * 8;
  for (int ks = 0; ks < 16; ks++) {
    short8 a0 = load_a_f32(a0p + ks * 32, ok0);
    short8 a1 = load_a_f32(a1p + ks * 32, ok1);
    const short* bb = bl + (ks << 12);
#pragma unroll
    for (int nf = 0; nf < 8; nf++) {
      short8 b = *(const short8*)(bb + (nf << 9));
      acc[0][nf] = __builtin_amdgcn_mfma_f32_16x16x32_bf16(a0, b, acc[0][nf], 0, 0, 0);
      acc[1][nf] = __builtin_amdgcn_mfma_f32_16x16x32_bf16(a1, b, acc[1][nf], 0, 0, 0);
    }
  }
  int col = lane & 15;
  int g = lane >> 4;
#pragma unroll
  for (int mi = 0; mi < 2; mi++)
#pragma unroll
    for (int nf = 0; nf < 8; nf++)
#pragma unroll
      for (int r = 0; r < 4; r++) {
        int row = m0 + mi * 16 + g * 4 + r;
        if (row < M) outb[(size_t)row * 128 + nf * 16 + col] = f2bf(acc[mi][nf][r]);
      }
}

// ---------------- GEMM2 (MFMA) + gate epilogue ----------------
__global__ __launch_bounds__(256) void k_gemm_fuse_mfma(const unsigned short* __restrict__ Xs,
                                                        const unsigned short* __restrict__ Xc,
                                                        const short* __restrict__ A1p, const float* __restrict__ ab1,
                                                        const float* __restrict__ A2, const float* __restrict__ ab2,
                                                        float* __restrict__ fused, int M) {
  int t = threadIdx.x;
  int lane = t & 63;
  int wid = t >> 6;
  int m0 = blockIdx.x * 128 + wid * 32;
  int mrow = lane & 15;
  int kg = lane >> 4;
  f32x4 acc[2][8];
#pragma unroll
  for (int mi = 0; mi < 2; mi++)
#pragma unroll
    for (int nf = 0; nf < 8; nf++) acc[mi][nf] = (f32x4){0.f, 0.f, 0.f, 0.f};
  int r0 = m0 + mrow, r1 = m0 + 16 + mrow;
  bool ok0 = r0 < M, ok1 = r1 < M;
  const short* bl = A1p + lane * 8;
  for (int ks = 0; ks < 8; ks++) {
    const unsigned short* src = (ks < 4) ? Xs : Xc;
    int kb = (ks & 3) * 32 + kg * 8;
    short8 a0 = ok0 ? *(const short8*)(src + (size_t)r0 * 128 + kb) : zero8();
    short8 a1 = ok1 ? *(const short8*)(src + (size_t)r1 * 128 + kb) : zero8();
    const short* bb = bl + (ks << 12);
#pragma unroll
    for (int nf = 0; nf < 8; nf++) {
      short8 b = *(const short8*)(bb + (nf << 9));
      acc[0][nf] = __builtin_amdgcn_mfma_f32_16x16x32_bf16(a0, b, acc[0][nf], 0, 0, 0);
      acc[1][nf] = __builtin_amdgcn_mfma_f32_16x16x32_bf16(a1, b, acc[1][nf], 0, 0, 0);
    }
  }
  int col16 = lane & 15;
  int g = lane >> 4;
  float bias[8], w20[8], w21[8];
#pragma unroll
  for (int nf = 0; nf < 8; nf++) {
    int cc = nf * 16 + col16;
    bias[nf] = ab1[cc];
    w20[nf] = A2[2 * cc];
    w21[nf] = A2[2 * cc + 1];
  }
  float b20 = ab2[0], b21 = ab2[1];
#pragma unroll
  for (int mi = 0; mi < 2; mi++) {
#pragma unroll
    for (int r = 0; r < 4; r++) {
      float u0 = 0.f, u1 = 0.f;
#pragma unroll
      for (int nf = 0; nf < 8; nf++) {
        float tv = fmaxf(acc[mi][nf][r] + bias[nf], 0.f);
        u0 = fmaf(tv, w20[nf], u0);
        u1 = fmaf(tv, w21[nf], u1);
      }
#pragma unroll
      for (int off = 1; off < 16; off <<= 1) {
        u0 += __shfl_xor(u0, off);
        u1 += __shfl_xor(u1, off);
      }
      int row = m0 + mi * 16 + g * 4 + r;
      if (row < M) {
        float ua = u0 + b20, ub = u1 + b21;
        float mx = fmaxf(ua, ub);
        float e0 = __expf(ua - mx), e1 = __expf(ub - mx);
        float inv = 1.f / (e0 + e1);
        float w0 = e0 * inv, w1 = e1 * inv;
        int p = col16;
        const unsigned short* xsp = Xs + (size_t)row * 128 + p * 8;
        const unsigned short* xcp = Xc + (size_t)row * 128 + p * 8;
        float* op = fused + (size_t)row * 128 + p * 8;
        float4 o0, o1;
        unsigned sx0 = *(const unsigned*)(xsp + 0), sx1 = *(const unsigned*)(xsp + 2);
        unsigned sx2 = *(const unsigned*)(xsp + 4), sx3 = *(const unsigned*)(xsp + 6);
        unsigned cx0 = *(const unsigned*)(xcp + 0), cx1 = *(const unsigned*)(xcp + 2);
        unsigned cx2 = *(const unsigned*)(xcp + 4), cx3 = *(const unsigned*)(xcp + 6);
        o0.x = w0 * bflo(sx0) + w1 * bflo(cx0);
        o0.y = w0 * bfhi(sx0) + w1 * bfhi(cx0);
        o0.z = w0 * bflo(sx1) + w1 * bflo(cx1);
        o0.w = w0 * bfhi(sx1) + w1 * bfhi(cx1);
        o1.x = w0 * bflo(sx2) + w1 * bflo(cx2);
        o1.y = w0 * bfhi(sx2) + w1 * bfhi(cx2);
        o1.z = w0 * bflo(sx3) + w1 * bflo(cx3);
        o1.w = w0 * bfhi(sx3) + w1 * bfhi(cx3);
        *(float4*)op = o0;
        *(float4*)(op + 4) = o1;
      }
    }
  }
}

// ---------------- heads ----------------
__global__ __launch_bounds__(256) void k_final(const float* __restrict__ fused, const float* __restrict__ Wcls,
                                               const float* __restrict__ bcls, const float* __restrict__ D1,
                                               const float* __restrict__ db1, const float* __restrict__ D2,
                                               const float* __restrict__ db2, float* __restrict__ cls_out,
                                               float* __restrict__ dom_out, int M) {
  __shared__ float D1s[128 * 64];
  __shared__ float Ws[128 * 9];
  __shared__ float D2s[64 * 2];
  __shared__ float fr[16][128];
  __shared__ float hh[16][64];
  int t = threadIdx.x;
  for (int j = t; j < 128 * 64; j += 256) D1s[j] = D1[j];
  for (int j = t; j < 128 * 9; j += 256) Ws[j] = Wcls[j];
  if (t < 128) D2s[t] = D2[t];
  int r0 = blockIdx.x * 16;
  for (int j = t; j < 16 * 128; j += 256) {
    int r = j >> 7, k = j & 127;
    int gr = r0 + r;
    fr[r][k] = (gr < M) ? fused[(size_t)gr * 128 + k] : 0.f;
  }
  __syncthreads();
#pragma unroll
  for (int q = 0; q < 4; q++) {
    int j = t + q * 256;
    int r = j >> 6, h = j & 63;
    float a = db1[h];
    for (int k = 0; k < 128; k++) a = fmaf(fr[r][k], D1s[k * 64 + h], a);
    hh[r][h] = fmaxf(a, 0.f);
  }
  if (t < 144) {
    int r = t / 9, c = t % 9;
    float a = bcls[c];
    for (int k = 0; k < 128; k++) a = fmaf(fr[r][k], Ws[k * 9 + c], a);
    int gr = r0 + r;
    if (gr < M) cls_out[(size_t)gr * 9 + c] = a;
  }
  __syncthreads();
  if (t < 32) {
    int r = t >> 1, j = t & 1;
    float a = db2[j];
    for (int h = 0; h < 64; h++) a = fmaf(hh[r][h], D2s[h * 2 + j], a);
    int gr = r0 + r;
    if (gr < M) dom_out[(size_t)gr * 2 + j] = a;
  }
}

extern "C" void kernel_launch(void* const* d_in, const int* in_sizes, int n_in,
                              void* d_out, int out_size, void* d_ws, size_t ws_size,
                              hipStream_t stream) {
  const float* x_s = (const float*)d_in[0];
  const float* x_c = (const float*)d_in[1];
  const float* Q = (const float*)d_in[2];
  const int* eis = (const int*)d_in[3];
  const int* eic = (const int*)d_in[4];
  const float* W1s = (const float*)d_in[5];
  const float* b1s = (const float*)d_in[6];
  const float* W2s = (const float*)d_in[7];
  const float* b2s = (const float*)d_in[8];
  const float* W1c = (const float*)d_in[9];
  const float* b1c = (const float*)d_in[10];
  const float* W2c = (const float*)d_in[11];
  const float* b2c = (const float*)d_in[12];
  const float* A1 = (const float*)d_in[13];
  const float* ab1 = (const float*)d_in[14];
  const float* A2 = (const float*)d_in[15];
  const float* ab2 = (const float*)d_in[16];
  const float* Wcls = (const float*)d_in[17];
  const float* bcls = (const float*)d_in[18];
  const float* D1 = (const float*)d_in[19];
  const float* db1 = (const float*)d_in[20];
  const float* D2 = (const float*)d_in[21];
  const float* db2 = (const float*)d_in[22];

  float* out_cls = (float*)d_out;
  float* out_dom = out_cls + (size_t)kNS * 9;
  float* out_fus = out_dom + (size_t)kNS * 2;

  char* p = (char*)d_ws;
  auto alloc = [&](size_t bytes) -> void* {
    void* r = (void*)p;
    p += (bytes + 255) & ~(size_t)255;
    return r;
  };
  // sample graph
  int* deg_s = (int*)alloc((size_t)kNS * 4);
  float* dis_s = (float*)alloc((size_t)kNS * 4);
  int* nstarts_s = (int*)alloc((size_t)kNS * 4);
  int* counts_s = (int*)alloc((size_t)kNB8 * 4);
  int* bstarts_s = (int*)alloc((size_t)(kNB8 + 1) * 4);
  int* bcursor_s = (int*)alloc((size_t)kNB8 * 4);
  // cluster graph
  int* deg_c = (int*)alloc((size_t)kNC * 4);
  int* cstarts_c = (int*)alloc((size_t)kNC * 4);
  int* cursor_c = (int*)alloc((size_t)kNC * 4);
  int* bsum_c = (int*)alloc(512 * 4);
  float* dis_c = (float*)alloc((size_t)kNC * 4);
  int* srow_c = (int*)alloc((size_t)kEC * 4);
  // feature buffers (bf16)
  unsigned short* hc1b = (unsigned short*)alloc((size_t)kNC * 64 * 2);
  unsigned short* xc1b = (unsigned short*)alloc((size_t)kNC * 64 * 2);
  unsigned short* hc2b = (unsigned short*)alloc((size_t)kNC * 128 * 2);
  unsigned short* xc2b = (unsigned short*)alloc((size_t)kNC * 128 * 2);
  unsigned short* hs1b = (unsigned short*)alloc((size_t)kNS * 64 * 2);
  unsigned short* xs1b = (unsigned short*)alloc((size_t)kNS * 64 * 2);
  unsigned short* hs2b = (unsigned short*)alloc((size_t)kNS * 128 * 2);
  unsigned short* xs2b = (unsigned short*)alloc((size_t)kNS * 128 * 2);
  unsigned short* xcdb = (unsigned short*)alloc((size_t)kNS * 128 * 2);
  short* Bq = (short*)alloc((size_t)512 * 128 * 2);
  short* A1p = (short*)alloc((size_t)256 * 128 * 2);
  // aliases (lifetimes disjoint along stream order):
  unsigned* edg_s = (unsigned*)hs2b;  // passB->passC; hs2b written later
  int* srow_s = (int*)xcdb;           // passC->agg128; xcdb written later (gemm_q)
  (void)ws_size; (void)in_sizes; (void)n_in; (void)out_size;

  hipMemsetAsync(counts_s, 0, (size_t)kNB8 * 4, stream);
  hipMemsetAsync(deg_c, 0, (size_t)kNC * 4, stream);

  const int nbC = (kNC + 255) / 256;

  // sample-graph grouping: bucket histogram -> scan -> reserved append -> per-node re-sort
  k_passA<<<kNBLK, 256, 0, stream>>>(eis + kES, kES, counts_s);
  k_scan_flat<<<1, 256, 0, stream>>>(counts_s, kNB8, bstarts_s, bcursor_s);
  k_passB<<<kNBLK, 256, 0, stream>>>(eis, eis + kES, kES, bcursor_s, edg_s);
  k_passC<<<kNB, 256, 0, stream>>>(edg_s, bstarts_s, deg_s, nstarts_s, dis_s, srow_s, kNS);

  // cluster-graph CSR
  k_hist<<<(kEC + 255) / 256, 256, 0, stream>>>(eic + kEC, kEC, deg_c);
  k_dis<<<nbC, 256, 0, stream>>>(deg_c, kNC, dis_c);
  k_scan1<<<nbC, 256, 0, stream>>>(deg_c, kNC, cstarts_c, bsum_c);
  k_scan2<<<1, 256, 0, stream>>>(bsum_c, nbC);
  k_scan3<<<nbC, 256, 0, stream>>>(cstarts_c, cursor_c, bsum_c, kNC);
  k_scatter<<<(kEC + 255) / 256, 256, 0, stream>>>(eic, eic + kEC, kEC, cursor_c, srow_c);

  // pack A1 (independent)
  k_pack_b_f32src<<<(256 * 128 + 255) / 256, 256, 0, stream>>>(A1, A1p, 256);

  // cluster branch
  k_lin7<<<(kNC * 32 + 255) / 256, 256, 0, stream>>>(x_c, W1c, dis_c, hc1b, kNC);
  k_agg_bf<64><<<(kNC + 7) / 8, 256, 0, stream>>>(hc1b, cstarts_c, deg_c, srow_c, dis_c, b1c, xc1b, kNC);
  k_lin64x128<<<(kNC + 31) / 32, 256, 0, stream>>>(xc1b, W2c, dis_c, hc2b, kNC);
  k_agg_bf<128><<<(kNC + 3) / 4, 256, 0, stream>>>(hc2b, cstarts_c, deg_c, srow_c, dis_c, b2c, xc2b, kNC);
  k_pack_b_bf16src<<<(512 * 128 + 255) / 256, 256, 0, stream>>>(xc2b, Bq, 512);

  // sample branch
  k_lin7<<<(kNS * 32 + 255) / 256, 256, 0, stream>>>(x_s, W1s, dis_s, hs1b, kNS);
  k_agg_bf<64><<<(kNS + 7) / 8, 256, 0, stream>>>(hs1b, nstarts_s, deg_s, srow_s, dis_s, b1s, xs1b, kNS);
  k_lin64x128<<<(kNS + 31) / 32, 256, 0, stream>>>(xs1b, W2s, dis_s, hs2b, kNS);
  k_agg_bf<128><<<(kNS + 3) / 4, 256, 0, stream>>>(hs2b, nstarts_s, deg_s, srow_s, dis_s, b2s, xs2b, kNS);

  // decode + fusion gate + heads
  k_gemm_q_mfma<<<(kNS + 127) / 128, 256, 0, stream>>>(Q, Bq, xcdb, kNS);
  k_gemm_fuse_mfma<<<(kNS + 127) / 128, 256, 0, stream>>>(xs2b, xcdb, A1p, ab1, A2, ab2, out_fus, kNS);
  k_final<<<(kNS + 15) / 16, 256, 0, stream>>>(out_fus, Wcls, bcls, D1, db1, D2, db2, out_cls, out_dom, kNS);
}

// Round 6
// 622.644 us; speedup vs baseline: 7.1564x; 1.1818x over previous
//
#include <hip/hip_runtime.h>
#include <cstdint>
#include <cstddef>

static constexpr int kNS = 100000;
static constexpr int kNC = 512;
static constexpr int kES = 3200000;
static constexpr int kEC = 16384;

static constexpr int kNB = (kNS + 63) / 64;        // 1563 coarse buckets (64 nodes each)
static constexpr int kNB8 = kNB * 8;               // sub-bucketed counters
static constexpr int kCHUNK = 8192;                // edges per block in passA/passB
static constexpr int kNBLK = (kES + kCHUNK - 1) / kCHUNK;  // 391 blocks

typedef __attribute__((ext_vector_type(8))) short short8;
typedef __attribute__((ext_vector_type(4))) float f32x4;

__device__ __forceinline__ unsigned short f2bf(float f) {
  union { float f; unsigned u; } v; v.f = f;
  unsigned u = v.u;
  unsigned r = (u + 0x7fffu + ((u >> 16) & 1u)) >> 16;
  return (unsigned short)r;
}
__device__ __forceinline__ float bflo(unsigned v) { return __uint_as_float(v << 16); }
__device__ __forceinline__ float bfhi(unsigned v) { return __uint_as_float(v & 0xffff0000u); }
__device__ __forceinline__ float bf2f(unsigned short s) { return __uint_as_float(((unsigned)s) << 16); }

// ---------------- sample graph: bucket histogram (1 global atomic per touched bucket) ----------------
__global__ __launch_bounds__(256) void k_passA(const int* __restrict__ col, int E,
                                               int* __restrict__ counts) {
  __shared__ int hist[kNB];
  int t = threadIdx.x, bid = blockIdx.x;
  for (int j = t; j < kNB; j += 256) hist[j] = 0;
  __syncthreads();
  int base = bid * kCHUNK;
#pragma unroll 4
  for (int i = 0; i < kCHUNK / 256; i++) {
    int e = base + i * 256 + t;
    if (e < E) atomicAdd(&hist[col[e] >> 6], 1);
  }
  __syncthreads();
  int sub = bid & 7;
  for (int j = t; j < kNB; j += 256) {
    int v = hist[j];
    if (v) atomicAdd(&counts[j * 8 + sub], v);
  }
}

// exclusive scan of n flat counters -> starts[n+1], cursor copy
__global__ void k_scan_flat(const int* __restrict__ cnt, int n, int* __restrict__ starts,
                            int* __restrict__ cursor) {
  __shared__ int s[256];
  int t = threadIdx.x;
  int run = 0;
  for (int base = 0; base < n; base += 256) {
    int i = base + t;
    int v = (i < n) ? cnt[i] : 0;
    s[t] = v;
    __syncthreads();
    for (int o = 1; o < 256; o <<= 1) {
      int x = (t >= o) ? s[t - o] : 0;
      __syncthreads();
      s[t] += x;
      __syncthreads();
    }
    if (i < n) {
      int ex = run + s[t] - v;
      starts[i] = ex;
      cursor[i] = ex;
    }
    int tot = s[255];
    __syncthreads();
    run += tot;
  }
  if (t == 0) starts[n] = run;
}

// Pass B: LDS-hist -> per-bucket range reservation (1 global atomic each) -> LDS-cursor append.
__global__ __launch_bounds__(256) void k_passB(const int* __restrict__ row, const int* __restrict__ col,
                                               int E, int* __restrict__ cursor, unsigned* __restrict__ edg) {
  __shared__ int hist[kNB];
  int t = threadIdx.x, bid = blockIdx.x;
  int sub = bid & 7;
  for (int j = t; j < kNB; j += 256) hist[j] = 0;
  __syncthreads();
  int base = bid * kCHUNK;
#pragma unroll 4
  for (int i = 0; i < kCHUNK / 256; i++) {
    int e = base + i * 256 + t;
    if (e < E) atomicAdd(&hist[col[e] >> 6], 1);
  }
  __syncthreads();
  for (int j = t; j < kNB; j += 256) {
    int v = hist[j];
    hist[j] = v ? atomicAdd(&cursor[j * 8 + sub], v) : 0;  // becomes this block's run start
  }
  __syncthreads();
#pragma unroll 4
  for (int i = 0; i < kCHUNK / 256; i++) {
    int e = base + i * 256 + t;
    if (e < E) {
      int c = col[e];
      int pos = atomicAdd(&hist[c >> 6], 1);  // LDS-only cursor
      edg[pos] = ((unsigned)row[e] << 6) | (unsigned)(c & 63);
    }
  }
}

// Pass C: per-bucket re-sort into exact per-node CSR; emits per-node degree + starts + dis.
__global__ __launch_bounds__(256) void k_passC(const unsigned* __restrict__ edg,
                                               const int* __restrict__ bstarts,
                                               int* __restrict__ deg, int* __restrict__ nstarts,
                                               float* __restrict__ dis,
                                               int* __restrict__ srow, int N) {
  __shared__ int ldeg[64];
  __shared__ int lcur[64];
  int b = blockIdx.x, t = threadIdx.x;
  int s0 = bstarts[b * 8], s1 = bstarts[b * 8 + 8];
  if (t < 64) ldeg[t] = 0;
  __syncthreads();
  for (int i = s0 + t; i < s1; i += 256) atomicAdd(&ldeg[edg[i] & 63u], 1);
  __syncthreads();
  if (t < 64) {
    int own = ldeg[t];
    int incl = own;
#pragma unroll
    for (int off = 1; off < 64; off <<= 1) {
      int o = __shfl_up(incl, off);
      if (t >= off) incl += o;
    }
    int st = s0 + incl - own;
    lcur[t] = st;
    int g = b * 64 + t;
    if (g < N) {
      deg[g] = own;
      nstarts[g] = st;
      dis[g] = rsqrtf((float)(own + 1));
    }
  }
  __syncthreads();
  for (int i = s0 + t; i < s1; i += 256) {
    unsigned ew = edg[i];
    int pos = atomicAdd(&lcur[ew & 63u], 1);
    srow[pos] = (int)(ew >> 6);
  }
}

// ---------------- cluster graph: small CSR path ----------------
__global__ void k_hist(const int* __restrict__ col, int E, int* __restrict__ cnt) {
  int i = blockIdx.x * blockDim.x + threadIdx.x;
  if (i < E) atomicAdd(&cnt[col[i]], 1);
}

__global__ void k_dis(const int* __restrict__ cnt, int N, float* __restrict__ dis) {
  int i = blockIdx.x * blockDim.x + threadIdx.x;
  if (i < N) dis[i] = rsqrtf((float)(cnt[i] + 1));
}

__global__ void k_scan1(const int* __restrict__ cnt, int N, int* __restrict__ starts, int* __restrict__ bsum) {
  __shared__ int s[256];
  int t = threadIdx.x;
  int i = blockIdx.x * 256 + t;
  int v = (i < N) ? cnt[i] : 0;
  s[t] = v;
  __syncthreads();
  for (int o = 1; o < 256; o <<= 1) {
    int x = (t >= o) ? s[t - o] : 0;
    __syncthreads();
    s[t] += x;
    __syncthreads();
  }
  if (i < N) starts[i] = s[t] - v;
  if (t == 255) bsum[blockIdx.x] = s[255];
}

__global__ void k_scan2(int* __restrict__ bsum, int nb) {
  __shared__ int s[256];
  int t = threadIdx.x;
  int run = 0;
  for (int base = 0; base < nb; base += 256) {
    int i = base + t;
    int v = (i < nb) ? bsum[i] : 0;
    s[t] = v;
    __syncthreads();
    for (int o = 1; o < 256; o <<= 1) {
      int x = (t >= o) ? s[t - o] : 0;
      __syncthreads();
      s[t] += x;
      __syncthreads();
    }
    if (i < nb) bsum[i] = run + s[t] - v;
    int tot = s[255];
    __syncthreads();
    run += tot;
  }
}

__global__ void k_scan3(int* __restrict__ starts, int* __restrict__ cursor, const int* __restrict__ bsum, int N) {
  int i = blockIdx.x * 256 + threadIdx.x;
  if (i < N) {
    int v = starts[i] + bsum[blockIdx.x];
    starts[i] = v;
    cursor[i] = v;
  }
}

__global__ void k_scatter(const int* __restrict__ row, const int* __restrict__ col, int E,
                          int* __restrict__ cursor, int* __restrict__ srow) {
  int i = blockIdx.x * blockDim.x + threadIdx.x;
  if (i < E) {
    int pos = atomicAdd(&cursor[col[i]], 1);
    srow[pos] = row[i];
  }
}

// ---------------- aggregation (bf16 in/out): out[c] = relu(dis[c]*(hs[c]+sum hs[r]) + b) ----------------
template <int F>
__global__ __launch_bounds__(256) void k_agg_bf(const unsigned short* __restrict__ hs,
                                                const int* __restrict__ starts, const int* __restrict__ cnt,
                                                const int* __restrict__ srow, const float* __restrict__ dis,
                                                const float* __restrict__ b, unsigned short* __restrict__ out, int N) {
  constexpr int LPN = F / 2;
  int t = threadIdx.x;
  int c = blockIdx.x * (256 / LPN) + t / LPN;
  if (c >= N) return;
  int fi = (t % LPN) * 2;
  unsigned v = *(const unsigned*)(hs + (size_t)c * F + fi);
  float ax = bflo(v), ay = bfhi(v);
  int s0 = starts[c], n = cnt[c];
  const int* sp = srow + s0;
  int e = 0;
  for (; e + 4 <= n; e += 4) {
    int r0 = sp[e], r1 = sp[e + 1], r2 = sp[e + 2], r3 = sp[e + 3];
    unsigned v0 = *(const unsigned*)(hs + (size_t)r0 * F + fi);
    unsigned v1 = *(const unsigned*)(hs + (size_t)r1 * F + fi);
    unsigned v2 = *(const unsigned*)(hs + (size_t)r2 * F + fi);
    unsigned v3 = *(const unsigned*)(hs + (size_t)r3 * F + fi);
    ax += bflo(v0) + bflo(v1) + bflo(v2) + bflo(v3);
    ay += bfhi(v0) + bfhi(v1) + bfhi(v2) + bfhi(v3);
  }
  for (; e < n; e++) {
    unsigned vv = *(const unsigned*)(hs + (size_t)sp[e] * F + fi);
    ax += bflo(vv);
    ay += bfhi(vv);
  }
  float d = dis[c];
  float ox = fmaxf(fmaf(d, ax, b[fi]), 0.f);
  float oy = fmaxf(fmaf(d, ay, b[fi + 1]), 0.f);
  *(unsigned*)(out + (size_t)c * F + fi) = (unsigned)f2bf(ox) | ((unsigned)f2bf(oy) << 16);
}

// ---------------- layer-1 linear: hs[N,64](bf16) = (x[N,7] @ W[7,64]) * dis[row] ----------------
__global__ __launch_bounds__(256) void k_lin7(const float* __restrict__ x, const float* __restrict__ W,
                                              const float* __restrict__ dis, unsigned short* __restrict__ hs, int N) {
  __shared__ float Ws[7 * 64];
  int t = threadIdx.x;
  for (int j = t; j < 7 * 64; j += 256) Ws[j] = W[j];
  __syncthreads();
  int idx = blockIdx.x * 256 + t;
  if (idx < N * 32) {
    int r = idx >> 5, c2 = (idx & 31) * 2;
    const float* xr = x + (size_t)r * 7;
    float a0 = 0.f, a1 = 0.f;
#pragma unroll
    for (int k = 0; k < 7; k++) {
      float xv = xr[k];
      a0 = fmaf(xv, Ws[k * 64 + c2], a0);
      a1 = fmaf(xv, Ws[k * 64 + c2 + 1], a1);
    }
    float d = dis[r];
    unsigned pk = (unsigned)f2bf(a0 * d) | ((unsigned)f2bf(a1 * d) << 16);
    *(unsigned*)(hs + (size_t)r * 64 + c2) = pk;
  }
}

// ---------------- layer-2 linear: 32 rows/block: hs2[N,128] = (xin[N,64] @ W[64,128]) * dis ----------------
__global__ __launch_bounds__(256) void k_lin64x128(const unsigned short* __restrict__ xin, const float* __restrict__ W,
                                                   const float* __restrict__ dis, unsigned short* __restrict__ hs, int N) {
  __shared__ float Ws[64 * 128];
  __shared__ float xs[32][64];
  int t = threadIdx.x;
  for (int j = t; j < 64 * 128; j += 256) Ws[j] = W[j];
  int r0 = blockIdx.x * 32;
  for (int j = t; j < 32 * 64; j += 256) {
    int r = j >> 6, k = j & 63;
    int gr = r0 + r;
    xs[r][k] = (gr < N) ? bf2f(xin[(size_t)gr * 64 + k]) : 0.f;
  }
  __syncthreads();
  int c = t & 63;            // cols c and c+64
  int rb = (t >> 6) * 8;     // 4 groups x 8 rows
  float a0[8], a1[8];
#pragma unroll
  for (int rr = 0; rr < 8; rr++) { a0[rr] = 0.f; a1[rr] = 0.f; }
  for (int k = 0; k < 64; k++) {
    float w0 = Ws[k * 128 + c];
    float w1 = Ws[k * 128 + c + 64];
#pragma unroll
    for (int rr = 0; rr < 8; rr++) {
      float xv = xs[rb + rr][k];
      a0[rr] = fmaf(xv, w0, a0[rr]);
      a1[rr] = fmaf(xv, w1, a1[rr]);
    }
  }
#pragma unroll
  for (int rr = 0; rr < 8; rr++) {
    int gr = r0 + rb + rr;
    if (gr < N) {
      float d = dis[gr];
      hs[(size_t)gr * 128 + c] = f2bf(a0[rr] * d);
      hs[(size_t)gr * 128 + c + 64] = f2bf(a1[rr] * d);
    }
  }
}

// ---------------- B-operand fragment packers (NF fragments per k-step of 32) ----------------
__global__ void k_pack_b_bf16src(const unsigned short* __restrict__ src, short* __restrict__ dst, int K) {
  int e = blockIdx.x * 256 + threadIdx.x;
  if (e >= K * 128) return;
  int k = e >> 7, n = e & 127;
  int frag = (k >> 5) * 8 + (n >> 4);
  int l = (n & 15) | (((k >> 3) & 3) << 4);
  int j = k & 7;
  dst[(size_t)frag * 512 + l * 8 + j] = (short)src[e];
}
__global__ void k_pack_b_f32src(const float* __restrict__ src, short* __restrict__ dst, int K) {
  int e = blockIdx.x * 256 + threadIdx.x;
  if (e >= K * 128) return;
  int k = e >> 7, n = e & 127;
  int frag = (k >> 5) * 8 + (n >> 4);
  int l = (n & 15) | (((k >> 3) & 3) << 4);
  int j = k & 7;
  dst[(size_t)frag * 512 + l * 8 + j] = (short)f2bf(src[e]);
}
// head B: [128 k][80 n]: n<64 -> D1[k,n]; 64<=n<73 -> Wcls[k,n-64]; else 0. NF=5.
__global__ void k_pack_bhead(const float* __restrict__ D1, const float* __restrict__ Wcls,
                             short* __restrict__ dst) {
  int e = blockIdx.x * 256 + threadIdx.x;
  if (e >= 128 * 80) return;
  int k = e / 80, n = e % 80;
  float v = 0.f;
  if (n < 64) v = D1[k * 64 + n];
  else if (n < 73) v = Wcls[k * 9 + (n - 64)];
  int frag = (k >> 5) * 5 + (n >> 4);
  int l = (n & 15) | (((k >> 3) & 3) << 4);
  int j = k & 7;
  dst[(size_t)frag * 512 + l * 8 + j] = (short)f2bf(v);
}

__device__ __forceinline__ short8 zero8() {
  short8 z;
#pragma unroll
  for (int j = 0; j < 8; j++) z[j] = 0;
  return z;
}

__device__ __forceinline__ short8 load_a_f32(const float* p, bool ok) {
  short8 r;
  if (ok) {
    float4 v0 = *(const float4*)p;
    float4 v1 = *(const float4*)(p + 4);
    r[0] = (short)f2bf(v0.x); r[1] = (short)f2bf(v0.y); r[2] = (short)f2bf(v0.z); r[3] = (short)f2bf(v0.w);
    r[4] = (short)f2bf(v1.x); r[5] = (short)f2bf(v1.y); r[6] = (short)f2bf(v1.z); r[7] = (short)f2bf(v1.w);
  } else {
    r = zero8();
  }
  return r;
}

// ---------------- GEMM1 (MFMA): xcdec[M,128](bf16) = Q[M,512](fp32) @ Bq ----------------
__global__ __launch_bounds__(256) void k_gemm_q_mfma(const float* __restrict__ Q, const short* __restrict__ Bp,
                                                     unsigned short* __restrict__ outb, int M) {
  int t = threadIdx.x;
  int lane = t & 63;
  int wid = t >> 6;
  int m0 = blockIdx.x * 128 + wid * 32;
  int mrow = lane & 15;
  int kg = lane >> 4;
  f32x4 acc[2][8];
#pragma unroll
  for (int mi = 0; mi < 2; mi++)
#pragma unroll
    for (int nf = 0; nf < 8; nf++) acc[mi][nf] = (f32x4){0.f, 0.f, 0.f, 0.f};
  int r0 = m0 + mrow, r1 = m0 + 16 + mrow;
  bool ok0 = r0 < M, ok1 = r1 < M;
  const float* a0p = Q + (size_t)r0 * 512 + kg * 8;
  const float* a1p = Q + (size_t)r1 * 512 + kg * 8;
  const short* bl = Bp + lane * 8;
  for (int ks = 0; ks < 16; ks++) {
    short8 a0 = load_a_f32(a0p + ks * 32, ok0);
    short8 a1 = load_a_f32(a1p + ks * 32, ok1);
    const short* bb = bl + (ks << 12);
#pragma unroll
    for (int nf = 0; nf < 8; nf++) {
      short8 b = *(const short8*)(bb + (nf << 9));
      acc[0][nf] = __builtin_amdgcn_mfma_f32_16x16x32_bf16(a0, b, acc[0][nf], 0, 0, 0);
      acc[1][nf] = __builtin_amdgcn_mfma_f32_16x16x32_bf16(a1, b, acc[1][nf], 0, 0, 0);
    }
  }
  int col = lane & 15;
  int g = lane >> 4;
#pragma unroll
  for (int mi = 0; mi < 2; mi++)
#pragma unroll
    for (int nf = 0; nf < 8; nf++)
#pragma unroll
      for (int r = 0; r < 4; r++) {
        int row = m0 + mi * 16 + g * 4 + r;
        if (row < M) outb[(size_t)row * 128 + nf * 16 + col] = f2bf(acc[mi][nf][r]);
      }
}

// ---------------- GEMM2 (MFMA) + gate epilogue ----------------
__global__ __launch_bounds__(256) void k_gemm_fuse_mfma(const unsigned short* __restrict__ Xs,
                                                        const unsigned short* __restrict__ Xc,
                                                        const short* __restrict__ A1p, const float* __restrict__ ab1,
                                                        const float* __restrict__ A2, const float* __restrict__ ab2,
                                                        float* __restrict__ fused, int M) {
  int t = threadIdx.x;
  int lane = t & 63;
  int wid = t >> 6;
  int m0 = blockIdx.x * 128 + wid * 32;
  int mrow = lane & 15;
  int kg = lane >> 4;
  f32x4 acc[2][8];
#pragma unroll
  for (int mi = 0; mi < 2; mi++)
#pragma unroll
    for (int nf = 0; nf < 8; nf++) acc[mi][nf] = (f32x4){0.f, 0.f, 0.f, 0.f};
  int r0 = m0 + mrow, r1 = m0 + 16 + mrow;
  bool ok0 = r0 < M, ok1 = r1 < M;
  const short* bl = A1p + lane * 8;
  for (int ks = 0; ks < 8; ks++) {
    const unsigned short* src = (ks < 4) ? Xs : Xc;
    int kb = (ks & 3) * 32 + kg * 8;
    short8 a0 = ok0 ? *(const short8*)(src + (size_t)r0 * 128 + kb) : zero8();
    short8 a1 = ok1 ? *(const short8*)(src + (size_t)r1 * 128 + kb) : zero8();
    const short* bb = bl + (ks << 12);
#pragma unroll
    for (int nf = 0; nf < 8; nf++) {
      short8 b = *(const short8*)(bb + (nf << 9));
      acc[0][nf] = __builtin_amdgcn_mfma_f32_16x16x32_bf16(a0, b, acc[0][nf], 0, 0, 0);
      acc[1][nf] = __builtin_amdgcn_mfma_f32_16x16x32_bf16(a1, b, acc[1][nf], 0, 0, 0);
    }
  }
  int col16 = lane & 15;
  int g = lane >> 4;
  float bias[8], w20[8], w21[8];
#pragma unroll
  for (int nf = 0; nf < 8; nf++) {
    int cc = nf * 16 + col16;
    bias[nf] = ab1[cc];
    w20[nf] = A2[2 * cc];
    w21[nf] = A2[2 * cc + 1];
  }
  float b20 = ab2[0], b21 = ab2[1];
#pragma unroll
  for (int mi = 0; mi < 2; mi++) {
#pragma unroll
    for (int r = 0; r < 4; r++) {
      float u0 = 0.f, u1 = 0.f;
#pragma unroll
      for (int nf = 0; nf < 8; nf++) {
        float tv = fmaxf(acc[mi][nf][r] + bias[nf], 0.f);
        u0 = fmaf(tv, w20[nf], u0);
        u1 = fmaf(tv, w21[nf], u1);
      }
#pragma unroll
      for (int off = 1; off < 16; off <<= 1) {
        u0 += __shfl_xor(u0, off);
        u1 += __shfl_xor(u1, off);
      }
      int row = m0 + mi * 16 + g * 4 + r;
      if (row < M) {
        float ua = u0 + b20, ub = u1 + b21;
        float mx = fmaxf(ua, ub);
        float e0 = __expf(ua - mx), e1 = __expf(ub - mx);
        float inv = 1.f / (e0 + e1);
        float w0 = e0 * inv, w1 = e1 * inv;
        int p = col16;
        const unsigned short* xsp = Xs + (size_t)row * 128 + p * 8;
        const unsigned short* xcp = Xc + (size_t)row * 128 + p * 8;
        float* op = fused + (size_t)row * 128 + p * 8;
        float4 o0, o1;
        unsigned sx0 = *(const unsigned*)(xsp + 0), sx1 = *(const unsigned*)(xsp + 2);
        unsigned sx2 = *(const unsigned*)(xsp + 4), sx3 = *(const unsigned*)(xsp + 6);
        unsigned cx0 = *(const unsigned*)(xcp + 0), cx1 = *(const unsigned*)(xcp + 2);
        unsigned cx2 = *(const unsigned*)(xcp + 4), cx3 = *(const unsigned*)(xcp + 6);
        o0.x = w0 * bflo(sx0) + w1 * bflo(cx0);
        o0.y = w0 * bfhi(sx0) + w1 * bfhi(cx0);
        o0.z = w0 * bflo(sx1) + w1 * bflo(cx1);
        o0.w = w0 * bfhi(sx1) + w1 * bfhi(cx1);
        o1.x = w0 * bflo(sx2) + w1 * bflo(cx2);
        o1.y = w0 * bfhi(sx2) + w1 * bfhi(cx2);
        o1.z = w0 * bflo(sx3) + w1 * bflo(cx3);
        o1.w = w0 * bfhi(sx3) + w1 * bfhi(cx3);
        *(float4*)op = o0;
        *(float4*)(op + 4) = o1;
      }
    }
  }
}

// ---------------- heads (MFMA): [class | domain] from fused[M,128] ----------------
// Bh[128x80]: n<64 = D1, 64..72 = Wcls. hidden=relu(.+db1); dom = hidden@D2+db2; class += bcls.
__global__ __launch_bounds__(256) void k_final_mfma(const float* __restrict__ fused, const short* __restrict__ Bh,
                                                    const float* __restrict__ bcls, const float* __restrict__ db1,
                                                    const float* __restrict__ D2, const float* __restrict__ db2,
                                                    float* __restrict__ cls_out, float* __restrict__ dom_out, int M) {
  int t = threadIdx.x;
  int lane = t & 63;
  int wid = t >> 6;
  int m0 = blockIdx.x * 128 + wid * 32;
  int mrow = lane & 15;
  int kg = lane >> 4;
  f32x4 acc[2][5];
#pragma unroll
  for (int mi = 0; mi < 2; mi++)
#pragma unroll
    for (int nf = 0; nf < 5; nf++) acc[mi][nf] = (f32x4){0.f, 0.f, 0.f, 0.f};
  int r0 = m0 + mrow, r1 = m0 + 16 + mrow;
  bool ok0 = r0 < M, ok1 = r1 < M;
  const float* a0p = fused + (size_t)r0 * 128 + kg * 8;
  const float* a1p = fused + (size_t)r1 * 128 + kg * 8;
  const short* bl = Bh + lane * 8;
  for (int ks = 0; ks < 4; ks++) {
    short8 a0 = load_a_f32(a0p + ks * 32, ok0);
    short8 a1 = load_a_f32(a1p + ks * 32, ok1);
    const short* bb = bl + ks * 5 * 512;
#pragma unroll
    for (int nf = 0; nf < 5; nf++) {
      short8 b = *(const short8*)(bb + (nf << 9));
      acc[0][nf] = __builtin_amdgcn_mfma_f32_16x16x32_bf16(a0, b, acc[0][nf], 0, 0, 0);
      acc[1][nf] = __builtin_amdgcn_mfma_f32_16x16x32_bf16(a1, b, acc[1][nf], 0, 0, 0);
    }
  }
  int col16 = lane & 15;
  int g = lane >> 4;
  float bh[4], d20[4], d21[4];
#pragma unroll
  for (int nf = 0; nf < 4; nf++) {
    int h = col16 + 16 * nf;
    bh[nf] = db1[h];
    d20[nf] = D2[h * 2];
    d21[nf] = D2[h * 2 + 1];
  }
  float bc = (col16 < 9) ? bcls[col16] : 0.f;
  float b20 = db2[0], b21 = db2[1];
#pragma unroll
  for (int mi = 0; mi < 2; mi++) {
#pragma unroll
    for (int r = 0; r < 4; r++) {
      float p0 = 0.f, p1 = 0.f;
#pragma unroll
      for (int nf = 0; nf < 4; nf++) {
        float hv = fmaxf(acc[mi][nf][r] + bh[nf], 0.f);
        p0 = fmaf(hv, d20[nf], p0);
        p1 = fmaf(hv, d21[nf], p1);
      }
#pragma unroll
      for (int off = 1; off < 16; off <<= 1) {
        p0 += __shfl_xor(p0, off);
        p1 += __shfl_xor(p1, off);
      }
      int row = m0 + mi * 16 + g * 4 + r;
      if (row < M) {
        if (col16 < 9) cls_out[(size_t)row * 9 + col16] = acc[mi][4][r] + bc;
        if (col16 == 0) {
          dom_out[(size_t)row * 2 + 0] = p0 + b20;
          dom_out[(size_t)row * 2 + 1] = p1 + b21;
        }
      }
    }
  }
}

extern "C" void kernel_launch(void* const* d_in, const int* in_sizes, int n_in,
                              void* d_out, int out_size, void* d_ws, size_t ws_size,
                              hipStream_t stream) {
  const float* x_s = (const float*)d_in[0];
  const float* x_c = (const float*)d_in[1];
  const float* Q = (const float*)d_in[2];
  const int* eis = (const int*)d_in[3];
  const int* eic = (const int*)d_in[4];
  const float* W1s = (const float*)d_in[5];
  const float* b1s = (const float*)d_in[6];
  const float* W2s = (const float*)d_in[7];
  const float* b2s = (const float*)d_in[8];
  const float* W1c = (const float*)d_in[9];
  const float* b1c = (const float*)d_in[10];
  const float* W2c = (const float*)d_in[11];
  const float* b2c = (const float*)d_in[12];
  const float* A1 = (const float*)d_in[13];
  const float* ab1 = (const float*)d_in[14];
  const float* A2 = (const float*)d_in[15];
  const float* ab2 = (const float*)d_in[16];
  const float* Wcls = (const float*)d_in[17];
  const float* bcls = (const float*)d_in[18];
  const float* D1 = (const float*)d_in[19];
  const float* db1 = (const float*)d_in[20];
  const float* D2 = (const float*)d_in[21];
  const float* db2 = (const float*)d_in[22];

  float* out_cls = (float*)d_out;
  float* out_dom = out_cls + (size_t)kNS * 9;
  float* out_fus = out_dom + (size_t)kNS * 2;

  char* p = (char*)d_ws;
  auto alloc = [&](size_t bytes) -> void* {
    void* r = (void*)p;
    p += (bytes + 255) & ~(size_t)255;
    return r;
  };
  // sample graph
  int* deg_s = (int*)alloc((size_t)kNS * 4);
  float* dis_s = (float*)alloc((size_t)kNS * 4);
  int* nstarts_s = (int*)alloc((size_t)kNS * 4);
  int* counts_s = (int*)alloc((size_t)kNB8 * 4);
  int* bstarts_s = (int*)alloc((size_t)(kNB8 + 1) * 4);
  int* bcursor_s = (int*)alloc((size_t)kNB8 * 4);
  // cluster graph
  int* deg_c = (int*)alloc((size_t)kNC * 4);
  int* cstarts_c = (int*)alloc((size_t)kNC * 4);
  int* cursor_c = (int*)alloc((size_t)kNC * 4);
  int* bsum_c = (int*)alloc(512 * 4);
  float* dis_c = (float*)alloc((size_t)kNC * 4);
  int* srow_c = (int*)alloc((size_t)kEC * 4);
  // feature buffers (bf16)
  unsigned short* hc1b = (unsigned short*)alloc((size_t)kNC * 64 * 2);
  unsigned short* xc1b = (unsigned short*)alloc((size_t)kNC * 64 * 2);
  unsigned short* hc2b = (unsigned short*)alloc((size_t)kNC * 128 * 2);
  unsigned short* xc2b = (unsigned short*)alloc((size_t)kNC * 128 * 2);
  unsigned short* hs1b = (unsigned short*)alloc((size_t)kNS * 64 * 2);
  unsigned short* xs1b = (unsigned short*)alloc((size_t)kNS * 64 * 2);
  unsigned short* hs2b = (unsigned short*)alloc((size_t)kNS * 128 * 2);
  unsigned short* xs2b = (unsigned short*)alloc((size_t)kNS * 128 * 2);
  unsigned short* xcdb = (unsigned short*)alloc((size_t)kNS * 128 * 2);
  short* Bq = (short*)alloc((size_t)512 * 128 * 2);
  short* A1p = (short*)alloc((size_t)256 * 128 * 2);
  short* Bh = (short*)alloc((size_t)128 * 80 * 2);
  // aliases (lifetimes disjoint along stream order):
  unsigned* edg_s = (unsigned*)hs2b;  // passB->passC; hs2b written later
  int* srow_s = (int*)xcdb;           // passC->agg128; xcdb written later (gemm_q)
  (void)ws_size; (void)in_sizes; (void)n_in; (void)out_size;

  hipMemsetAsync(counts_s, 0, (size_t)kNB8 * 4, stream);
  hipMemsetAsync(deg_c, 0, (size_t)kNC * 4, stream);

  const int nbC = (kNC + 255) / 256;

  // sample-graph grouping: bucket histogram -> scan -> reserved append -> per-node re-sort
  k_passA<<<kNBLK, 256, 0, stream>>>(eis + kES, kES, counts_s);
  k_scan_flat<<<1, 256, 0, stream>>>(counts_s, kNB8, bstarts_s, bcursor_s);
  k_passB<<<kNBLK, 256, 0, stream>>>(eis, eis + kES, kES, bcursor_s, edg_s);
  k_passC<<<kNB, 256, 0, stream>>>(edg_s, bstarts_s, deg_s, nstarts_s, dis_s, srow_s, kNS);

  // cluster-graph CSR
  k_hist<<<(kEC + 255) / 256, 256, 0, stream>>>(eic + kEC, kEC, deg_c);
  k_dis<<<nbC, 256, 0, stream>>>(deg_c, kNC, dis_c);
  k_scan1<<<nbC, 256, 0, stream>>>(deg_c, kNC, cstarts_c, bsum_c);
  k_scan2<<<1, 256, 0, stream>>>(bsum_c, nbC);
  k_scan3<<<nbC, 256, 0, stream>>>(cstarts_c, cursor_c, bsum_c, kNC);
  k_scatter<<<(kEC + 255) / 256, 256, 0, stream>>>(eic, eic + kEC, kEC, cursor_c, srow_c);

  // pack A1 + head B (independent)
  k_pack_b_f32src<<<(256 * 128 + 255) / 256, 256, 0, stream>>>(A1, A1p, 256);
  k_pack_bhead<<<(128 * 80 + 255) / 256, 256, 0, stream>>>(D1, Wcls, Bh);

  // cluster branch
  k_lin7<<<(kNC * 32 + 255) / 256, 256, 0, stream>>>(x_c, W1c, dis_c, hc1b, kNC);
  k_agg_bf<64><<<(kNC + 7) / 8, 256, 0, stream>>>(hc1b, cstarts_c, deg_c, srow_c, dis_c, b1c, xc1b, kNC);
  k_lin64x128<<<(kNC + 31) / 32, 256, 0, stream>>>(xc1b, W2c, dis_c, hc2b, kNC);
  k_agg_bf<128><<<(kNC + 3) / 4, 256, 0, stream>>>(hc2b, cstarts_c, deg_c, srow_c, dis_c, b2c, xc2b, kNC);
  k_pack_b_bf16src<<<(512 * 128 + 255) / 256, 256, 0, stream>>>(xc2b, Bq, 512);

  // sample branch
  k_lin7<<<(kNS * 32 + 255) / 256, 256, 0, stream>>>(x_s, W1s, dis_s, hs1b, kNS);
  k_agg_bf<64><<<(kNS + 7) / 8, 256, 0, stream>>>(hs1b, nstarts_s, deg_s, srow_s, dis_s, b1s, xs1b, kNS);
  k_lin64x128<<<(kNS + 31) / 32, 256, 0, stream>>>(xs1b, W2s, dis_s, hs2b, kNS);
  k_agg_bf<128><<<(kNS + 3) / 4, 256, 0, stream>>>(hs2b, nstarts_s, deg_s, srow_s, dis_s, b2s, xs2b, kNS);

  // decode + fusion gate + heads
  k_gemm_q_mfma<<<(kNS + 127) / 128, 256, 0, stream>>>(Q, Bq, xcdb, kNS);
  k_gemm_fuse_mfma<<<(kNS + 127) / 128, 256, 0, stream>>>(xs2b, xcdb, A1p, ab1, A2, ab2, out_fus, kNS);
  k_final_mfma<<<(kNS + 127) / 128, 256, 0, stream>>>(out_fus, Bh, bcls, db1, D2, db2, out_cls, out_dom, kNS);
}

// Round 7
// 586.233 us; speedup vs baseline: 7.6009x; 1.0621x over previous
//
#include <hip/hip_runtime.h>
#include <cstdint>
#include <cstddef>

static constexpr int kNS = 100000;
static constexpr int kNC = 512;
static constexpr int kES = 3200000;
static constexpr int kEC = 16384;

static constexpr int kNB = (kNS + 63) / 64;        // 1563 coarse buckets (64 nodes each)
static constexpr int kNB8 = kNB * 8;               // sub-bucketed counters
static constexpr int kCHUNK = 8192;                // edges per block in passA/passB
static constexpr int kNBLK = (kES + kCHUNK - 1) / kCHUNK;  // 391 blocks

typedef __attribute__((ext_vector_type(8))) short short8;
typedef __attribute__((ext_vector_type(4))) float f32x4;

__device__ __forceinline__ unsigned short f2bf(float f) {
  union { float f; unsigned u; } v; v.f = f;
  unsigned u = v.u;
  unsigned r = (u + 0x7fffu + ((u >> 16) & 1u)) >> 16;
  return (unsigned short)r;
}
__device__ __forceinline__ float bflo(unsigned v) { return __uint_as_float(v << 16); }
__device__ __forceinline__ float bfhi(unsigned v) { return __uint_as_float(v & 0xffff0000u); }
__device__ __forceinline__ float bf2f(unsigned short s) { return __uint_as_float(((unsigned)s) << 16); }

// ---------------- sample graph: bucket histogram (1 global atomic per touched bucket) ----------------
__global__ __launch_bounds__(256) void k_passA(const int* __restrict__ col, int E,
                                               int* __restrict__ counts) {
  __shared__ int hist[kNB];
  int t = threadIdx.x, bid = blockIdx.x;
  for (int j = t; j < kNB; j += 256) hist[j] = 0;
  __syncthreads();
  int base = bid * kCHUNK;
#pragma unroll 4
  for (int i = 0; i < kCHUNK / 256; i++) {
    int e = base + i * 256 + t;
    if (e < E) atomicAdd(&hist[col[e] >> 6], 1);
  }
  __syncthreads();
  int sub = bid & 7;
  for (int j = t; j < kNB; j += 256) {
    int v = hist[j];
    if (v) atomicAdd(&counts[j * 8 + sub], v);
  }
}

// exclusive scan of n flat counters -> starts[n+1], cursor copy
__global__ void k_scan_flat(const int* __restrict__ cnt, int n, int* __restrict__ starts,
                            int* __restrict__ cursor) {
  __shared__ int s[256];
  int t = threadIdx.x;
  int run = 0;
  for (int base = 0; base < n; base += 256) {
    int i = base + t;
    int v = (i < n) ? cnt[i] : 0;
    s[t] = v;
    __syncthreads();
    for (int o = 1; o < 256; o <<= 1) {
      int x = (t >= o) ? s[t - o] : 0;
      __syncthreads();
      s[t] += x;
      __syncthreads();
    }
    if (i < n) {
      int ex = run + s[t] - v;
      starts[i] = ex;
      cursor[i] = ex;
    }
    int tot = s[255];
    __syncthreads();
    run += tot;
  }
  if (t == 0) starts[n] = run;
}

// Pass B: LDS-hist -> per-bucket range reservation (1 global atomic each) -> LDS-cursor append.
__global__ __launch_bounds__(256) void k_passB(const int* __restrict__ row, const int* __restrict__ col,
                                               int E, int* __restrict__ cursor, unsigned* __restrict__ edg) {
  __shared__ int hist[kNB];
  int t = threadIdx.x, bid = blockIdx.x;
  int sub = bid & 7;
  for (int j = t; j < kNB; j += 256) hist[j] = 0;
  __syncthreads();
  int base = bid * kCHUNK;
#pragma unroll 4
  for (int i = 0; i < kCHUNK / 256; i++) {
    int e = base + i * 256 + t;
    if (e < E) atomicAdd(&hist[col[e] >> 6], 1);
  }
  __syncthreads();
  for (int j = t; j < kNB; j += 256) {
    int v = hist[j];
    hist[j] = v ? atomicAdd(&cursor[j * 8 + sub], v) : 0;  // becomes this block's run start
  }
  __syncthreads();
#pragma unroll 4
  for (int i = 0; i < kCHUNK / 256; i++) {
    int e = base + i * 256 + t;
    if (e < E) {
      int c = col[e];
      int pos = atomicAdd(&hist[c >> 6], 1);  // LDS-only cursor
      edg[pos] = ((unsigned)row[e] << 6) | (unsigned)(c & 63);
    }
  }
}

// Pass C: per-bucket re-sort into exact per-node CSR; emits per-node degree + starts + dis.
__global__ __launch_bounds__(256) void k_passC(const unsigned* __restrict__ edg,
                                               const int* __restrict__ bstarts,
                                               int* __restrict__ deg, int* __restrict__ nstarts,
                                               float* __restrict__ dis,
                                               int* __restrict__ srow, int N) {
  __shared__ int ldeg[64];
  __shared__ int lcur[64];
  int b = blockIdx.x, t = threadIdx.x;
  int s0 = bstarts[b * 8], s1 = bstarts[b * 8 + 8];
  if (t < 64) ldeg[t] = 0;
  __syncthreads();
  for (int i = s0 + t; i < s1; i += 256) atomicAdd(&ldeg[edg[i] & 63u], 1);
  __syncthreads();
  if (t < 64) {
    int own = ldeg[t];
    int incl = own;
#pragma unroll
    for (int off = 1; off < 64; off <<= 1) {
      int o = __shfl_up(incl, off);
      if (t >= off) incl += o;
    }
    int st = s0 + incl - own;
    lcur[t] = st;
    int g = b * 64 + t;
    if (g < N) {
      deg[g] = own;
      nstarts[g] = st;
      dis[g] = rsqrtf((float)(own + 1));
    }
  }
  __syncthreads();
  for (int i = s0 + t; i < s1; i += 256) {
    unsigned ew = edg[i];
    int pos = atomicAdd(&lcur[ew & 63u], 1);
    srow[pos] = (int)(ew >> 6);
  }
}

// ---------------- cluster graph: small CSR path ----------------
__global__ void k_hist(const int* __restrict__ col, int E, int* __restrict__ cnt) {
  int i = blockIdx.x * blockDim.x + threadIdx.x;
  if (i < E) atomicAdd(&cnt[col[i]], 1);
}

__global__ void k_dis(const int* __restrict__ cnt, int N, float* __restrict__ dis) {
  int i = blockIdx.x * blockDim.x + threadIdx.x;
  if (i < N) dis[i] = rsqrtf((float)(cnt[i] + 1));
}

__global__ void k_scan1(const int* __restrict__ cnt, int N, int* __restrict__ starts, int* __restrict__ bsum) {
  __shared__ int s[256];
  int t = threadIdx.x;
  int i = blockIdx.x * 256 + t;
  int v = (i < N) ? cnt[i] : 0;
  s[t] = v;
  __syncthreads();
  for (int o = 1; o < 256; o <<= 1) {
    int x = (t >= o) ? s[t - o] : 0;
    __syncthreads();
    s[t] += x;
    __syncthreads();
  }
  if (i < N) starts[i] = s[t] - v;
  if (t == 255) bsum[blockIdx.x] = s[255];
}

__global__ void k_scan2(int* __restrict__ bsum, int nb) {
  __shared__ int s[256];
  int t = threadIdx.x;
  int run = 0;
  for (int base = 0; base < nb; base += 256) {
    int i = base + t;
    int v = (i < nb) ? bsum[i] : 0;
    s[t] = v;
    __syncthreads();
    for (int o = 1; o < 256; o <<= 1) {
      int x = (t >= o) ? s[t - o] : 0;
      __syncthreads();
      s[t] += x;
      __syncthreads();
    }
    if (i < nb) bsum[i] = run + s[t] - v;
    int tot = s[255];
    __syncthreads();
    run += tot;
  }
}

__global__ void k_scan3(int* __restrict__ starts, int* __restrict__ cursor, const int* __restrict__ bsum, int N) {
  int i = blockIdx.x * 256 + threadIdx.x;
  if (i < N) {
    int v = starts[i] + bsum[blockIdx.x];
    starts[i] = v;
    cursor[i] = v;
  }
}

__global__ void k_scatter(const int* __restrict__ row, const int* __restrict__ col, int E,
                          int* __restrict__ cursor, int* __restrict__ srow) {
  int i = blockIdx.x * blockDim.x + threadIdx.x;
  if (i < E) {
    int pos = atomicAdd(&cursor[col[i]], 1);
    srow[pos] = row[i];
  }
}

// ---------------- aggregation (bf16 in/out): out[c] = relu(dis[c]*(hs[c]+sum hs[r]) + b) ----------------
template <int F>
__global__ __launch_bounds__(256) void k_agg_bf(const unsigned short* __restrict__ hs,
                                                const int* __restrict__ starts, const int* __restrict__ cnt,
                                                const int* __restrict__ srow, const float* __restrict__ dis,
                                                const float* __restrict__ b, unsigned short* __restrict__ out, int N) {
  constexpr int LPN = F / 2;
  int t = threadIdx.x;
  int c = blockIdx.x * (256 / LPN) + t / LPN;
  if (c >= N) return;
  int fi = (t % LPN) * 2;
  unsigned v = *(const unsigned*)(hs + (size_t)c * F + fi);
  float ax = bflo(v), ay = bfhi(v);
  int s0 = starts[c], n = cnt[c];
  const int* sp = srow + s0;
  int e = 0;
  for (; e + 8 <= n; e += 8) {
    int r0 = sp[e], r1 = sp[e + 1], r2 = sp[e + 2], r3 = sp[e + 3];
    int r4 = sp[e + 4], r5 = sp[e + 5], r6 = sp[e + 6], r7 = sp[e + 7];
    unsigned v0 = *(const unsigned*)(hs + (size_t)r0 * F + fi);
    unsigned v1 = *(const unsigned*)(hs + (size_t)r1 * F + fi);
    unsigned v2 = *(const unsigned*)(hs + (size_t)r2 * F + fi);
    unsigned v3 = *(const unsigned*)(hs + (size_t)r3 * F + fi);
    unsigned v4 = *(const unsigned*)(hs + (size_t)r4 * F + fi);
    unsigned v5 = *(const unsigned*)(hs + (size_t)r5 * F + fi);
    unsigned v6 = *(const unsigned*)(hs + (size_t)r6 * F + fi);
    unsigned v7 = *(const unsigned*)(hs + (size_t)r7 * F + fi);
    ax += bflo(v0) + bflo(v1) + bflo(v2) + bflo(v3) + bflo(v4) + bflo(v5) + bflo(v6) + bflo(v7);
    ay += bfhi(v0) + bfhi(v1) + bfhi(v2) + bfhi(v3) + bfhi(v4) + bfhi(v5) + bfhi(v6) + bfhi(v7);
  }
  for (; e + 4 <= n; e += 4) {
    int r0 = sp[e], r1 = sp[e + 1], r2 = sp[e + 2], r3 = sp[e + 3];
    unsigned v0 = *(const unsigned*)(hs + (size_t)r0 * F + fi);
    unsigned v1 = *(const unsigned*)(hs + (size_t)r1 * F + fi);
    unsigned v2 = *(const unsigned*)(hs + (size_t)r2 * F + fi);
    unsigned v3 = *(const unsigned*)(hs + (size_t)r3 * F + fi);
    ax += bflo(v0) + bflo(v1) + bflo(v2) + bflo(v3);
    ay += bfhi(v0) + bfhi(v1) + bfhi(v2) + bfhi(v3);
  }
  for (; e < n; e++) {
    unsigned vv = *(const unsigned*)(hs + (size_t)sp[e] * F + fi);
    ax += bflo(vv);
    ay += bfhi(vv);
  }
  float d = dis[c];
  float ox = fmaxf(fmaf(d, ax, b[fi]), 0.f);
  float oy = fmaxf(fmaf(d, ay, b[fi + 1]), 0.f);
  *(unsigned*)(out + (size_t)c * F + fi) = (unsigned)f2bf(ox) | ((unsigned)f2bf(oy) << 16);
}

// ---------------- layer-1 linear: hs[N,64](bf16) = (x[N,7] @ W[7,64]) * dis[row] ----------------
__global__ __launch_bounds__(256) void k_lin7(const float* __restrict__ x, const float* __restrict__ W,
                                              const float* __restrict__ dis, unsigned short* __restrict__ hs, int N) {
  __shared__ float Ws[7 * 64];
  int t = threadIdx.x;
  for (int j = t; j < 7 * 64; j += 256) Ws[j] = W[j];
  __syncthreads();
  int idx = blockIdx.x * 256 + t;
  if (idx < N * 32) {
    int r = idx >> 5, c2 = (idx & 31) * 2;
    const float* xr = x + (size_t)r * 7;
    float a0 = 0.f, a1 = 0.f;
#pragma unroll
    for (int k = 0; k < 7; k++) {
      float xv = xr[k];
      a0 = fmaf(xv, Ws[k * 64 + c2], a0);
      a1 = fmaf(xv, Ws[k * 64 + c2 + 1], a1);
    }
    float d = dis[r];
    unsigned pk = (unsigned)f2bf(a0 * d) | ((unsigned)f2bf(a1 * d) << 16);
    *(unsigned*)(hs + (size_t)r * 64 + c2) = pk;
  }
}

// ---------------- layer-2 linear: 32 rows/block: hs2[N,128] = (xin[N,64] @ W[64,128]) * dis ----------------
__global__ __launch_bounds__(256) void k_lin64x128(const unsigned short* __restrict__ xin, const float* __restrict__ W,
                                                   const float* __restrict__ dis, unsigned short* __restrict__ hs, int N) {
  __shared__ float Ws[64 * 128];
  __shared__ float xs[32][64];
  int t = threadIdx.x;
  for (int j = t; j < 64 * 128; j += 256) Ws[j] = W[j];
  int r0 = blockIdx.x * 32;
  for (int j = t; j < 32 * 64; j += 256) {
    int r = j >> 6, k = j & 63;
    int gr = r0 + r;
    xs[r][k] = (gr < N) ? bf2f(xin[(size_t)gr * 64 + k]) : 0.f;
  }
  __syncthreads();
  int c = t & 63;            // cols c and c+64
  int rb = (t >> 6) * 8;     // 4 groups x 8 rows
  float a0[8], a1[8];
#pragma unroll
  for (int rr = 0; rr < 8; rr++) { a0[rr] = 0.f; a1[rr] = 0.f; }
  for (int k = 0; k < 64; k++) {
    float w0 = Ws[k * 128 + c];
    float w1 = Ws[k * 128 + c + 64];
#pragma unroll
    for (int rr = 0; rr < 8; rr++) {
      float xv = xs[rb + rr][k];
      a0[rr] = fmaf(xv, w0, a0[rr]);
      a1[rr] = fmaf(xv, w1, a1[rr]);
    }
  }
#pragma unroll
  for (int rr = 0; rr < 8; rr++) {
    int gr = r0 + rb + rr;
    if (gr < N) {
      float d = dis[gr];
      hs[(size_t)gr * 128 + c] = f2bf(a0[rr] * d);
      hs[(size_t)gr * 128 + c + 64] = f2bf(a1[rr] * d);
    }
  }
}

// ---------------- B-operand fragment packers (NF fragments per k-step of 32) ----------------
__global__ void k_pack_b_bf16src(const unsigned short* __restrict__ src, short* __restrict__ dst, int K) {
  int e = blockIdx.x * 256 + threadIdx.x;
  if (e >= K * 128) return;
  int k = e >> 7, n = e & 127;
  int frag = (k >> 5) * 8 + (n >> 4);
  int l = (n & 15) | (((k >> 3) & 3) << 4);
  int j = k & 7;
  dst[(size_t)frag * 512 + l * 8 + j] = (short)src[e];
}
__global__ void k_pack_b_f32src(const float* __restrict__ src, short* __restrict__ dst, int K) {
  int e = blockIdx.x * 256 + threadIdx.x;
  if (e >= K * 128) return;
  int k = e >> 7, n = e & 127;
  int frag = (k >> 5) * 8 + (n >> 4);
  int l = (n & 15) | (((k >> 3) & 3) << 4);
  int j = k & 7;
  dst[(size_t)frag * 512 + l * 8 + j] = (short)f2bf(src[e]);
}
// head B: [128 k][80 n]: n<64 -> D1[k,n]; 64<=n<73 -> Wcls[k,n-64]; else 0. NF=5.
__global__ void k_pack_bhead(const float* __restrict__ D1, const float* __restrict__ Wcls,
                             short* __restrict__ dst) {
  int e = blockIdx.x * 256 + threadIdx.x;
  if (e >= 128 * 80) return;
  int k = e / 80, n = e % 80;
  float v = 0.f;
  if (n < 64) v = D1[k * 64 + n];
  else if (n < 73) v = Wcls[k * 9 + (n - 64)];
  int frag = (k >> 5) * 5 + (n >> 4);
  int l = (n & 15) | (((k >> 3) & 3) << 4);
  int j = k & 7;
  dst[(size_t)frag * 512 + l * 8 + j] = (short)f2bf(v);
}

__device__ __forceinline__ short8 zero8() {
  short8 z;
#pragma unroll
  for (int j = 0; j < 8; j++) z[j] = 0;
  return z;
}

__device__ __forceinline__ short8 cvt8(float4 v0, float4 v1) {
  short8 r;
  r[0] = (short)f2bf(v0.x); r[1] = (short)f2bf(v0.y); r[2] = (short)f2bf(v0.z); r[3] = (short)f2bf(v0.w);
  r[4] = (short)f2bf(v1.x); r[5] = (short)f2bf(v1.y); r[6] = (short)f2bf(v1.z); r[7] = (short)f2bf(v1.w);
  return r;
}

__device__ __forceinline__ short8 load_a_f32(const float* p, bool ok) {
  if (!ok) return zero8();
  return cvt8(*(const float4*)p, *(const float4*)(p + 4));
}

// ---------------- GEMM1 (MFMA): xcdec[M,128](bf16) = Q[M,512](fp32) @ Bq ----------------
// 64 rows/block (16 rows/wave), register double-buffered A loads for latency hiding.
__global__ __launch_bounds__(256) void k_gemm_q_mfma(const float* __restrict__ Q, const short* __restrict__ Bp,
                                                     unsigned short* __restrict__ outb, int M) {
  int t = threadIdx.x;
  int lane = t & 63;
  int wid = t >> 6;
  int m0 = blockIdx.x * 64 + wid * 16;
  int mrow = lane & 15;
  int kg = lane >> 4;
  f32x4 acc[8];
#pragma unroll
  for (int nf = 0; nf < 8; nf++) acc[nf] = (f32x4){0.f, 0.f, 0.f, 0.f};
  int r0 = m0 + mrow;
  bool ok = r0 < M;
  const float* ap = Q + (size_t)r0 * 512 + kg * 8;
  const short* bl = Bp + lane * 8;
  float4 z4 = {0.f, 0.f, 0.f, 0.f};
  float4 v0 = ok ? *(const float4*)ap : z4;
  float4 v1 = ok ? *(const float4*)(ap + 4) : z4;
  for (int ks = 0; ks < 16; ks++) {
    float4 n0 = z4, n1 = z4;
    if (ks < 15 && ok) {
      n0 = *(const float4*)(ap + (ks + 1) * 32);
      n1 = *(const float4*)(ap + (ks + 1) * 32 + 4);
    }
    short8 a = cvt8(v0, v1);
    const short* bb = bl + (ks << 12);
#pragma unroll
    for (int nf = 0; nf < 8; nf++) {
      short8 b = *(const short8*)(bb + (nf << 9));
      acc[nf] = __builtin_amdgcn_mfma_f32_16x16x32_bf16(a, b, acc[nf], 0, 0, 0);
    }
    v0 = n0;
    v1 = n1;
  }
  int col = lane & 15;
  int g = lane >> 4;
#pragma unroll
  for (int nf = 0; nf < 8; nf++)
#pragma unroll
    for (int r = 0; r < 4; r++) {
      int row = m0 + g * 4 + r;
      if (row < M) outb[(size_t)row * 128 + nf * 16 + col] = f2bf(acc[nf][r]);
    }
}

// ---------------- GEMM2 (MFMA) + gate epilogue (64 rows/block, 16 rows/wave) ----------------
__global__ __launch_bounds__(256) void k_gemm_fuse_mfma(const unsigned short* __restrict__ Xs,
                                                        const unsigned short* __restrict__ Xc,
                                                        const short* __restrict__ A1p, const float* __restrict__ ab1,
                                                        const float* __restrict__ A2, const float* __restrict__ ab2,
                                                        float* __restrict__ fused, int M) {
  int t = threadIdx.x;
  int lane = t & 63;
  int wid = t >> 6;
  int m0 = blockIdx.x * 64 + wid * 16;
  int mrow = lane & 15;
  int kg = lane >> 4;
  f32x4 acc[8];
#pragma unroll
  for (int nf = 0; nf < 8; nf++) acc[nf] = (f32x4){0.f, 0.f, 0.f, 0.f};
  int r0 = m0 + mrow;
  bool ok = r0 < M;
  const short* bl = A1p + lane * 8;
  short8 a = ok ? *(const short8*)(Xs + (size_t)r0 * 128 + kg * 8) : zero8();
  for (int ks = 0; ks < 8; ks++) {
    short8 an = zero8();
    if (ks < 7 && ok) {
      int ks1 = ks + 1;
      const unsigned short* src = (ks1 < 4) ? Xs : Xc;
      an = *(const short8*)(src + (size_t)r0 * 128 + (ks1 & 3) * 32 + kg * 8);
    }
    const short* bb = bl + (ks << 12);
#pragma unroll
    for (int nf = 0; nf < 8; nf++) {
      short8 b = *(const short8*)(bb + (nf << 9));
      acc[nf] = __builtin_amdgcn_mfma_f32_16x16x32_bf16(a, b, acc[nf], 0, 0, 0);
    }
    a = an;
  }
  int col16 = lane & 15;
  int g = lane >> 4;
  float bias[8], w20[8], w21[8];
#pragma unroll
  for (int nf = 0; nf < 8; nf++) {
    int cc = nf * 16 + col16;
    bias[nf] = ab1[cc];
    w20[nf] = A2[2 * cc];
    w21[nf] = A2[2 * cc + 1];
  }
  float b20 = ab2[0], b21 = ab2[1];
#pragma unroll
  for (int r = 0; r < 4; r++) {
    float u0 = 0.f, u1 = 0.f;
#pragma unroll
    for (int nf = 0; nf < 8; nf++) {
      float tv = fmaxf(acc[nf][r] + bias[nf], 0.f);
      u0 = fmaf(tv, w20[nf], u0);
      u1 = fmaf(tv, w21[nf], u1);
    }
#pragma unroll
    for (int off = 1; off < 16; off <<= 1) {
      u0 += __shfl_xor(u0, off);
      u1 += __shfl_xor(u1, off);
    }
    int row = m0 + g * 4 + r;
    if (row < M) {
      float ua = u0 + b20, ub = u1 + b21;
      float mx = fmaxf(ua, ub);
      float e0 = __expf(ua - mx), e1 = __expf(ub - mx);
      float inv = 1.f / (e0 + e1);
      float w0 = e0 * inv, w1 = e1 * inv;
      int p = col16;
      const unsigned short* xsp = Xs + (size_t)row * 128 + p * 8;
      const unsigned short* xcp = Xc + (size_t)row * 128 + p * 8;
      float* op = fused + (size_t)row * 128 + p * 8;
      float4 o0, o1;
      unsigned sx0 = *(const unsigned*)(xsp + 0), sx1 = *(const unsigned*)(xsp + 2);
      unsigned sx2 = *(const unsigned*)(xsp + 4), sx3 = *(const unsigned*)(xsp + 6);
      unsigned cx0 = *(const unsigned*)(xcp + 0), cx1 = *(const unsigned*)(xcp + 2);
      unsigned cx2 = *(const unsigned*)(xcp + 4), cx3 = *(const unsigned*)(xcp + 6);
      o0.x = w0 * bflo(sx0) + w1 * bflo(cx0);
      o0.y = w0 * bfhi(sx0) + w1 * bfhi(cx0);
      o0.z = w0 * bflo(sx1) + w1 * bflo(cx1);
      o0.w = w0 * bfhi(sx1) + w1 * bfhi(cx1);
      o1.x = w0 * bflo(sx2) + w1 * bflo(cx2);
      o1.y = w0 * bfhi(sx2) + w1 * bfhi(cx2);
      o1.z = w0 * bflo(sx3) + w1 * bflo(cx3);
      o1.w = w0 * bfhi(sx3) + w1 * bfhi(cx3);
      *(float4*)op = o0;
      *(float4*)(op + 4) = o1;
    }
  }
}

// ---------------- heads (MFMA): [class | domain] from fused[M,128] ----------------
__global__ __launch_bounds__(256) void k_final_mfma(const float* __restrict__ fused, const short* __restrict__ Bh,
                                                    const float* __restrict__ bcls, const float* __restrict__ db1,
                                                    const float* __restrict__ D2, const float* __restrict__ db2,
                                                    float* __restrict__ cls_out, float* __restrict__ dom_out, int M) {
  int t = threadIdx.x;
  int lane = t & 63;
  int wid = t >> 6;
  int m0 = blockIdx.x * 128 + wid * 32;
  int mrow = lane & 15;
  int kg = lane >> 4;
  f32x4 acc[2][5];
#pragma unroll
  for (int mi = 0; mi < 2; mi++)
#pragma unroll
    for (int nf = 0; nf < 5; nf++) acc[mi][nf] = (f32x4){0.f, 0.f, 0.f, 0.f};
  int r0 = m0 + mrow, r1 = m0 + 16 + mrow;
  bool ok0 = r0 < M, ok1 = r1 < M;
  const float* a0p = fused + (size_t)r0 * 128 + kg * 8;
  const float* a1p = fused + (size_t)r1 * 128 + kg * 8;
  const short* bl = Bh + lane * 8;
  for (int ks = 0; ks < 4; ks++) {
    short8 a0 = load_a_f32(a0p + ks * 32, ok0);
    short8 a1 = load_a_f32(a1p + ks * 32, ok1);
    const short* bb = bl + ks * 5 * 512;
#pragma unroll
    for (int nf = 0; nf < 5; nf++) {
      short8 b = *(const short8*)(bb + (nf << 9));
      acc[0][nf] = __builtin_amdgcn_mfma_f32_16x16x32_bf16(a0, b, acc[0][nf], 0, 0, 0);
      acc[1][nf] = __builtin_amdgcn_mfma_f32_16x16x32_bf16(a1, b, acc[1][nf], 0, 0, 0);
    }
  }
  int col16 = lane & 15;
  int g = lane >> 4;
  float bh[4], d20[4], d21[4];
#pragma unroll
  for (int nf = 0; nf < 4; nf++) {
    int h = col16 + 16 * nf;
    bh[nf] = db1[h];
    d20[nf] = D2[h * 2];
    d21[nf] = D2[h * 2 + 1];
  }
  float bc = (col16 < 9) ? bcls[col16] : 0.f;
  float b20 = db2[0], b21 = db2[1];
#pragma unroll
  for (int mi = 0; mi < 2; mi++) {
#pragma unroll
    for (int r = 0; r < 4; r++) {
      float p0 = 0.f, p1 = 0.f;
#pragma unroll
      for (int nf = 0; nf < 4; nf++) {
        float hv = fmaxf(acc[mi][nf][r] + bh[nf], 0.f);
        p0 = fmaf(hv, d20[nf], p0);
        p1 = fmaf(hv, d21[nf], p1);
      }
#pragma unroll
      for (int off = 1; off < 16; off <<= 1) {
        p0 += __shfl_xor(p0, off);
        p1 += __shfl_xor(p1, off);
      }
      int row = m0 + mi * 16 + g * 4 + r;
      if (row < M) {
        if (col16 < 9) cls_out[(size_t)row * 9 + col16] = acc[mi][4][r] + bc;
        if (col16 == 0) {
          dom_out[(size_t)row * 2 + 0] = p0 + b20;
          dom_out[(size_t)row * 2 + 1] = p1 + b21;
        }
      }
    }
  }
}

extern "C" void kernel_launch(void* const* d_in, const int* in_sizes, int n_in,
                              void* d_out, int out_size, void* d_ws, size_t ws_size,
                              hipStream_t stream) {
  const float* x_s = (const float*)d_in[0];
  const float* x_c = (const float*)d_in[1];
  const float* Q = (const float*)d_in[2];
  const int* eis = (const int*)d_in[3];
  const int* eic = (const int*)d_in[4];
  const float* W1s = (const float*)d_in[5];
  const float* b1s = (const float*)d_in[6];
  const float* W2s = (const float*)d_in[7];
  const float* b2s = (const float*)d_in[8];
  const float* W1c = (const float*)d_in[9];
  const float* b1c = (const float*)d_in[10];
  const float* W2c = (const float*)d_in[11];
  const float* b2c = (const float*)d_in[12];
  const float* A1 = (const float*)d_in[13];
  const float* ab1 = (const float*)d_in[14];
  const float* A2 = (const float*)d_in[15];
  const float* ab2 = (const float*)d_in[16];
  const float* Wcls = (const float*)d_in[17];
  const float* bcls = (const float*)d_in[18];
  const float* D1 = (const float*)d_in[19];
  const float* db1 = (const float*)d_in[20];
  const float* D2 = (const float*)d_in[21];
  const float* db2 = (const float*)d_in[22];

  float* out_cls = (float*)d_out;
  float* out_dom = out_cls + (size_t)kNS * 9;
  float* out_fus = out_dom + (size_t)kNS * 2;

  char* p = (char*)d_ws;
  auto alloc = [&](size_t bytes) -> void* {
    void* r = (void*)p;
    p += (bytes + 255) & ~(size_t)255;
    return r;
  };
  // sample graph
  int* deg_s = (int*)alloc((size_t)kNS * 4);
  float* dis_s = (float*)alloc((size_t)kNS * 4);
  int* nstarts_s = (int*)alloc((size_t)kNS * 4);
  int* counts_s = (int*)alloc((size_t)kNB8 * 4);
  int* bstarts_s = (int*)alloc((size_t)(kNB8 + 1) * 4);
  int* bcursor_s = (int*)alloc((size_t)kNB8 * 4);
  // cluster graph
  int* deg_c = (int*)alloc((size_t)kNC * 4);
  int* cstarts_c = (int*)alloc((size_t)kNC * 4);
  int* cursor_c = (int*)alloc((size_t)kNC * 4);
  int* bsum_c = (int*)alloc(512 * 4);
  float* dis_c = (float*)alloc((size_t)kNC * 4);
  int* srow_c = (int*)alloc((size_t)kEC * 4);
  // feature buffers (bf16)
  unsigned short* hc1b = (unsigned short*)alloc((size_t)kNC * 64 * 2);
  unsigned short* xc1b = (unsigned short*)alloc((size_t)kNC * 64 * 2);
  unsigned short* hc2b = (unsigned short*)alloc((size_t)kNC * 128 * 2);
  unsigned short* xc2b = (unsigned short*)alloc((size_t)kNC * 128 * 2);
  unsigned short* hs1b = (unsigned short*)alloc((size_t)kNS * 64 * 2);
  unsigned short* xs1b = (unsigned short*)alloc((size_t)kNS * 64 * 2);
  unsigned short* hs2b = (unsigned short*)alloc((size_t)kNS * 128 * 2);
  unsigned short* xs2b = (unsigned short*)alloc((size_t)kNS * 128 * 2);
  unsigned short* xcdb = (unsigned short*)alloc((size_t)kNS * 128 * 2);
  short* Bq = (short*)alloc((size_t)512 * 128 * 2);
  short* A1p = (short*)alloc((size_t)256 * 128 * 2);
  short* Bh = (short*)alloc((size_t)128 * 80 * 2);
  // aliases (lifetimes disjoint along stream order):
  unsigned* edg_s = (unsigned*)hs2b;  // passB->passC; hs2b written later
  int* srow_s = (int*)xcdb;           // passC->agg128; xcdb written later (gemm_q)
  (void)ws_size; (void)in_sizes; (void)n_in; (void)out_size;

  hipMemsetAsync(counts_s, 0, (size_t)kNB8 * 4, stream);
  hipMemsetAsync(deg_c, 0, (size_t)kNC * 4, stream);

  const int nbC = (kNC + 255) / 256;

  // sample-graph grouping: bucket histogram -> scan -> reserved append -> per-node re-sort
  k_passA<<<kNBLK, 256, 0, stream>>>(eis + kES, kES, counts_s);
  k_scan_flat<<<1, 256, 0, stream>>>(counts_s, kNB8, bstarts_s, bcursor_s);
  k_passB<<<kNBLK, 256, 0, stream>>>(eis, eis + kES, kES, bcursor_s, edg_s);
  k_passC<<<kNB, 256, 0, stream>>>(edg_s, bstarts_s, deg_s, nstarts_s, dis_s, srow_s, kNS);

  // cluster-graph CSR
  k_hist<<<(kEC + 255) / 256, 256, 0, stream>>>(eic + kEC, kEC, deg_c);
  k_dis<<<nbC, 256, 0, stream>>>(deg_c, kNC, dis_c);
  k_scan1<<<nbC, 256, 0, stream>>>(deg_c, kNC, cstarts_c, bsum_c);
  k_scan2<<<1, 256, 0, stream>>>(bsum_c, nbC);
  k_scan3<<<nbC, 256, 0, stream>>>(cstarts_c, cursor_c, bsum_c, kNC);
  k_scatter<<<(kEC + 255) / 256, 256, 0, stream>>>(eic, eic + kEC, kEC, cursor_c, srow_c);

  // pack A1 + head B (independent)
  k_pack_b_f32src<<<(256 * 128 + 255) / 256, 256, 0, stream>>>(A1, A1p, 256);
  k_pack_bhead<<<(128 * 80 + 255) / 256, 256, 0, stream>>>(D1, Wcls, Bh);

  // cluster branch
  k_lin7<<<(kNC * 32 + 255) / 256, 256, 0, stream>>>(x_c, W1c, dis_c, hc1b, kNC);
  k_agg_bf<64><<<(kNC + 7) / 8, 256, 0, stream>>>(hc1b, cstarts_c, deg_c, srow_c, dis_c, b1c, xc1b, kNC);
  k_lin64x128<<<(kNC + 31) / 32, 256, 0, stream>>>(xc1b, W2c, dis_c, hc2b, kNC);
  k_agg_bf<128><<<(kNC + 3) / 4, 256, 0, stream>>>(hc2b, cstarts_c, deg_c, srow_c, dis_c, b2c, xc2b, kNC);
  k_pack_b_bf16src<<<(512 * 128 + 255) / 256, 256, 0, stream>>>(xc2b, Bq, 512);

  // sample branch
  k_lin7<<<(kNS * 32 + 255) / 256, 256, 0, stream>>>(x_s, W1s, dis_s, hs1b, kNS);
  k_agg_bf<64><<<(kNS + 7) / 8, 256, 0, stream>>>(hs1b, nstarts_s, deg_s, srow_s, dis_s, b1s, xs1b, kNS);
  k_lin64x128<<<(kNS + 31) / 32, 256, 0, stream>>>(xs1b, W2s, dis_s, hs2b, kNS);
  k_agg_bf<128><<<(kNS + 3) / 4, 256, 0, stream>>>(hs2b, nstarts_s, deg_s, srow_s, dis_s, b2s, xs2b, kNS);

  // decode + fusion gate + heads
  k_gemm_q_mfma<<<(kNS + 63) / 64, 256, 0, stream>>>(Q, Bq, xcdb, kNS);
  k_gemm_fuse_mfma<<<(kNS + 63) / 64, 256, 0, stream>>>(xs2b, xcdb, A1p, ab1, A2, ab2, out_fus, kNS);
  k_final_mfma<<<(kNS + 127) / 128, 256, 0, stream>>>(out_fus, Bh, bcls, db1, D2, db2, out_cls, out_dom, kNS);
}

// Round 8
// 570.984 us; speedup vs baseline: 7.8039x; 1.0267x over previous
//
#include <hip/hip_runtime.h>
#include <cstdint>
#include <cstddef>

static constexpr int kNS = 100000;
static constexpr int kNC = 512;
static constexpr int kES = 3200000;
static constexpr int kEC = 16384;

static constexpr int kNB = (kNS + 63) / 64;        // 1563 coarse buckets (64 nodes each)
static constexpr int kNB8 = kNB * 8;               // sub-bucketed counters
static constexpr int kCHUNK = 8192;                // edges per block in passA/passB
static constexpr int kNBLK = (kES + kCHUNK - 1) / kCHUNK;  // 391 blocks

static constexpr int kGemmQBlocks = (kNS + 63) / 64;   // 1563
static constexpr int kAgg128Blocks = (kNS + 3) / 4;    // 25000

typedef __attribute__((ext_vector_type(8))) short short8;
typedef __attribute__((ext_vector_type(4))) float f32x4;

__device__ __forceinline__ unsigned short f2bf(float f) {
  union { float f; unsigned u; } v; v.f = f;
  unsigned u = v.u;
  unsigned r = (u + 0x7fffu + ((u >> 16) & 1u)) >> 16;
  return (unsigned short)r;
}
__device__ __forceinline__ float bflo(unsigned v) { return __uint_as_float(v << 16); }
__device__ __forceinline__ float bfhi(unsigned v) { return __uint_as_float(v & 0xffff0000u); }
__device__ __forceinline__ float bf2f(unsigned short s) { return __uint_as_float(((unsigned)s) << 16); }

// ---------------- sample graph: bucket histogram (1 global atomic per touched bucket) ----------------
__global__ __launch_bounds__(256) void k_passA(const int* __restrict__ col, int E,
                                               int* __restrict__ counts) {
  __shared__ int hist[kNB];
  int t = threadIdx.x, bid = blockIdx.x;
  for (int j = t; j < kNB; j += 256) hist[j] = 0;
  __syncthreads();
  int base = bid * kCHUNK;
#pragma unroll 4
  for (int i = 0; i < kCHUNK / 256; i++) {
    int e = base + i * 256 + t;
    if (e < E) atomicAdd(&hist[col[e] >> 6], 1);
  }
  __syncthreads();
  int sub = bid & 7;
  for (int j = t; j < kNB; j += 256) {
    int v = hist[j];
    if (v) atomicAdd(&counts[j * 8 + sub], v);
  }
}

// exclusive scan of n flat counters -> starts[n+1], cursor copy
__global__ void k_scan_flat(const int* __restrict__ cnt, int n, int* __restrict__ starts,
                            int* __restrict__ cursor) {
  __shared__ int s[256];
  int t = threadIdx.x;
  int run = 0;
  for (int base = 0; base < n; base += 256) {
    int i = base + t;
    int v = (i < n) ? cnt[i] : 0;
    s[t] = v;
    __syncthreads();
    for (int o = 1; o < 256; o <<= 1) {
      int x = (t >= o) ? s[t - o] : 0;
      __syncthreads();
      s[t] += x;
      __syncthreads();
    }
    if (i < n) {
      int ex = run + s[t] - v;
      starts[i] = ex;
      cursor[i] = ex;
    }
    int tot = s[255];
    __syncthreads();
    run += tot;
  }
  if (t == 0) starts[n] = run;
}

// Pass B: LDS-hist -> per-bucket range reservation (1 global atomic each) -> LDS-cursor append.
__global__ __launch_bounds__(256) void k_passB(const int* __restrict__ row, const int* __restrict__ col,
                                               int E, int* __restrict__ cursor, unsigned* __restrict__ edg) {
  __shared__ int hist[kNB];
  int t = threadIdx.x, bid = blockIdx.x;
  int sub = bid & 7;
  for (int j = t; j < kNB; j += 256) hist[j] = 0;
  __syncthreads();
  int base = bid * kCHUNK;
#pragma unroll 4
  for (int i = 0; i < kCHUNK / 256; i++) {
    int e = base + i * 256 + t;
    if (e < E) atomicAdd(&hist[col[e] >> 6], 1);
  }
  __syncthreads();
  for (int j = t; j < kNB; j += 256) {
    int v = hist[j];
    hist[j] = v ? atomicAdd(&cursor[j * 8 + sub], v) : 0;  // becomes this block's run start
  }
  __syncthreads();
#pragma unroll 4
  for (int i = 0; i < kCHUNK / 256; i++) {
    int e = base + i * 256 + t;
    if (e < E) {
      int c = col[e];
      int pos = atomicAdd(&hist[c >> 6], 1);  // LDS-only cursor
      edg[pos] = ((unsigned)row[e] << 6) | (unsigned)(c & 63);
    }
  }
}

// Pass C: per-bucket re-sort into exact per-node CSR; emits per-node degree + starts + dis.
__global__ __launch_bounds__(256) void k_passC(const unsigned* __restrict__ edg,
                                               const int* __restrict__ bstarts,
                                               int* __restrict__ deg, int* __restrict__ nstarts,
                                               float* __restrict__ dis,
                                               int* __restrict__ srow, int N) {
  __shared__ int ldeg[64];
  __shared__ int lcur[64];
  int b = blockIdx.x, t = threadIdx.x;
  int s0 = bstarts[b * 8], s1 = bstarts[b * 8 + 8];
  if (t < 64) ldeg[t] = 0;
  __syncthreads();
  for (int i = s0 + t; i < s1; i += 256) atomicAdd(&ldeg[edg[i] & 63u], 1);
  __syncthreads();
  if (t < 64) {
    int own = ldeg[t];
    int incl = own;
#pragma unroll
    for (int off = 1; off < 64; off <<= 1) {
      int o = __shfl_up(incl, off);
      if (t >= off) incl += o;
    }
    int st = s0 + incl - own;
    lcur[t] = st;
    int g = b * 64 + t;
    if (g < N) {
      deg[g] = own;
      nstarts[g] = st;
      dis[g] = rsqrtf((float)(own + 1));
    }
  }
  __syncthreads();
  for (int i = s0 + t; i < s1; i += 256) {
    unsigned ew = edg[i];
    int pos = atomicAdd(&lcur[ew & 63u], 1);
    srow[pos] = (int)(ew >> 6);
  }
}

// ---------------- cluster graph: small CSR path ----------------
__global__ void k_hist(const int* __restrict__ col, int E, int* __restrict__ cnt) {
  int i = blockIdx.x * blockDim.x + threadIdx.x;
  if (i < E) atomicAdd(&cnt[col[i]], 1);
}

__global__ void k_dis(const int* __restrict__ cnt, int N, float* __restrict__ dis) {
  int i = blockIdx.x * blockDim.x + threadIdx.x;
  if (i < N) dis[i] = rsqrtf((float)(cnt[i] + 1));
}

__global__ void k_scan1(const int* __restrict__ cnt, int N, int* __restrict__ starts, int* __restrict__ bsum) {
  __shared__ int s[256];
  int t = threadIdx.x;
  int i = blockIdx.x * 256 + t;
  int v = (i < N) ? cnt[i] : 0;
  s[t] = v;
  __syncthreads();
  for (int o = 1; o < 256; o <<= 1) {
    int x = (t >= o) ? s[t - o] : 0;
    __syncthreads();
    s[t] += x;
    __syncthreads();
  }
  if (i < N) starts[i] = s[t] - v;
  if (t == 255) bsum[blockIdx.x] = s[255];
}

__global__ void k_scan2(int* __restrict__ bsum, int nb) {
  __shared__ int s[256];
  int t = threadIdx.x;
  int run = 0;
  for (int base = 0; base < nb; base += 256) {
    int i = base + t;
    int v = (i < nb) ? bsum[i] : 0;
    s[t] = v;
    __syncthreads();
    for (int o = 1; o < 256; o <<= 1) {
      int x = (t >= o) ? s[t - o] : 0;
      __syncthreads();
      s[t] += x;
      __syncthreads();
    }
    if (i < nb) bsum[i] = run + s[t] - v;
    int tot = s[255];
    __syncthreads();
    run += tot;
  }
}

__global__ void k_scan3(int* __restrict__ starts, int* __restrict__ cursor, const int* __restrict__ bsum, int N) {
  int i = blockIdx.x * 256 + threadIdx.x;
  if (i < N) {
    int v = starts[i] + bsum[blockIdx.x];
    starts[i] = v;
    cursor[i] = v;
  }
}

__global__ void k_scatter(const int* __restrict__ row, const int* __restrict__ col, int E,
                          int* __restrict__ cursor, int* __restrict__ srow) {
  int i = blockIdx.x * blockDim.x + threadIdx.x;
  if (i < E) {
    int pos = atomicAdd(&cursor[col[i]], 1);
    srow[pos] = row[i];
  }
}

// ---------------- aggregation body (bf16 in/out) ----------------
template <int F>
__device__ __forceinline__ void agg_body(int bid, int t,
                                         const unsigned short* __restrict__ hs,
                                         const int* __restrict__ starts, const int* __restrict__ cnt,
                                         const int* __restrict__ srow, const float* __restrict__ dis,
                                         const float* __restrict__ b, unsigned short* __restrict__ out, int N) {
  constexpr int LPN = F / 2;
  int c = bid * (256 / LPN) + t / LPN;
  if (c >= N) return;
  int fi = (t % LPN) * 2;
  unsigned v = *(const unsigned*)(hs + (size_t)c * F + fi);
  float ax = bflo(v), ay = bfhi(v);
  int s0 = starts[c], n = cnt[c];
  const int* sp = srow + s0;
  int e = 0;
  for (; e + 8 <= n; e += 8) {
    int r0 = sp[e], r1 = sp[e + 1], r2 = sp[e + 2], r3 = sp[e + 3];
    int r4 = sp[e + 4], r5 = sp[e + 5], r6 = sp[e + 6], r7 = sp[e + 7];
    unsigned v0 = *(const unsigned*)(hs + (size_t)r0 * F + fi);
    unsigned v1 = *(const unsigned*)(hs + (size_t)r1 * F + fi);
    unsigned v2 = *(const unsigned*)(hs + (size_t)r2 * F + fi);
    unsigned v3 = *(const unsigned*)(hs + (size_t)r3 * F + fi);
    unsigned v4 = *(const unsigned*)(hs + (size_t)r4 * F + fi);
    unsigned v5 = *(const unsigned*)(hs + (size_t)r5 * F + fi);
    unsigned v6 = *(const unsigned*)(hs + (size_t)r6 * F + fi);
    unsigned v7 = *(const unsigned*)(hs + (size_t)r7 * F + fi);
    ax += bflo(v0) + bflo(v1) + bflo(v2) + bflo(v3) + bflo(v4) + bflo(v5) + bflo(v6) + bflo(v7);
    ay += bfhi(v0) + bfhi(v1) + bfhi(v2) + bfhi(v3) + bfhi(v4) + bfhi(v5) + bfhi(v6) + bfhi(v7);
  }
  for (; e + 4 <= n; e += 4) {
    int r0 = sp[e], r1 = sp[e + 1], r2 = sp[e + 2], r3 = sp[e + 3];
    unsigned v0 = *(const unsigned*)(hs + (size_t)r0 * F + fi);
    unsigned v1 = *(const unsigned*)(hs + (size_t)r1 * F + fi);
    unsigned v2 = *(const unsigned*)(hs + (size_t)r2 * F + fi);
    unsigned v3 = *(const unsigned*)(hs + (size_t)r3 * F + fi);
    ax += bflo(v0) + bflo(v1) + bflo(v2) + bflo(v3);
    ay += bfhi(v0) + bfhi(v1) + bfhi(v2) + bfhi(v3);
  }
  for (; e < n; e++) {
    unsigned vv = *(const unsigned*)(hs + (size_t)sp[e] * F + fi);
    ax += bflo(vv);
    ay += bfhi(vv);
  }
  float d = dis[c];
  float ox = fmaxf(fmaf(d, ax, b[fi]), 0.f);
  float oy = fmaxf(fmaf(d, ay, b[fi + 1]), 0.f);
  *(unsigned*)(out + (size_t)c * F + fi) = (unsigned)f2bf(ox) | ((unsigned)f2bf(oy) << 16);
}

template <int F>
__global__ __launch_bounds__(256) void k_agg_bf(const unsigned short* __restrict__ hs,
                                                const int* __restrict__ starts, const int* __restrict__ cnt,
                                                const int* __restrict__ srow, const float* __restrict__ dis,
                                                const float* __restrict__ b, unsigned short* __restrict__ out, int N) {
  agg_body<F>(blockIdx.x, threadIdx.x, hs, starts, cnt, srow, dis, b, out, N);
}

// ---------------- layer-1 linear: hs[N,64](bf16) = (x[N,7] @ W[7,64]) * dis[row] ----------------
__global__ __launch_bounds__(256) void k_lin7(const float* __restrict__ x, const float* __restrict__ W,
                                              const float* __restrict__ dis, unsigned short* __restrict__ hs, int N) {
  __shared__ float Ws[7 * 64];
  int t = threadIdx.x;
  for (int j = t; j < 7 * 64; j += 256) Ws[j] = W[j];
  __syncthreads();
  int idx = blockIdx.x * 256 + t;
  if (idx < N * 32) {
    int r = idx >> 5, c2 = (idx & 31) * 2;
    const float* xr = x + (size_t)r * 7;
    float a0 = 0.f, a1 = 0.f;
#pragma unroll
    for (int k = 0; k < 7; k++) {
      float xv = xr[k];
      a0 = fmaf(xv, Ws[k * 64 + c2], a0);
      a1 = fmaf(xv, Ws[k * 64 + c2 + 1], a1);
    }
    float d = dis[r];
    unsigned pk = (unsigned)f2bf(a0 * d) | ((unsigned)f2bf(a1 * d) << 16);
    *(unsigned*)(hs + (size_t)r * 64 + c2) = pk;
  }
}

// ---------------- layer-2 linear: 32 rows/block ----------------
__global__ __launch_bounds__(256) void k_lin64x128(const unsigned short* __restrict__ xin, const float* __restrict__ W,
                                                   const float* __restrict__ dis, unsigned short* __restrict__ hs, int N) {
  __shared__ float Ws[64 * 128];
  __shared__ float xs[32][64];
  int t = threadIdx.x;
  for (int j = t; j < 64 * 128; j += 256) Ws[j] = W[j];
  int r0 = blockIdx.x * 32;
  for (int j = t; j < 32 * 64; j += 256) {
    int r = j >> 6, k = j & 63;
    int gr = r0 + r;
    xs[r][k] = (gr < N) ? bf2f(xin[(size_t)gr * 64 + k]) : 0.f;
  }
  __syncthreads();
  int c = t & 63;
  int rb = (t >> 6) * 8;
  float a0[8], a1[8];
#pragma unroll
  for (int rr = 0; rr < 8; rr++) { a0[rr] = 0.f; a1[rr] = 0.f; }
  for (int k = 0; k < 64; k++) {
    float w0 = Ws[k * 128 + c];
    float w1 = Ws[k * 128 + c + 64];
#pragma unroll
    for (int rr = 0; rr < 8; rr++) {
      float xv = xs[rb + rr][k];
      a0[rr] = fmaf(xv, w0, a0[rr]);
      a1[rr] = fmaf(xv, w1, a1[rr]);
    }
  }
#pragma unroll
  for (int rr = 0; rr < 8; rr++) {
    int gr = r0 + rb + rr;
    if (gr < N) {
      float d = dis[gr];
      hs[(size_t)gr * 128 + c] = f2bf(a0[rr] * d);
      hs[(size_t)gr * 128 + c + 64] = f2bf(a1[rr] * d);
    }
  }
}

// ---------------- combined B-operand pack: Bq (from xc2b), A1p, Bh ----------------
__global__ void k_pack_all(const unsigned short* __restrict__ xc2b, const float* __restrict__ A1,
                           const float* __restrict__ D1, const float* __restrict__ Wcls,
                           short* __restrict__ Bq, short* __restrict__ A1p, short* __restrict__ Bh) {
  int i = blockIdx.x * 256 + threadIdx.x;
  if (i < 512 * 128) {
    int e = i;
    int k = e >> 7, n = e & 127;
    int frag = (k >> 5) * 8 + (n >> 4);
    int l = (n & 15) | (((k >> 3) & 3) << 4);
    int j = k & 7;
    Bq[(size_t)frag * 512 + l * 8 + j] = (short)xc2b[e];
  } else if (i < 512 * 128 + 256 * 128) {
    int e = i - 512 * 128;
    int k = e >> 7, n = e & 127;
    int frag = (k >> 5) * 8 + (n >> 4);
    int l = (n & 15) | (((k >> 3) & 3) << 4);
    int j = k & 7;
    A1p[(size_t)frag * 512 + l * 8 + j] = (short)f2bf(A1[e]);
  } else if (i < 512 * 128 + 256 * 128 + 128 * 80) {
    int e = i - (512 * 128 + 256 * 128);
    int k = e / 80, n = e % 80;
    float v = 0.f;
    if (n < 64) v = D1[k * 64 + n];
    else if (n < 73) v = Wcls[k * 9 + (n - 64)];
    int frag = (k >> 5) * 5 + (n >> 4);
    int l = (n & 15) | (((k >> 3) & 3) << 4);
    int j = k & 7;
    Bh[(size_t)frag * 512 + l * 8 + j] = (short)f2bf(v);
  }
}

__device__ __forceinline__ short8 zero8() {
  short8 z;
#pragma unroll
  for (int j = 0; j < 8; j++) z[j] = 0;
  return z;
}

__device__ __forceinline__ short8 cvt8(float4 v0, float4 v1) {
  short8 r;
  r[0] = (short)f2bf(v0.x); r[1] = (short)f2bf(v0.y); r[2] = (short)f2bf(v0.z); r[3] = (short)f2bf(v0.w);
  r[4] = (short)f2bf(v1.x); r[5] = (short)f2bf(v1.y); r[6] = (short)f2bf(v1.z); r[7] = (short)f2bf(v1.w);
  return r;
}

__device__ __forceinline__ short8 load_a_f32(const float* p, bool ok) {
  if (!ok) return zero8();
  return cvt8(*(const float4*)p, *(const float4*)(p + 4));
}

// ---------------- gemm_q body (64 rows/block, 16 rows/wave, reg double-buffered) ----------------
__device__ __forceinline__ void gemm_q_body(int bid, int t, const float* __restrict__ Q,
                                            const short* __restrict__ Bp,
                                            unsigned short* __restrict__ outb, int M) {
  int lane = t & 63;
  int wid = t >> 6;
  int m0 = bid * 64 + wid * 16;
  int mrow = lane & 15;
  int kg = lane >> 4;
  f32x4 acc[8];
#pragma unroll
  for (int nf = 0; nf < 8; nf++) acc[nf] = (f32x4){0.f, 0.f, 0.f, 0.f};
  int r0 = m0 + mrow;
  bool ok = r0 < M;
  const float* ap = Q + (size_t)r0 * 512 + kg * 8;
  const short* bl = Bp + lane * 8;
  float4 z4 = {0.f, 0.f, 0.f, 0.f};
  float4 v0 = ok ? *(const float4*)ap : z4;
  float4 v1 = ok ? *(const float4*)(ap + 4) : z4;
  for (int ks = 0; ks < 16; ks++) {
    float4 n0 = z4, n1 = z4;
    if (ks < 15 && ok) {
      n0 = *(const float4*)(ap + (ks + 1) * 32);
      n1 = *(const float4*)(ap + (ks + 1) * 32 + 4);
    }
    short8 a = cvt8(v0, v1);
    const short* bb = bl + (ks << 12);
#pragma unroll
    for (int nf = 0; nf < 8; nf++) {
      short8 b = *(const short8*)(bb + (nf << 9));
      acc[nf] = __builtin_amdgcn_mfma_f32_16x16x32_bf16(a, b, acc[nf], 0, 0, 0);
    }
    v0 = n0;
    v1 = n1;
  }
  int col = lane & 15;
  int g = lane >> 4;
#pragma unroll
  for (int nf = 0; nf < 8; nf++)
#pragma unroll
    for (int r = 0; r < 4; r++) {
      int row = m0 + g * 4 + r;
      if (row < M) outb[(size_t)row * 128 + nf * 16 + col] = f2bf(acc[nf][r]);
    }
}

// ---------------- FAT kernel: gemm_q blocks first, then agg128 blocks (independent work) --------
__global__ __launch_bounds__(256) void k_aggq(const float* __restrict__ Q, const short* __restrict__ Bp,
                                              unsigned short* __restrict__ xcdb,
                                              const unsigned short* __restrict__ hs,
                                              const int* __restrict__ starts, const int* __restrict__ cnt,
                                              const int* __restrict__ srow, const float* __restrict__ dis,
                                              const float* __restrict__ b, unsigned short* __restrict__ out,
                                              int M) {
  int bid = blockIdx.x, t = threadIdx.x;
  if (bid < kGemmQBlocks) {
    gemm_q_body(bid, t, Q, Bp, xcdb, M);
  } else {
    agg_body<128>(bid - kGemmQBlocks, t, hs, starts, cnt, srow, dis, b, out, M);
  }
}

// ---------------- GEMM2 (MFMA) + gate epilogue (64 rows/block, 16 rows/wave) ----------------
__global__ __launch_bounds__(256) void k_gemm_fuse_mfma(const unsigned short* __restrict__ Xs,
                                                        const unsigned short* __restrict__ Xc,
                                                        const short* __restrict__ A1p, const float* __restrict__ ab1,
                                                        const float* __restrict__ A2, const float* __restrict__ ab2,
                                                        float* __restrict__ fused, int M) {
  int t = threadIdx.x;
  int lane = t & 63;
  int wid = t >> 6;
  int m0 = blockIdx.x * 64 + wid * 16;
  int mrow = lane & 15;
  int kg = lane >> 4;
  f32x4 acc[8];
#pragma unroll
  for (int nf = 0; nf < 8; nf++) acc[nf] = (f32x4){0.f, 0.f, 0.f, 0.f};
  int r0 = m0 + mrow;
  bool ok = r0 < M;
  const short* bl = A1p + lane * 8;
  short8 a = ok ? *(const short8*)(Xs + (size_t)r0 * 128 + kg * 8) : zero8();
  for (int ks = 0; ks < 8; ks++) {
    short8 an = zero8();
    if (ks < 7 && ok) {
      int ks1 = ks + 1;
      const unsigned short* src = (ks1 < 4) ? Xs : Xc;
      an = *(const short8*)(src + (size_t)r0 * 128 + (ks1 & 3) * 32 + kg * 8);
    }
    const short* bb = bl + (ks << 12);
#pragma unroll
    for (int nf = 0; nf < 8; nf++) {
      short8 b = *(const short8*)(bb + (nf << 9));
      acc[nf] = __builtin_amdgcn_mfma_f32_16x16x32_bf16(a, b, acc[nf], 0, 0, 0);
    }
    a = an;
  }
  int col16 = lane & 15;
  int g = lane >> 4;
  float bias[8], w20[8], w21[8];
#pragma unroll
  for (int nf = 0; nf < 8; nf++) {
    int cc = nf * 16 + col16;
    bias[nf] = ab1[cc];
    w20[nf] = A2[2 * cc];
    w21[nf] = A2[2 * cc + 1];
  }
  float b20 = ab2[0], b21 = ab2[1];
#pragma unroll
  for (int r = 0; r < 4; r++) {
    float u0 = 0.f, u1 = 0.f;
#pragma unroll
    for (int nf = 0; nf < 8; nf++) {
      float tv = fmaxf(acc[nf][r] + bias[nf], 0.f);
      u0 = fmaf(tv, w20[nf], u0);
      u1 = fmaf(tv, w21[nf], u1);
    }
#pragma unroll
    for (int off = 1; off < 16; off <<= 1) {
      u0 += __shfl_xor(u0, off);
      u1 += __shfl_xor(u1, off);
    }
    int row = m0 + g * 4 + r;
    if (row < M) {
      float ua = u0 + b20, ub = u1 + b21;
      float mx = fmaxf(ua, ub);
      float e0 = __expf(ua - mx), e1 = __expf(ub - mx);
      float inv = 1.f / (e0 + e1);
      float w0 = e0 * inv, w1 = e1 * inv;
      int p = col16;
      const unsigned short* xsp = Xs + (size_t)row * 128 + p * 8;
      const unsigned short* xcp = Xc + (size_t)row * 128 + p * 8;
      float* op = fused + (size_t)row * 128 + p * 8;
      float4 o0, o1;
      unsigned sx0 = *(const unsigned*)(xsp + 0), sx1 = *(const unsigned*)(xsp + 2);
      unsigned sx2 = *(const unsigned*)(xsp + 4), sx3 = *(const unsigned*)(xsp + 6);
      unsigned cx0 = *(const unsigned*)(xcp + 0), cx1 = *(const unsigned*)(xcp + 2);
      unsigned cx2 = *(const unsigned*)(xcp + 4), cx3 = *(const unsigned*)(xcp + 6);
      o0.x = w0 * bflo(sx0) + w1 * bflo(cx0);
      o0.y = w0 * bfhi(sx0) + w1 * bfhi(cx0);
      o0.z = w0 * bflo(sx1) + w1 * bflo(cx1);
      o0.w = w0 * bfhi(sx1) + w1 * bfhi(cx1);
      o1.x = w0 * bflo(sx2) + w1 * bflo(cx2);
      o1.y = w0 * bfhi(sx2) + w1 * bfhi(cx2);
      o1.z = w0 * bflo(sx3) + w1 * bflo(cx3);
      o1.w = w0 * bfhi(sx3) + w1 * bfhi(cx3);
      *(float4*)op = o0;
      *(float4*)(op + 4) = o1;
    }
  }
}

// ---------------- heads (MFMA): [class | domain] from fused[M,128] ----------------
__global__ __launch_bounds__(256) void k_final_mfma(const float* __restrict__ fused, const short* __restrict__ Bh,
                                                    const float* __restrict__ bcls, const float* __restrict__ db1,
                                                    const float* __restrict__ D2, const float* __restrict__ db2,
                                                    float* __restrict__ cls_out, float* __restrict__ dom_out, int M) {
  int t = threadIdx.x;
  int lane = t & 63;
  int wid = t >> 6;
  int m0 = blockIdx.x * 128 + wid * 32;
  int mrow = lane & 15;
  int kg = lane >> 4;
  f32x4 acc[2][5];
#pragma unroll
  for (int mi = 0; mi < 2; mi++)
#pragma unroll
    for (int nf = 0; nf < 5; nf++) acc[mi][nf] = (f32x4){0.f, 0.f, 0.f, 0.f};
  int r0 = m0 + mrow, r1 = m0 + 16 + mrow;
  bool ok0 = r0 < M, ok1 = r1 < M;
  const float* a0p = fused + (size_t)r0 * 128 + kg * 8;
  const float* a1p = fused + (size_t)r1 * 128 + kg * 8;
  const short* bl = Bh + lane * 8;
  for (int ks = 0; ks < 4; ks++) {
    short8 a0 = load_a_f32(a0p + ks * 32, ok0);
    short8 a1 = load_a_f32(a1p + ks * 32, ok1);
    const short* bb = bl + ks * 5 * 512;
#pragma unroll
    for (int nf = 0; nf < 5; nf++) {
      short8 b = *(const short8*)(bb + (nf << 9));
      acc[0][nf] = __builtin_amdgcn_mfma_f32_16x16x32_bf16(a0, b, acc[0][nf], 0, 0, 0);
      acc[1][nf] = __builtin_amdgcn_mfma_f32_16x16x32_bf16(a1, b, acc[1][nf], 0, 0, 0);
    }
  }
  int col16 = lane & 15;
  int g = lane >> 4;
  float bh[4], d20[4], d21[4];
#pragma unroll
  for (int nf = 0; nf < 4; nf++) {
    int h = col16 + 16 * nf;
    bh[nf] = db1[h];
    d20[nf] = D2[h * 2];
    d21[nf] = D2[h * 2 + 1];
  }
  float bc = (col16 < 9) ? bcls[col16] : 0.f;
  float b20 = db2[0], b21 = db2[1];
#pragma unroll
  for (int mi = 0; mi < 2; mi++) {
#pragma unroll
    for (int r = 0; r < 4; r++) {
      float p0 = 0.f, p1 = 0.f;
#pragma unroll
      for (int nf = 0; nf < 4; nf++) {
        float hv = fmaxf(acc[mi][nf][r] + bh[nf], 0.f);
        p0 = fmaf(hv, d20[nf], p0);
        p1 = fmaf(hv, d21[nf], p1);
      }
#pragma unroll
      for (int off = 1; off < 16; off <<= 1) {
        p0 += __shfl_xor(p0, off);
        p1 += __shfl_xor(p1, off);
      }
      int row = m0 + mi * 16 + g * 4 + r;
      if (row < M) {
        if (col16 < 9) cls_out[(size_t)row * 9 + col16] = acc[mi][4][r] + bc;
        if (col16 == 0) {
          dom_out[(size_t)row * 2 + 0] = p0 + b20;
          dom_out[(size_t)row * 2 + 1] = p1 + b21;
        }
      }
    }
  }
}

extern "C" void kernel_launch(void* const* d_in, const int* in_sizes, int n_in,
                              void* d_out, int out_size, void* d_ws, size_t ws_size,
                              hipStream_t stream) {
  const float* x_s = (const float*)d_in[0];
  const float* x_c = (const float*)d_in[1];
  const float* Q = (const float*)d_in[2];
  const int* eis = (const int*)d_in[3];
  const int* eic = (const int*)d_in[4];
  const float* W1s = (const float*)d_in[5];
  const float* b1s = (const float*)d_in[6];
  const float* W2s = (const float*)d_in[7];
  const float* b2s = (const float*)d_in[8];
  const float* W1c = (const float*)d_in[9];
  const float* b1c = (const float*)d_in[10];
  const float* W2c = (const float*)d_in[11];
  const float* b2c = (const float*)d_in[12];
  const float* A1 = (const float*)d_in[13];
  const float* ab1 = (const float*)d_in[14];
  const float* A2 = (const float*)d_in[15];
  const float* ab2 = (const float*)d_in[16];
  const float* Wcls = (const float*)d_in[17];
  const float* bcls = (const float*)d_in[18];
  const float* D1 = (const float*)d_in[19];
  const float* db1 = (const float*)d_in[20];
  const float* D2 = (const float*)d_in[21];
  const float* db2 = (const float*)d_in[22];

  float* out_cls = (float*)d_out;
  float* out_dom = out_cls + (size_t)kNS * 9;
  float* out_fus = out_dom + (size_t)kNS * 2;

  char* p = (char*)d_ws;
  auto alloc = [&](size_t bytes) -> void* {
    void* r = (void*)p;
    p += (bytes + 255) & ~(size_t)255;
    return r;
  };
  // sample graph
  int* deg_s = (int*)alloc((size_t)kNS * 4);
  float* dis_s = (float*)alloc((size_t)kNS * 4);
  int* nstarts_s = (int*)alloc((size_t)kNS * 4);
  int* counts_s = (int*)alloc((size_t)kNB8 * 4);
  int* bstarts_s = (int*)alloc((size_t)(kNB8 + 1) * 4);
  int* bcursor_s = (int*)alloc((size_t)kNB8 * 4);
  int* srow_s = (int*)alloc((size_t)kES * 4);  // dedicated (fat kernel: must not alias xcdb)
  // cluster graph
  int* deg_c = (int*)alloc((size_t)kNC * 4);
  int* cstarts_c = (int*)alloc((size_t)kNC * 4);
  int* cursor_c = (int*)alloc((size_t)kNC * 4);
  int* bsum_c = (int*)alloc(512 * 4);
  float* dis_c = (float*)alloc((size_t)kNC * 4);
  int* srow_c = (int*)alloc((size_t)kEC * 4);
  // feature buffers (bf16)
  unsigned short* hc1b = (unsigned short*)alloc((size_t)kNC * 64 * 2);
  unsigned short* xc1b = (unsigned short*)alloc((size_t)kNC * 64 * 2);
  unsigned short* hc2b = (unsigned short*)alloc((size_t)kNC * 128 * 2);
  unsigned short* xc2b = (unsigned short*)alloc((size_t)kNC * 128 * 2);
  unsigned short* hs1b = (unsigned short*)alloc((size_t)kNS * 64 * 2);
  unsigned short* xs1b = (unsigned short*)alloc((size_t)kNS * 64 * 2);
  unsigned short* hs2b = (unsigned short*)alloc((size_t)kNS * 128 * 2);
  unsigned short* xs2b = (unsigned short*)alloc((size_t)kNS * 128 * 2);
  unsigned short* xcdb = (unsigned short*)alloc((size_t)kNS * 128 * 2);
  short* Bq = (short*)alloc((size_t)512 * 128 * 2);
  short* A1p = (short*)alloc((size_t)256 * 128 * 2);
  short* Bh = (short*)alloc((size_t)128 * 80 * 2);
  // alias (lifetimes disjoint along stream order): edg lives passB->passC; hs2b written later.
  unsigned* edg_s = (unsigned*)hs2b;
  (void)ws_size; (void)in_sizes; (void)n_in; (void)out_size;

  hipMemsetAsync(counts_s, 0, (size_t)kNB8 * 4, stream);
  hipMemsetAsync(deg_c, 0, (size_t)kNC * 4, stream);

  const int nbC = (kNC + 255) / 256;

  // sample-graph grouping: bucket histogram -> scan -> reserved append -> per-node re-sort
  k_passA<<<kNBLK, 256, 0, stream>>>(eis + kES, kES, counts_s);
  k_scan_flat<<<1, 256, 0, stream>>>(counts_s, kNB8, bstarts_s, bcursor_s);
  k_passB<<<kNBLK, 256, 0, stream>>>(eis, eis + kES, kES, bcursor_s, edg_s);
  k_passC<<<kNB, 256, 0, stream>>>(edg_s, bstarts_s, deg_s, nstarts_s, dis_s, srow_s, kNS);

  // cluster-graph CSR
  k_hist<<<(kEC + 255) / 256, 256, 0, stream>>>(eic + kEC, kEC, deg_c);
  k_dis<<<nbC, 256, 0, stream>>>(deg_c, kNC, dis_c);
  k_scan1<<<nbC, 256, 0, stream>>>(deg_c, kNC, cstarts_c, bsum_c);
  k_scan2<<<1, 256, 0, stream>>>(bsum_c, nbC);
  k_scan3<<<nbC, 256, 0, stream>>>(cstarts_c, cursor_c, bsum_c, kNC);
  k_scatter<<<(kEC + 255) / 256, 256, 0, stream>>>(eic, eic + kEC, kEC, cursor_c, srow_c);

  // cluster branch
  k_lin7<<<(kNC * 32 + 255) / 256, 256, 0, stream>>>(x_c, W1c, dis_c, hc1b, kNC);
  k_agg_bf<64><<<(kNC + 7) / 8, 256, 0, stream>>>(hc1b, cstarts_c, deg_c, srow_c, dis_c, b1c, xc1b, kNC);
  k_lin64x128<<<(kNC + 31) / 32, 256, 0, stream>>>(xc1b, W2c, dis_c, hc2b, kNC);
  k_agg_bf<128><<<(kNC + 3) / 4, 256, 0, stream>>>(hc2b, cstarts_c, deg_c, srow_c, dis_c, b2c, xc2b, kNC);
  k_pack_all<<<(512 * 128 + 256 * 128 + 128 * 80 + 255) / 256, 256, 0, stream>>>(xc2b, A1, D1, Wcls, Bq, A1p, Bh);

  // sample branch
  k_lin7<<<(kNS * 32 + 255) / 256, 256, 0, stream>>>(x_s, W1s, dis_s, hs1b, kNS);
  k_agg_bf<64><<<(kNS + 7) / 8, 256, 0, stream>>>(hs1b, nstarts_s, deg_s, srow_s, dis_s, b1s, xs1b, kNS);
  k_lin64x128<<<(kNS + 31) / 32, 256, 0, stream>>>(xs1b, W2s, dis_s, hs2b, kNS);

  // FAT: gemm_q (decode) || agg128 (sample layer 2) — independent work, different pipes
  k_aggq<<<kGemmQBlocks + kAgg128Blocks, 256, 0, stream>>>(Q, Bq, xcdb,
                                                           hs2b, nstarts_s, deg_s, srow_s, dis_s, b2s, xs2b, kNS);

  // fusion gate + heads
  k_gemm_fuse_mfma<<<(kNS + 63) / 64, 256, 0, stream>>>(xs2b, xcdb, A1p, ab1, A2, ab2, out_fus, kNS);
  k_final_mfma<<<(kNS + 127) / 128, 256, 0, stream>>>(out_fus, Bh, bcls, db1, D2, db2, out_cls, out_dom, kNS);
}

// Round 9
// 488.868 us; speedup vs baseline: 9.1147x; 1.1680x over previous
//
#include <hip/hip_runtime.h>
#include <cstdint>
#include <cstddef>

static constexpr int kNS = 100000;
static constexpr int kNC = 512;
static constexpr int kES = 3200000;
static constexpr int kEC = 16384;

static constexpr int kNB = (kNS + 63) / 64;        // 1563 coarse buckets (64 nodes each)
static constexpr int kNB8 = kNB * 8;               // sub-bucketed counters
static constexpr int kCHUNK = 8192;                // edges per block in passA/passB
static constexpr int kNBLK = (kES + kCHUNK - 1) / kCHUNK;  // 391 blocks

static constexpr int kGemmQBlocks = (kNS + 63) / 64;   // 1563
static constexpr int kAgg64Blocks = (kNS + 7) / 8;     // 12500

typedef __attribute__((ext_vector_type(8))) short short8;
typedef __attribute__((ext_vector_type(4))) float f32x4;

__device__ __forceinline__ unsigned short f2bf(float f) {
  union { float f; unsigned u; } v; v.f = f;
  unsigned u = v.u;
  unsigned r = (u + 0x7fffu + ((u >> 16) & 1u)) >> 16;
  return (unsigned short)r;
}
__device__ __forceinline__ float bflo(unsigned v) { return __uint_as_float(v << 16); }
__device__ __forceinline__ float bfhi(unsigned v) { return __uint_as_float(v & 0xffff0000u); }
__device__ __forceinline__ float bf2f(unsigned short s) { return __uint_as_float(((unsigned)s) << 16); }

// ---------------- sample graph: bucket histogram (1 global atomic per touched bucket) ----------------
__global__ __launch_bounds__(256) void k_passA(const int* __restrict__ col, int E,
                                               int* __restrict__ counts) {
  __shared__ int hist[kNB];
  int t = threadIdx.x, bid = blockIdx.x;
  for (int j = t; j < kNB; j += 256) hist[j] = 0;
  __syncthreads();
  int base = bid * kCHUNK;
#pragma unroll 4
  for (int i = 0; i < kCHUNK / 256; i++) {
    int e = base + i * 256 + t;
    if (e < E) atomicAdd(&hist[col[e] >> 6], 1);
  }
  __syncthreads();
  int sub = bid & 7;
  for (int j = t; j < kNB; j += 256) {
    int v = hist[j];
    if (v) atomicAdd(&counts[j * 8 + sub], v);
  }
}

// exclusive scan of n flat counters -> starts[n+1], cursor copy
__global__ void k_scan_flat(const int* __restrict__ cnt, int n, int* __restrict__ starts,
                            int* __restrict__ cursor) {
  __shared__ int s[256];
  int t = threadIdx.x;
  int run = 0;
  for (int base = 0; base < n; base += 256) {
    int i = base + t;
    int v = (i < n) ? cnt[i] : 0;
    s[t] = v;
    __syncthreads();
    for (int o = 1; o < 256; o <<= 1) {
      int x = (t >= o) ? s[t - o] : 0;
      __syncthreads();
      s[t] += x;
      __syncthreads();
    }
    if (i < n) {
      int ex = run + s[t] - v;
      starts[i] = ex;
      cursor[i] = ex;
    }
    int tot = s[255];
    __syncthreads();
    run += tot;
  }
  if (t == 0) starts[n] = run;
}

// Pass B: LDS-hist -> per-bucket range reservation (1 global atomic each) -> LDS-cursor append.
__global__ __launch_bounds__(256) void k_passB(const int* __restrict__ row, const int* __restrict__ col,
                                               int E, int* __restrict__ cursor, unsigned* __restrict__ edg) {
  __shared__ int hist[kNB];
  int t = threadIdx.x, bid = blockIdx.x;
  int sub = bid & 7;
  for (int j = t; j < kNB; j += 256) hist[j] = 0;
  __syncthreads();
  int base = bid * kCHUNK;
#pragma unroll 4
  for (int i = 0; i < kCHUNK / 256; i++) {
    int e = base + i * 256 + t;
    if (e < E) atomicAdd(&hist[col[e] >> 6], 1);
  }
  __syncthreads();
  for (int j = t; j < kNB; j += 256) {
    int v = hist[j];
    hist[j] = v ? atomicAdd(&cursor[j * 8 + sub], v) : 0;  // becomes this block's run start
  }
  __syncthreads();
#pragma unroll 4
  for (int i = 0; i < kCHUNK / 256; i++) {
    int e = base + i * 256 + t;
    if (e < E) {
      int c = col[e];
      int pos = atomicAdd(&hist[c >> 6], 1);  // LDS-only cursor
      edg[pos] = ((unsigned)row[e] << 6) | (unsigned)(c & 63);
    }
  }
}

// Pass C: per-bucket re-sort into exact per-node CSR; emits per-node degree + starts + dis.
__global__ __launch_bounds__(256) void k_passC(const unsigned* __restrict__ edg,
                                               const int* __restrict__ bstarts,
                                               int* __restrict__ deg, int* __restrict__ nstarts,
                                               float* __restrict__ dis,
                                               int* __restrict__ srow, int N) {
  __shared__ int ldeg[64];
  __shared__ int lcur[64];
  int b = blockIdx.x, t = threadIdx.x;
  int s0 = bstarts[b * 8], s1 = bstarts[b * 8 + 8];
  if (t < 64) ldeg[t] = 0;
  __syncthreads();
  for (int i = s0 + t; i < s1; i += 256) atomicAdd(&ldeg[edg[i] & 63u], 1);
  __syncthreads();
  if (t < 64) {
    int own = ldeg[t];
    int incl = own;
#pragma unroll
    for (int off = 1; off < 64; off <<= 1) {
      int o = __shfl_up(incl, off);
      if (t >= off) incl += o;
    }
    int st = s0 + incl - own;
    lcur[t] = st;
    int g = b * 64 + t;
    if (g < N) {
      deg[g] = own;
      nstarts[g] = st;
      dis[g] = rsqrtf((float)(own + 1));
    }
  }
  __syncthreads();
  for (int i = s0 + t; i < s1; i += 256) {
    unsigned ew = edg[i];
    int pos = atomicAdd(&lcur[ew & 63u], 1);
    srow[pos] = (int)(ew >> 6);
  }
}

// ---------------- cluster graph: small CSR path ----------------
__global__ void k_hist(const int* __restrict__ col, int E, int* __restrict__ cnt) {
  int i = blockIdx.x * blockDim.x + threadIdx.x;
  if (i < E) atomicAdd(&cnt[col[i]], 1);
}

__global__ void k_dis(const int* __restrict__ cnt, int N, float* __restrict__ dis) {
  int i = blockIdx.x * blockDim.x + threadIdx.x;
  if (i < N) dis[i] = rsqrtf((float)(cnt[i] + 1));
}

__global__ void k_scan1(const int* __restrict__ cnt, int N, int* __restrict__ starts, int* __restrict__ bsum) {
  __shared__ int s[256];
  int t = threadIdx.x;
  int i = blockIdx.x * 256 + t;
  int v = (i < N) ? cnt[i] : 0;
  s[t] = v;
  __syncthreads();
  for (int o = 1; o < 256; o <<= 1) {
    int x = (t >= o) ? s[t - o] : 0;
    __syncthreads();
    s[t] += x;
    __syncthreads();
  }
  if (i < N) starts[i] = s[t] - v;
  if (t == 255) bsum[blockIdx.x] = s[255];
}

__global__ void k_scan2(int* __restrict__ bsum, int nb) {
  __shared__ int s[256];
  int t = threadIdx.x;
  int run = 0;
  for (int base = 0; base < nb; base += 256) {
    int i = base + t;
    int v = (i < nb) ? bsum[i] : 0;
    s[t] = v;
    __syncthreads();
    for (int o = 1; o < 256; o <<= 1) {
      int x = (t >= o) ? s[t - o] : 0;
      __syncthreads();
      s[t] += x;
      __syncthreads();
    }
    if (i < nb) bsum[i] = run + s[t] - v;
    int tot = s[255];
    __syncthreads();
    run += tot;
  }
}

__global__ void k_scan3(int* __restrict__ starts, int* __restrict__ cursor, const int* __restrict__ bsum, int N) {
  int i = blockIdx.x * 256 + threadIdx.x;
  if (i < N) {
    int v = starts[i] + bsum[blockIdx.x];
    starts[i] = v;
    cursor[i] = v;
  }
}

__global__ void k_scatter(const int* __restrict__ row, const int* __restrict__ col, int E,
                          int* __restrict__ cursor, int* __restrict__ srow) {
  int i = blockIdx.x * blockDim.x + threadIdx.x;
  if (i < E) {
    int pos = atomicAdd(&cursor[col[i]], 1);
    srow[pos] = row[i];
  }
}

// ---------------- z = x * dis  (7 fp32 -> 8 bf16 padded) ----------------
__global__ __launch_bounds__(256) void k_z(const float* __restrict__ x, const float* __restrict__ dis,
                                           unsigned* __restrict__ z, int N) {
  int r = blockIdx.x * 256 + threadIdx.x;
  if (r >= N) return;
  const float* xr = x + (size_t)r * 7;
  float d = dis[r];
  unsigned w0 = (unsigned)f2bf(xr[0] * d) | ((unsigned)f2bf(xr[1] * d) << 16);
  unsigned w1 = (unsigned)f2bf(xr[2] * d) | ((unsigned)f2bf(xr[3] * d) << 16);
  unsigned w2 = (unsigned)f2bf(xr[4] * d) | ((unsigned)f2bf(xr[5] * d) << 16);
  unsigned w3 = (unsigned)f2bf(xr[6] * d);
  uint4 o = {w0, w1, w2, w3};
  *(uint4*)(z + (size_t)r * 4) = o;
}

// ---------------- agg7: a7[c] = dis[c] * (z[c] + sum z[r])  (thread per node, 16B gathers) -------
__global__ __launch_bounds__(256) void k_agg7(const unsigned* __restrict__ z,
                                              const int* __restrict__ starts, const int* __restrict__ cnt,
                                              const int* __restrict__ srow, const float* __restrict__ dis,
                                              unsigned* __restrict__ a7, int N) {
  int c = blockIdx.x * 256 + threadIdx.x;
  if (c >= N) return;
  uint4 v = *(const uint4*)(z + (size_t)c * 4);
  float a0 = bflo(v.x), a1 = bfhi(v.x), a2 = bflo(v.y), a3 = bfhi(v.y);
  float a4 = bflo(v.z), a5 = bfhi(v.z), a6 = bflo(v.w), a7v = bfhi(v.w);
  int s0 = starts[c], n = cnt[c];
  const int* sp = srow + s0;
  int e = 0;
  for (; e + 4 <= n; e += 4) {
    uint4 w0 = *(const uint4*)(z + (size_t)sp[e] * 4);
    uint4 w1 = *(const uint4*)(z + (size_t)sp[e + 1] * 4);
    uint4 w2 = *(const uint4*)(z + (size_t)sp[e + 2] * 4);
    uint4 w3 = *(const uint4*)(z + (size_t)sp[e + 3] * 4);
    a0 += bflo(w0.x) + bflo(w1.x) + bflo(w2.x) + bflo(w3.x);
    a1 += bfhi(w0.x) + bfhi(w1.x) + bfhi(w2.x) + bfhi(w3.x);
    a2 += bflo(w0.y) + bflo(w1.y) + bflo(w2.y) + bflo(w3.y);
    a3 += bfhi(w0.y) + bfhi(w1.y) + bfhi(w2.y) + bfhi(w3.y);
    a4 += bflo(w0.z) + bflo(w1.z) + bflo(w2.z) + bflo(w3.z);
    a5 += bfhi(w0.z) + bfhi(w1.z) + bfhi(w2.z) + bfhi(w3.z);
    a6 += bflo(w0.w) + bflo(w1.w) + bflo(w2.w) + bflo(w3.w);
    a7v += bfhi(w0.w) + bfhi(w1.w) + bfhi(w2.w) + bfhi(w3.w);
  }
  for (; e < n; e++) {
    uint4 w = *(const uint4*)(z + (size_t)sp[e] * 4);
    a0 += bflo(w.x); a1 += bfhi(w.x); a2 += bflo(w.y); a3 += bfhi(w.y);
    a4 += bflo(w.z); a5 += bfhi(w.z); a6 += bflo(w.w); a7v += bfhi(w.w);
  }
  float d = dis[c];
  unsigned o0 = (unsigned)f2bf(a0 * d) | ((unsigned)f2bf(a1 * d) << 16);
  unsigned o1 = (unsigned)f2bf(a2 * d) | ((unsigned)f2bf(a3 * d) << 16);
  unsigned o2 = (unsigned)f2bf(a4 * d) | ((unsigned)f2bf(a5 * d) << 16);
  unsigned o3 = (unsigned)f2bf(a6 * d) | ((unsigned)f2bf(a7v * d) << 16);
  uint4 o = {o0, o1, o2, o3};
  *(uint4*)(a7 + (size_t)c * 4) = o;
}

// ---------------- lin7b: y[c] = relu(a7[c] @ W1 + b1) * dis[c]  (64-dim bf16) ----------------
__global__ __launch_bounds__(256) void k_lin7b(const unsigned* __restrict__ a7, const float* __restrict__ W,
                                               const float* __restrict__ b, const float* __restrict__ dis,
                                               unsigned short* __restrict__ y, int N) {
  __shared__ float Ws[7 * 64];
  int t = threadIdx.x;
  for (int j = t; j < 7 * 64; j += 256) Ws[j] = W[j];
  __syncthreads();
  int idx = blockIdx.x * 256 + t;
  if (idx < N * 32) {
    int r = idx >> 5, c2 = (idx & 31) * 2;
    uint4 v = *(const uint4*)(a7 + (size_t)r * 4);
    float a[7] = {bflo(v.x), bfhi(v.x), bflo(v.y), bfhi(v.y), bflo(v.z), bfhi(v.z), bflo(v.w)};
    float s0 = b[c2], s1 = b[c2 + 1];
#pragma unroll
    for (int k = 0; k < 7; k++) {
      s0 = fmaf(a[k], Ws[k * 64 + c2], s0);
      s1 = fmaf(a[k], Ws[k * 64 + c2 + 1], s1);
    }
    float d = dis[r];
    float y0 = fmaxf(s0, 0.f) * d;
    float y1 = fmaxf(s1, 0.f) * d;
    *(unsigned*)(y + (size_t)r * 64 + c2) = (unsigned)f2bf(y0) | ((unsigned)f2bf(y1) << 16);
  }
}

// ---------------- agg64 (no bias/relu): gt[c] = dis[c] * (y[c] + sum y[r]) ----------------
__device__ __forceinline__ void agg64_body(int bid, int t,
                                           const unsigned short* __restrict__ ys,
                                           const int* __restrict__ starts, const int* __restrict__ cnt,
                                           const int* __restrict__ srow, const float* __restrict__ dis,
                                           unsigned short* __restrict__ out, int N) {
  constexpr int F = 64, LPN = 32;
  int c = bid * (256 / LPN) + t / LPN;
  if (c >= N) return;
  int fi = (t % LPN) * 2;
  unsigned v = *(const unsigned*)(ys + (size_t)c * F + fi);
  float ax = bflo(v), ay = bfhi(v);
  int s0 = starts[c], n = cnt[c];
  const int* sp = srow + s0;
  int e = 0;
  for (; e + 8 <= n; e += 8) {
    int r0 = sp[e], r1 = sp[e + 1], r2 = sp[e + 2], r3 = sp[e + 3];
    int r4 = sp[e + 4], r5 = sp[e + 5], r6 = sp[e + 6], r7 = sp[e + 7];
    unsigned v0 = *(const unsigned*)(ys + (size_t)r0 * F + fi);
    unsigned v1 = *(const unsigned*)(ys + (size_t)r1 * F + fi);
    unsigned v2 = *(const unsigned*)(ys + (size_t)r2 * F + fi);
    unsigned v3 = *(const unsigned*)(ys + (size_t)r3 * F + fi);
    unsigned v4 = *(const unsigned*)(ys + (size_t)r4 * F + fi);
    unsigned v5 = *(const unsigned*)(ys + (size_t)r5 * F + fi);
    unsigned v6 = *(const unsigned*)(ys + (size_t)r6 * F + fi);
    unsigned v7 = *(const unsigned*)(ys + (size_t)r7 * F + fi);
    ax += bflo(v0) + bflo(v1) + bflo(v2) + bflo(v3) + bflo(v4) + bflo(v5) + bflo(v6) + bflo(v7);
    ay += bfhi(v0) + bfhi(v1) + bfhi(v2) + bfhi(v3) + bfhi(v4) + bfhi(v5) + bfhi(v6) + bfhi(v7);
  }
  for (; e + 4 <= n; e += 4) {
    int r0 = sp[e], r1 = sp[e + 1], r2 = sp[e + 2], r3 = sp[e + 3];
    unsigned v0 = *(const unsigned*)(ys + (size_t)r0 * F + fi);
    unsigned v1 = *(const unsigned*)(ys + (size_t)r1 * F + fi);
    unsigned v2 = *(const unsigned*)(ys + (size_t)r2 * F + fi);
    unsigned v3 = *(const unsigned*)(ys + (size_t)r3 * F + fi);
    ax += bflo(v0) + bflo(v1) + bflo(v2) + bflo(v3);
    ay += bfhi(v0) + bfhi(v1) + bfhi(v2) + bfhi(v3);
  }
  for (; e < n; e++) {
    unsigned vv = *(const unsigned*)(ys + (size_t)sp[e] * F + fi);
    ax += bflo(vv);
    ay += bfhi(vv);
  }
  float d = dis[c];
  *(unsigned*)(out + (size_t)c * F + fi) = (unsigned)f2bf(ax * d) | ((unsigned)f2bf(ay * d) << 16);
}

__global__ __launch_bounds__(256) void k_agg64(const unsigned short* __restrict__ ys,
                                               const int* __restrict__ starts, const int* __restrict__ cnt,
                                               const int* __restrict__ srow, const float* __restrict__ dis,
                                               unsigned short* __restrict__ out, int N) {
  agg64_body(blockIdx.x, threadIdx.x, ys, starts, cnt, srow, dis, out, N);
}

// ---------------- lin64x128: out[c] = relu(gt[c] @ W + b)  (bf16, 32 rows/block) ----------------
__global__ __launch_bounds__(256) void k_lin64x128(const unsigned short* __restrict__ xin, const float* __restrict__ W,
                                                   const float* __restrict__ b, unsigned short* __restrict__ hs, int N) {
  __shared__ float Ws[64 * 128];
  __shared__ float xs[32][64];
  int t = threadIdx.x;
  for (int j = t; j < 64 * 128; j += 256) Ws[j] = W[j];
  int r0 = blockIdx.x * 32;
  for (int j = t; j < 32 * 64; j += 256) {
    int r = j >> 6, k = j & 63;
    int gr = r0 + r;
    xs[r][k] = (gr < N) ? bf2f(xin[(size_t)gr * 64 + k]) : 0.f;
  }
  __syncthreads();
  int c = t & 63;
  int rb = (t >> 6) * 8;
  float a0[8], a1[8];
#pragma unroll
  for (int rr = 0; rr < 8; rr++) { a0[rr] = 0.f; a1[rr] = 0.f; }
  for (int k = 0; k < 64; k++) {
    float w0 = Ws[k * 128 + c];
    float w1 = Ws[k * 128 + c + 64];
#pragma unroll
    for (int rr = 0; rr < 8; rr++) {
      float xv = xs[rb + rr][k];
      a0[rr] = fmaf(xv, w0, a0[rr]);
      a1[rr] = fmaf(xv, w1, a1[rr]);
    }
  }
  float bb0 = b[c], bb1 = b[c + 64];
#pragma unroll
  for (int rr = 0; rr < 8; rr++) {
    int gr = r0 + rb + rr;
    if (gr < N) {
      hs[(size_t)gr * 128 + c] = f2bf(fmaxf(a0[rr] + bb0, 0.f));
      hs[(size_t)gr * 128 + c + 64] = f2bf(fmaxf(a1[rr] + bb1, 0.f));
    }
  }
}

// ---------------- combined B-operand pack: Bq (from xc2b), A1p, Bh ----------------
__global__ void k_pack_all(const unsigned short* __restrict__ xc2b, const float* __restrict__ A1,
                           const float* __restrict__ D1, const float* __restrict__ Wcls,
                           short* __restrict__ Bq, short* __restrict__ A1p, short* __restrict__ Bh) {
  int i = blockIdx.x * 256 + threadIdx.x;
  if (i < 512 * 128) {
    int e = i;
    int k = e >> 7, n = e & 127;
    int frag = (k >> 5) * 8 + (n >> 4);
    int l = (n & 15) | (((k >> 3) & 3) << 4);
    int j = k & 7;
    Bq[(size_t)frag * 512 + l * 8 + j] = (short)xc2b[e];
  } else if (i < 512 * 128 + 256 * 128) {
    int e = i - 512 * 128;
    int k = e >> 7, n = e & 127;
    int frag = (k >> 5) * 8 + (n >> 4);
    int l = (n & 15) | (((k >> 3) & 3) << 4);
    int j = k & 7;
    A1p[(size_t)frag * 512 + l * 8 + j] = (short)f2bf(A1[e]);
  } else if (i < 512 * 128 + 256 * 128 + 128 * 80) {
    int e = i - (512 * 128 + 256 * 128);
    int k = e / 80, n = e % 80;
    float v = 0.f;
    if (n < 64) v = D1[k * 64 + n];
    else if (n < 73) v = Wcls[k * 9 + (n - 64)];
    int frag = (k >> 5) * 5 + (n >> 4);
    int l = (n & 15) | (((k >> 3) & 3) << 4);
    int j = k & 7;
    Bh[(size_t)frag * 512 + l * 8 + j] = (short)f2bf(v);
  }
}

__device__ __forceinline__ short8 zero8() {
  short8 z;
#pragma unroll
  for (int j = 0; j < 8; j++) z[j] = 0;
  return z;
}

__device__ __forceinline__ short8 cvt8(float4 v0, float4 v1) {
  short8 r;
  r[0] = (short)f2bf(v0.x); r[1] = (short)f2bf(v0.y); r[2] = (short)f2bf(v0.z); r[3] = (short)f2bf(v0.w);
  r[4] = (short)f2bf(v1.x); r[5] = (short)f2bf(v1.y); r[6] = (short)f2bf(v1.z); r[7] = (short)f2bf(v1.w);
  return r;
}

__device__ __forceinline__ short8 load_a_f32(const float* p, bool ok) {
  if (!ok) return zero8();
  return cvt8(*(const float4*)p, *(const float4*)(p + 4));
}

// ---------------- gemm_q body (64 rows/block, 16 rows/wave, reg double-buffered) ----------------
__device__ __forceinline__ void gemm_q_body(int bid, int t, const float* __restrict__ Q,
                                            const short* __restrict__ Bp,
                                            unsigned short* __restrict__ outb, int M) {
  int lane = t & 63;
  int wid = t >> 6;
  int m0 = bid * 64 + wid * 16;
  int mrow = lane & 15;
  int kg = lane >> 4;
  f32x4 acc[8];
#pragma unroll
  for (int nf = 0; nf < 8; nf++) acc[nf] = (f32x4){0.f, 0.f, 0.f, 0.f};
  int r0 = m0 + mrow;
  bool ok = r0 < M;
  const float* ap = Q + (size_t)r0 * 512 + kg * 8;
  const short* bl = Bp + lane * 8;
  float4 z4 = {0.f, 0.f, 0.f, 0.f};
  float4 v0 = ok ? *(const float4*)ap : z4;
  float4 v1 = ok ? *(const float4*)(ap + 4) : z4;
  for (int ks = 0; ks < 16; ks++) {
    float4 n0 = z4, n1 = z4;
    if (ks < 15 && ok) {
      n0 = *(const float4*)(ap + (ks + 1) * 32);
      n1 = *(const float4*)(ap + (ks + 1) * 32 + 4);
    }
    short8 a = cvt8(v0, v1);
    const short* bb = bl + (ks << 12);
#pragma unroll
    for (int nf = 0; nf < 8; nf++) {
      short8 b = *(const short8*)(bb + (nf << 9));
      acc[nf] = __builtin_amdgcn_mfma_f32_16x16x32_bf16(a, b, acc[nf], 0, 0, 0);
    }
    v0 = n0;
    v1 = n1;
  }
  int col = lane & 15;
  int g = lane >> 4;
#pragma unroll
  for (int nf = 0; nf < 8; nf++)
#pragma unroll
    for (int r = 0; r < 4; r++) {
      int row = m0 + g * 4 + r;
      if (row < M) outb[(size_t)row * 128 + nf * 16 + col] = f2bf(acc[nf][r]);
    }
}

// ---------------- FAT kernel: gemm_q blocks first, then agg64 blocks (independent work) --------
__global__ __launch_bounds__(256) void k_aggq(const float* __restrict__ Q, const short* __restrict__ Bp,
                                              unsigned short* __restrict__ xcdb,
                                              const unsigned short* __restrict__ ys,
                                              const int* __restrict__ starts, const int* __restrict__ cnt,
                                              const int* __restrict__ srow, const float* __restrict__ dis,
                                              unsigned short* __restrict__ gt, int M) {
  int bid = blockIdx.x, t = threadIdx.x;
  if (bid < kGemmQBlocks) {
    gemm_q_body(bid, t, Q, Bp, xcdb, M);
  } else {
    agg64_body(bid - kGemmQBlocks, t, ys, starts, cnt, srow, dis, gt, M);
  }
}

// ---------------- GEMM2 (MFMA) + gate epilogue (64 rows/block, 16 rows/wave) ----------------
__global__ __launch_bounds__(256) void k_gemm_fuse_mfma(const unsigned short* __restrict__ Xs,
                                                        const unsigned short* __restrict__ Xc,
                                                        const short* __restrict__ A1p, const float* __restrict__ ab1,
                                                        const float* __restrict__ A2, const float* __restrict__ ab2,
                                                        float* __restrict__ fused, int M) {
  int t = threadIdx.x;
  int lane = t & 63;
  int wid = t >> 6;
  int m0 = blockIdx.x * 64 + wid * 16;
  int mrow = lane & 15;
  int kg = lane >> 4;
  f32x4 acc[8];
#pragma unroll
  for (int nf = 0; nf < 8; nf++) acc[nf] = (f32x4){0.f, 0.f, 0.f, 0.f};
  int r0 = m0 + mrow;
  bool ok = r0 < M;
  const short* bl = A1p + lane * 8;
  short8 a = ok ? *(const short8*)(Xs + (size_t)r0 * 128 + kg * 8) : zero8();
  for (int ks = 0; ks < 8; ks++) {
    short8 an = zero8();
    if (ks < 7 && ok) {
      int ks1 = ks + 1;
      const unsigned short* src = (ks1 < 4) ? Xs : Xc;
      an = *(const short8*)(src + (size_t)r0 * 128 + (ks1 & 3) * 32 + kg * 8);
    }
    const short* bb = bl + (ks << 12);
#pragma unroll
    for (int nf = 0; nf < 8; nf++) {
      short8 b = *(const short8*)(bb + (nf << 9));
      acc[nf] = __builtin_amdgcn_mfma_f32_16x16x32_bf16(a, b, acc[nf], 0, 0, 0);
    }
    a = an;
  }
  int col16 = lane & 15;
  int g = lane >> 4;
  float bias[8], w20[8], w21[8];
#pragma unroll
  for (int nf = 0; nf < 8; nf++) {
    int cc = nf * 16 + col16;
    bias[nf] = ab1[cc];
    w20[nf] = A2[2 * cc];
    w21[nf] = A2[2 * cc + 1];
  }
  float b20 = ab2[0], b21 = ab2[1];
#pragma unroll
  for (int r = 0; r < 4; r++) {
    float u0 = 0.f, u1 = 0.f;
#pragma unroll
    for (int nf = 0; nf < 8; nf++) {
      float tv = fmaxf(acc[nf][r] + bias[nf], 0.f);
      u0 = fmaf(tv, w20[nf], u0);
      u1 = fmaf(tv, w21[nf], u1);
    }
#pragma unroll
    for (int off = 1; off < 16; off <<= 1) {
      u0 += __shfl_xor(u0, off);
      u1 += __shfl_xor(u1, off);
    }
    int row = m0 + g * 4 + r;
    if (row < M) {
      float ua = u0 + b20, ub = u1 + b21;
      float mx = fmaxf(ua, ub);
      float e0 = __expf(ua - mx), e1 = __expf(ub - mx);
      float inv = 1.f / (e0 + e1);
      float w0 = e0 * inv, w1 = e1 * inv;
      int p = col16;
      const unsigned short* xsp = Xs + (size_t)row * 128 + p * 8;
      const unsigned short* xcp = Xc + (size_t)row * 128 + p * 8;
      float* op = fused + (size_t)row * 128 + p * 8;
      float4 o0, o1;
      unsigned sx0 = *(const unsigned*)(xsp + 0), sx1 = *(const unsigned*)(xsp + 2);
      unsigned sx2 = *(const unsigned*)(xsp + 4), sx3 = *(const unsigned*)(xsp + 6);
      unsigned cx0 = *(const unsigned*)(xcp + 0), cx1 = *(const unsigned*)(xcp + 2);
      unsigned cx2 = *(const unsigned*)(xcp + 4), cx3 = *(const unsigned*)(xcp + 6);
      o0.x = w0 * bflo(sx0) + w1 * bflo(cx0);
      o0.y = w0 * bfhi(sx0) + w1 * bfhi(cx0);
      o0.z = w0 * bflo(sx1) + w1 * bflo(cx1);
      o0.w = w0 * bfhi(sx1) + w1 * bfhi(cx1);
      o1.x = w0 * bflo(sx2) + w1 * bflo(cx2);
      o1.y = w0 * bfhi(sx2) + w1 * bfhi(cx2);
      o1.z = w0 * bflo(sx3) + w1 * bflo(cx3);
      o1.w = w0 * bfhi(sx3) + w1 * bfhi(cx3);
      *(float4*)op = o0;
      *(float4*)(op + 4) = o1;
    }
  }
}

// ---------------- heads (MFMA): [class | domain] from fused[M,128] ----------------
__global__ __launch_bounds__(256) void k_final_mfma(const float* __restrict__ fused, const short* __restrict__ Bh,
                                                    const float* __restrict__ bcls, const float* __restrict__ db1,
                                                    const float* __restrict__ D2, const float* __restrict__ db2,
                                                    float* __restrict__ cls_out, float* __restrict__ dom_out, int M) {
  int t = threadIdx.x;
  int lane = t & 63;
  int wid = t >> 6;
  int m0 = blockIdx.x * 128 + wid * 32;
  int mrow = lane & 15;
  int kg = lane >> 4;
  f32x4 acc[2][5];
#pragma unroll
  for (int mi = 0; mi < 2; mi++)
#pragma unroll
    for (int nf = 0; nf < 5; nf++) acc[mi][nf] = (f32x4){0.f, 0.f, 0.f, 0.f};
  int r0 = m0 + mrow, r1 = m0 + 16 + mrow;
  bool ok0 = r0 < M, ok1 = r1 < M;
  const float* a0p = fused + (size_t)r0 * 128 + kg * 8;
  const float* a1p = fused + (size_t)r1 * 128 + kg * 8;
  const short* bl = Bh + lane * 8;
  for (int ks = 0; ks < 4; ks++) {
    short8 a0 = load_a_f32(a0p + ks * 32, ok0);
    short8 a1 = load_a_f32(a1p + ks * 32, ok1);
    const short* bb = bl + ks * 5 * 512;
#pragma unroll
    for (int nf = 0; nf < 5; nf++) {
      short8 b = *(const short8*)(bb + (nf << 9));
      acc[0][nf] = __builtin_amdgcn_mfma_f32_16x16x32_bf16(a0, b, acc[0][nf], 0, 0, 0);
      acc[1][nf] = __builtin_amdgcn_mfma_f32_16x16x32_bf16(a1, b, acc[1][nf], 0, 0, 0);
    }
  }
  int col16 = lane & 15;
  int g = lane >> 4;
  float bh[4], d20[4], d21[4];
#pragma unroll
  for (int nf = 0; nf < 4; nf++) {
    int h = col16 + 16 * nf;
    bh[nf] = db1[h];
    d20[nf] = D2[h * 2];
    d21[nf] = D2[h * 2 + 1];
  }
  float bc = (col16 < 9) ? bcls[col16] : 0.f;
  float b20 = db2[0], b21 = db2[1];
#pragma unroll
  for (int mi = 0; mi < 2; mi++) {
#pragma unroll
    for (int r = 0; r < 4; r++) {
      float p0 = 0.f, p1 = 0.f;
#pragma unroll
      for (int nf = 0; nf < 4; nf++) {
        float hv = fmaxf(acc[mi][nf][r] + bh[nf], 0.f);
        p0 = fmaf(hv, d20[nf], p0);
        p1 = fmaf(hv, d21[nf], p1);
      }
#pragma unroll
      for (int off = 1; off < 16; off <<= 1) {
        p0 += __shfl_xor(p0, off);
        p1 += __shfl_xor(p1, off);
      }
      int row = m0 + mi * 16 + g * 4 + r;
      if (row < M) {
        if (col16 < 9) cls_out[(size_t)row * 9 + col16] = acc[mi][4][r] + bc;
        if (col16 == 0) {
          dom_out[(size_t)row * 2 + 0] = p0 + b20;
          dom_out[(size_t)row * 2 + 1] = p1 + b21;
        }
      }
    }
  }
}

extern "C" void kernel_launch(void* const* d_in, const int* in_sizes, int n_in,
                              void* d_out, int out_size, void* d_ws, size_t ws_size,
                              hipStream_t stream) {
  const float* x_s = (const float*)d_in[0];
  const float* x_c = (const float*)d_in[1];
  const float* Q = (const float*)d_in[2];
  const int* eis = (const int*)d_in[3];
  const int* eic = (const int*)d_in[4];
  const float* W1s = (const float*)d_in[5];
  const float* b1s = (const float*)d_in[6];
  const float* W2s = (const float*)d_in[7];
  const float* b2s = (const float*)d_in[8];
  const float* W1c = (const float*)d_in[9];
  const float* b1c = (const float*)d_in[10];
  const float* W2c = (const float*)d_in[11];
  const float* b2c = (const float*)d_in[12];
  const float* A1 = (const float*)d_in[13];
  const float* ab1 = (const float*)d_in[14];
  const float* A2 = (const float*)d_in[15];
  const float* ab2 = (const float*)d_in[16];
  const float* Wcls = (const float*)d_in[17];
  const float* bcls = (const float*)d_in[18];
  const float* D1 = (const float*)d_in[19];
  const float* db1 = (const float*)d_in[20];
  const float* D2 = (const float*)d_in[21];
  const float* db2 = (const float*)d_in[22];

  float* out_cls = (float*)d_out;
  float* out_dom = out_cls + (size_t)kNS * 9;
  float* out_fus = out_dom + (size_t)kNS * 2;

  char* p = (char*)d_ws;
  auto alloc = [&](size_t bytes) -> void* {
    void* r = (void*)p;
    p += (bytes + 255) & ~(size_t)255;
    return r;
  };
  // sample graph
  int* deg_s = (int*)alloc((size_t)kNS * 4);
  float* dis_s = (float*)alloc((size_t)kNS * 4);
  int* nstarts_s = (int*)alloc((size_t)kNS * 4);
  int* counts_s = (int*)alloc((size_t)kNB8 * 4);
  int* bstarts_s = (int*)alloc((size_t)(kNB8 + 1) * 4);
  int* bcursor_s = (int*)alloc((size_t)kNB8 * 4);
  int* srow_s = (int*)alloc((size_t)kES * 4);    // dedicated (fat kernel)
  unsigned* edg_s = (unsigned*)alloc((size_t)kES * 4);
  // cluster graph
  int* deg_c = (int*)alloc((size_t)kNC * 4);
  int* cstarts_c = (int*)alloc((size_t)kNC * 4);
  int* cursor_c = (int*)alloc((size_t)kNC * 4);
  int* bsum_c = (int*)alloc(512 * 4);
  float* dis_c = (float*)alloc((size_t)kNC * 4);
  int* srow_c = (int*)alloc((size_t)kEC * 4);
  // sample feature buffers
  unsigned* zs = (unsigned*)alloc((size_t)kNS * 16);     // 8 bf16/node
  unsigned* a7s = (unsigned*)alloc((size_t)kNS * 16);
  unsigned short* ys = (unsigned short*)alloc((size_t)kNS * 64 * 2);
  unsigned short* gts = (unsigned short*)alloc((size_t)kNS * 64 * 2);
  unsigned short* xs2b = (unsigned short*)alloc((size_t)kNS * 128 * 2);
  unsigned short* xcdb = (unsigned short*)alloc((size_t)kNS * 128 * 2);
  // cluster feature buffers
  unsigned* zc = (unsigned*)alloc((size_t)kNC * 16);
  unsigned* a7c = (unsigned*)alloc((size_t)kNC * 16);
  unsigned short* yc = (unsigned short*)alloc((size_t)kNC * 64 * 2);
  unsigned short* gtc = (unsigned short*)alloc((size_t)kNC * 64 * 2);
  unsigned short* xc2b = (unsigned short*)alloc((size_t)kNC * 128 * 2);
  // packed B operands
  short* Bq = (short*)alloc((size_t)512 * 128 * 2);
  short* A1p = (short*)alloc((size_t)256 * 128 * 2);
  short* Bh = (short*)alloc((size_t)128 * 80 * 2);
  (void)ws_size; (void)in_sizes; (void)n_in; (void)out_size;

  hipMemsetAsync(counts_s, 0, (size_t)kNB8 * 4, stream);
  hipMemsetAsync(deg_c, 0, (size_t)kNC * 4, stream);

  const int nbC = (kNC + 255) / 256;
  const int nbS = (kNS + 255) / 256;

  // sample-graph grouping: bucket histogram -> scan -> reserved append -> per-node re-sort
  k_passA<<<kNBLK, 256, 0, stream>>>(eis + kES, kES, counts_s);
  k_scan_flat<<<1, 256, 0, stream>>>(counts_s, kNB8, bstarts_s, bcursor_s);
  k_passB<<<kNBLK, 256, 0, stream>>>(eis, eis + kES, kES, bcursor_s, edg_s);
  k_passC<<<kNB, 256, 0, stream>>>(edg_s, bstarts_s, deg_s, nstarts_s, dis_s, srow_s, kNS);

  // cluster-graph CSR
  k_hist<<<(kEC + 255) / 256, 256, 0, stream>>>(eic + kEC, kEC, deg_c);
  k_dis<<<nbC, 256, 0, stream>>>(deg_c, kNC, dis_c);
  k_scan1<<<nbC, 256, 0, stream>>>(deg_c, kNC, cstarts_c, bsum_c);
  k_scan2<<<1, 256, 0, stream>>>(bsum_c, nbC);
  k_scan3<<<nbC, 256, 0, stream>>>(cstarts_c, cursor_c, bsum_c, kNC);
  k_scatter<<<(kEC + 255) / 256, 256, 0, stream>>>(eic, eic + kEC, kEC, cursor_c, srow_c);

  // cluster branch (aggregate-then-transform)
  k_z<<<(kNC + 255) / 256, 256, 0, stream>>>(x_c, dis_c, zc, kNC);
  k_agg7<<<(kNC + 255) / 256, 256, 0, stream>>>(zc, cstarts_c, deg_c, srow_c, dis_c, a7c, kNC);
  k_lin7b<<<(kNC * 32 + 255) / 256, 256, 0, stream>>>(a7c, W1c, b1c, dis_c, yc, kNC);
  k_agg64<<<(kNC + 7) / 8, 256, 0, stream>>>(yc, cstarts_c, deg_c, srow_c, dis_c, gtc, kNC);
  k_lin64x128<<<(kNC + 31) / 32, 256, 0, stream>>>(gtc, W2c, b2c, xc2b, kNC);
  k_pack_all<<<(512 * 128 + 256 * 128 + 128 * 80 + 255) / 256, 256, 0, stream>>>(xc2b, A1, D1, Wcls, Bq, A1p, Bh);

  // sample branch (aggregate-then-transform)
  k_z<<<nbS, 256, 0, stream>>>(x_s, dis_s, zs, kNS);
  k_agg7<<<nbS, 256, 0, stream>>>(zs, nstarts_s, deg_s, srow_s, dis_s, a7s, kNS);
  k_lin7b<<<(kNS * 32 + 255) / 256, 256, 0, stream>>>(a7s, W1s, b1s, dis_s, ys, kNS);

  // FAT: gemm_q (decode) || agg64 (sample layer-2 aggregation)
  k_aggq<<<kGemmQBlocks + kAgg64Blocks, 256, 0, stream>>>(Q, Bq, xcdb,
                                                          ys, nstarts_s, deg_s, srow_s, dis_s, gts, kNS);

  k_lin64x128<<<(kNS + 31) / 32, 256, 0, stream>>>(gts, W2s, b2s, xs2b, kNS);

  // fusion gate + heads
  k_gemm_fuse_mfma<<<(kNS + 63) / 64, 256, 0, stream>>>(xs2b, xcdb, A1p, ab1, A2, ab2, out_fus, kNS);
  k_final_mfma<<<(kNS + 127) / 128, 256, 0, stream>>>(out_fus, Bh, bcls, db1, D2, db2, out_cls, out_dom, kNS);
}

// Round 10
// 480.239 us; speedup vs baseline: 9.2785x; 1.0180x over previous
//
#include <hip/hip_runtime.h>
#include <cstdint>
#include <cstddef>

static constexpr int kNS = 100000;
static constexpr int kNC = 512;
static constexpr int kES = 3200000;
static constexpr int kEC = 16384;

static constexpr int kNB = (kNS + 63) / 64;        // 1563 coarse buckets (64 nodes each)
static constexpr int kNB8 = kNB * 8;               // sub-bucketed counters
static constexpr int kCHUNK = 8192;                // edges per block in passA/passB
static constexpr int kNBLK = (kES + kCHUNK - 1) / kCHUNK;  // 391 blocks

static constexpr int kGemmQBlocks = (kNS + 63) / 64;   // 1563
static constexpr int kAgg64Blocks = (kNS + 7) / 8;     // 12500
static constexpr int kG1 = 625;                        // gemm blocks paired with passB
static constexpr int kG2 = 469;                        // gemm blocks paired with passC
static constexpr int kG3 = kGemmQBlocks - kG1 - kG2;   // 469, paired with agg64

typedef __attribute__((ext_vector_type(8))) short short8;
typedef __attribute__((ext_vector_type(4))) float f32x4;

__device__ __forceinline__ unsigned short f2bf(float f) {
  union { float f; unsigned u; } v; v.f = f;
  unsigned u = v.u;
  unsigned r = (u + 0x7fffu + ((u >> 16) & 1u)) >> 16;
  return (unsigned short)r;
}
__device__ __forceinline__ float bflo(unsigned v) { return __uint_as_float(v << 16); }
__device__ __forceinline__ float bfhi(unsigned v) { return __uint_as_float(v & 0xffff0000u); }
__device__ __forceinline__ float bf2f(unsigned short s) { return __uint_as_float(((unsigned)s) << 16); }

// ---------------- sample graph: bucket histogram (1 global atomic per touched bucket) ----------------
__global__ __launch_bounds__(256) void k_passA(const int* __restrict__ col, int E,
                                               int* __restrict__ counts) {
  __shared__ int hist[kNB];
  int t = threadIdx.x, bid = blockIdx.x;
  for (int j = t; j < kNB; j += 256) hist[j] = 0;
  __syncthreads();
  int base = bid * kCHUNK;
#pragma unroll 4
  for (int i = 0; i < kCHUNK / 256; i++) {
    int e = base + i * 256 + t;
    if (e < E) atomicAdd(&hist[col[e] >> 6], 1);
  }
  __syncthreads();
  int sub = bid & 7;
  for (int j = t; j < kNB; j += 256) {
    int v = hist[j];
    if (v) atomicAdd(&counts[j * 8 + sub], v);
  }
}

// exclusive scan of n flat counters -> starts[n+1], cursor copy (+ optional dis from counts)
__global__ void k_scan_flat(const int* __restrict__ cnt, int n, int* __restrict__ starts,
                            int* __restrict__ cursor, float* __restrict__ dis) {
  __shared__ int s[256];
  int t = threadIdx.x;
  int run = 0;
  for (int base = 0; base < n; base += 256) {
    int i = base + t;
    int v = (i < n) ? cnt[i] : 0;
    s[t] = v;
    __syncthreads();
    for (int o = 1; o < 256; o <<= 1) {
      int x = (t >= o) ? s[t - o] : 0;
      __syncthreads();
      s[t] += x;
      __syncthreads();
    }
    if (i < n) {
      int ex = run + s[t] - v;
      starts[i] = ex;
      cursor[i] = ex;
      if (dis) dis[i] = rsqrtf((float)(v + 1));
    }
    int tot = s[255];
    __syncthreads();
    run += tot;
  }
  if (t == 0) starts[n] = run;
}

// Pass B body: LDS-hist -> per-bucket range reservation (1 global atomic each) -> LDS-cursor append.
__device__ __forceinline__ void passB_body(int bid, int t, const int* __restrict__ row,
                                           const int* __restrict__ col, int E,
                                           int* __restrict__ cursor, unsigned* __restrict__ edg) {
  __shared__ int hist[kNB];
  int sub = bid & 7;
  for (int j = t; j < kNB; j += 256) hist[j] = 0;
  __syncthreads();
  int base = bid * kCHUNK;
#pragma unroll 4
  for (int i = 0; i < kCHUNK / 256; i++) {
    int e = base + i * 256 + t;
    if (e < E) atomicAdd(&hist[col[e] >> 6], 1);
  }
  __syncthreads();
  for (int j = t; j < kNB; j += 256) {
    int v = hist[j];
    hist[j] = v ? atomicAdd(&cursor[j * 8 + sub], v) : 0;
  }
  __syncthreads();
#pragma unroll 4
  for (int i = 0; i < kCHUNK / 256; i++) {
    int e = base + i * 256 + t;
    if (e < E) {
      int c = col[e];
      int pos = atomicAdd(&hist[c >> 6], 1);
      edg[pos] = ((unsigned)row[e] << 6) | (unsigned)(c & 63);
    }
  }
}

// Pass C body: per-bucket re-sort into per-node CSR; emits degree + starts + dis + z = x*dis (bf16x8).
__device__ __forceinline__ void passC_body(int b, int t, const unsigned* __restrict__ edg,
                                           const int* __restrict__ bstarts,
                                           int* __restrict__ deg, int* __restrict__ nstarts,
                                           float* __restrict__ dis, int* __restrict__ srow,
                                           const float* __restrict__ x, unsigned* __restrict__ z, int N) {
  __shared__ int ldeg[64];
  __shared__ int lcur[64];
  int s0 = bstarts[b * 8], s1 = bstarts[b * 8 + 8];
  if (t < 64) ldeg[t] = 0;
  __syncthreads();
  for (int i = s0 + t; i < s1; i += 256) atomicAdd(&ldeg[edg[i] & 63u], 1);
  __syncthreads();
  if (t < 64) {
    int own = ldeg[t];
    int incl = own;
#pragma unroll
    for (int off = 1; off < 64; off <<= 1) {
      int o = __shfl_up(incl, off);
      if (t >= off) incl += o;
    }
    int st = s0 + incl - own;
    lcur[t] = st;
    int g = b * 64 + t;
    if (g < N) {
      deg[g] = own;
      nstarts[g] = st;
      float d = rsqrtf((float)(own + 1));
      dis[g] = d;
      const float* xr = x + (size_t)g * 7;
      unsigned w0 = (unsigned)f2bf(xr[0] * d) | ((unsigned)f2bf(xr[1] * d) << 16);
      unsigned w1 = (unsigned)f2bf(xr[2] * d) | ((unsigned)f2bf(xr[3] * d) << 16);
      unsigned w2 = (unsigned)f2bf(xr[4] * d) | ((unsigned)f2bf(xr[5] * d) << 16);
      unsigned w3 = (unsigned)f2bf(xr[6] * d);
      uint4 o = {w0, w1, w2, w3};
      *(uint4*)(z + (size_t)g * 4) = o;
    }
  }
  __syncthreads();
  for (int i = s0 + t; i < s1; i += 256) {
    unsigned ew = edg[i];
    int pos = atomicAdd(&lcur[ew & 63u], 1);
    srow[pos] = (int)(ew >> 6);
  }
}

// ---------------- cluster graph helpers ----------------
__global__ void k_hist(const int* __restrict__ col, int E, int* __restrict__ cnt) {
  int i = blockIdx.x * blockDim.x + threadIdx.x;
  if (i < E) atomicAdd(&cnt[col[i]], 1);
}

__global__ void k_scatter(const int* __restrict__ row, const int* __restrict__ col, int E,
                          int* __restrict__ cursor, int* __restrict__ srow) {
  int i = blockIdx.x * blockDim.x + threadIdx.x;
  if (i < E) {
    int pos = atomicAdd(&cursor[col[i]], 1);
    srow[pos] = row[i];
  }
}

// ---------------- z = x * dis  (7 fp32 -> 8 bf16 padded) — cluster only ----------------
__global__ __launch_bounds__(256) void k_z(const float* __restrict__ x, const float* __restrict__ dis,
                                           unsigned* __restrict__ z, int N) {
  int r = blockIdx.x * 256 + threadIdx.x;
  if (r >= N) return;
  const float* xr = x + (size_t)r * 7;
  float d = dis[r];
  unsigned w0 = (unsigned)f2bf(xr[0] * d) | ((unsigned)f2bf(xr[1] * d) << 16);
  unsigned w1 = (unsigned)f2bf(xr[2] * d) | ((unsigned)f2bf(xr[3] * d) << 16);
  unsigned w2 = (unsigned)f2bf(xr[4] * d) | ((unsigned)f2bf(xr[5] * d) << 16);
  unsigned w3 = (unsigned)f2bf(xr[6] * d);
  uint4 o = {w0, w1, w2, w3};
  *(uint4*)(z + (size_t)r * 4) = o;
}

// ---------------- agg7: a7[c] = dis[c] * (z[c] + sum z[r]) ----------------
__global__ __launch_bounds__(256) void k_agg7(const unsigned* __restrict__ z,
                                              const int* __restrict__ starts, const int* __restrict__ cnt,
                                              const int* __restrict__ srow, const float* __restrict__ dis,
                                              unsigned* __restrict__ a7, int N) {
  int c = blockIdx.x * 256 + threadIdx.x;
  if (c >= N) return;
  uint4 v = *(const uint4*)(z + (size_t)c * 4);
  float a0 = bflo(v.x), a1 = bfhi(v.x), a2 = bflo(v.y), a3 = bfhi(v.y);
  float a4 = bflo(v.z), a5 = bfhi(v.z), a6 = bflo(v.w), a7v = bfhi(v.w);
  int s0 = starts[c], n = cnt[c];
  const int* sp = srow + s0;
  int e = 0;
  for (; e + 4 <= n; e += 4) {
    uint4 w0 = *(const uint4*)(z + (size_t)sp[e] * 4);
    uint4 w1 = *(const uint4*)(z + (size_t)sp[e + 1] * 4);
    uint4 w2 = *(const uint4*)(z + (size_t)sp[e + 2] * 4);
    uint4 w3 = *(const uint4*)(z + (size_t)sp[e + 3] * 4);
    a0 += bflo(w0.x) + bflo(w1.x) + bflo(w2.x) + bflo(w3.x);
    a1 += bfhi(w0.x) + bfhi(w1.x) + bfhi(w2.x) + bfhi(w3.x);
    a2 += bflo(w0.y) + bflo(w1.y) + bflo(w2.y) + bflo(w3.y);
    a3 += bfhi(w0.y) + bfhi(w1.y) + bfhi(w2.y) + bfhi(w3.y);
    a4 += bflo(w0.z) + bflo(w1.z) + bflo(w2.z) + bflo(w3.z);
    a5 += bfhi(w0.z) + bfhi(w1.z) + bfhi(w2.z) + bfhi(w3.z);
    a6 += bflo(w0.w) + bflo(w1.w) + bflo(w2.w) + bflo(w3.w);
    a7v += bfhi(w0.w) + bfhi(w1.w) + bfhi(w2.w) + bfhi(w3.w);
  }
  for (; e < n; e++) {
    uint4 w = *(const uint4*)(z + (size_t)sp[e] * 4);
    a0 += bflo(w.x); a1 += bfhi(w.x); a2 += bflo(w.y); a3 += bfhi(w.y);
    a4 += bflo(w.z); a5 += bfhi(w.z); a6 += bflo(w.w); a7v += bfhi(w.w);
  }
  float d = dis[c];
  unsigned o0 = (unsigned)f2bf(a0 * d) | ((unsigned)f2bf(a1 * d) << 16);
  unsigned o1 = (unsigned)f2bf(a2 * d) | ((unsigned)f2bf(a3 * d) << 16);
  unsigned o2 = (unsigned)f2bf(a4 * d) | ((unsigned)f2bf(a5 * d) << 16);
  unsigned o3 = (unsigned)f2bf(a6 * d) | ((unsigned)f2bf(a7v * d) << 16);
  uint4 o = {o0, o1, o2, o3};
  *(uint4*)(a7 + (size_t)c * 4) = o;
}

// ---------------- lin7b: y[c] = relu(a7[c] @ W1 + b1) * dis[c]  (64-dim bf16) ----------------
__global__ __launch_bounds__(256) void k_lin7b(const unsigned* __restrict__ a7, const float* __restrict__ W,
                                               const float* __restrict__ b, const float* __restrict__ dis,
                                               unsigned short* __restrict__ y, int N) {
  __shared__ float Ws[7 * 64];
  int t = threadIdx.x;
  for (int j = t; j < 7 * 64; j += 256) Ws[j] = W[j];
  __syncthreads();
  int idx = blockIdx.x * 256 + t;
  if (idx < N * 32) {
    int r = idx >> 5, c2 = (idx & 31) * 2;
    uint4 v = *(const uint4*)(a7 + (size_t)r * 4);
    float a[7] = {bflo(v.x), bfhi(v.x), bflo(v.y), bfhi(v.y), bflo(v.z), bfhi(v.z), bflo(v.w)};
    float s0 = b[c2], s1 = b[c2 + 1];
#pragma unroll
    for (int k = 0; k < 7; k++) {
      s0 = fmaf(a[k], Ws[k * 64 + c2], s0);
      s1 = fmaf(a[k], Ws[k * 64 + c2 + 1], s1);
    }
    float d = dis[r];
    float y0 = fmaxf(s0, 0.f) * d;
    float y1 = fmaxf(s1, 0.f) * d;
    *(unsigned*)(y + (size_t)r * 64 + c2) = (unsigned)f2bf(y0) | ((unsigned)f2bf(y1) << 16);
  }
}

// ---------------- agg64 (no bias/relu): gt[c] = dis[c] * (y[c] + sum y[r]) ----------------
__device__ __forceinline__ void agg64_body(int bid, int t,
                                           const unsigned short* __restrict__ ys,
                                           const int* __restrict__ starts, const int* __restrict__ cnt,
                                           const int* __restrict__ srow, const float* __restrict__ dis,
                                           unsigned short* __restrict__ out, int N) {
  constexpr int F = 64, LPN = 32;
  int c = bid * (256 / LPN) + t / LPN;
  if (c >= N) return;
  int fi = (t % LPN) * 2;
  unsigned v = *(const unsigned*)(ys + (size_t)c * F + fi);
  float ax = bflo(v), ay = bfhi(v);
  int s0 = starts[c], n = cnt[c];
  const int* sp = srow + s0;
  int e = 0;
  for (; e + 8 <= n; e += 8) {
    int r0 = sp[e], r1 = sp[e + 1], r2 = sp[e + 2], r3 = sp[e + 3];
    int r4 = sp[e + 4], r5 = sp[e + 5], r6 = sp[e + 6], r7 = sp[e + 7];
    unsigned v0 = *(const unsigned*)(ys + (size_t)r0 * F + fi);
    unsigned v1 = *(const unsigned*)(ys + (size_t)r1 * F + fi);
    unsigned v2 = *(const unsigned*)(ys + (size_t)r2 * F + fi);
    unsigned v3 = *(const unsigned*)(ys + (size_t)r3 * F + fi);
    unsigned v4 = *(const unsigned*)(ys + (size_t)r4 * F + fi);
    unsigned v5 = *(const unsigned*)(ys + (size_t)r5 * F + fi);
    unsigned v6 = *(const unsigned*)(ys + (size_t)r6 * F + fi);
    unsigned v7 = *(const unsigned*)(ys + (size_t)r7 * F + fi);
    ax += bflo(v0) + bflo(v1) + bflo(v2) + bflo(v3) + bflo(v4) + bflo(v5) + bflo(v6) + bflo(v7);
    ay += bfhi(v0) + bfhi(v1) + bfhi(v2) + bfhi(v3) + bfhi(v4) + bfhi(v5) + bfhi(v6) + bfhi(v7);
  }
  for (; e + 4 <= n; e += 4) {
    int r0 = sp[e], r1 = sp[e + 1], r2 = sp[e + 2], r3 = sp[e + 3];
    unsigned v0 = *(const unsigned*)(ys + (size_t)r0 * F + fi);
    unsigned v1 = *(const unsigned*)(ys + (size_t)r1 * F + fi);
    unsigned v2 = *(const unsigned*)(ys + (size_t)r2 * F + fi);
    unsigned v3 = *(const unsigned*)(ys + (size_t)r3 * F + fi);
    ax += bflo(v0) + bflo(v1) + bflo(v2) + bflo(v3);
    ay += bfhi(v0) + bfhi(v1) + bfhi(v2) + bfhi(v3);
  }
  for (; e < n; e++) {
    unsigned vv = *(const unsigned*)(ys + (size_t)sp[e] * F + fi);
    ax += bflo(vv);
    ay += bfhi(vv);
  }
  float d = dis[c];
  *(unsigned*)(out + (size_t)c * F + fi) = (unsigned)f2bf(ax * d) | ((unsigned)f2bf(ay * d) << 16);
}

__global__ __launch_bounds__(256) void k_agg64(const unsigned short* __restrict__ ys,
                                               const int* __restrict__ starts, const int* __restrict__ cnt,
                                               const int* __restrict__ srow, const float* __restrict__ dis,
                                               unsigned short* __restrict__ out, int N) {
  agg64_body(blockIdx.x, threadIdx.x, ys, starts, cnt, srow, dis, out, N);
}

// ---------------- lin64x128: out[c] = relu(gt[c] @ W + b)  (bf16, 32 rows/block) ----------------
__global__ __launch_bounds__(256) void k_lin64x128(const unsigned short* __restrict__ xin, const float* __restrict__ W,
                                                   const float* __restrict__ b, unsigned short* __restrict__ hs, int N) {
  __shared__ float Ws[64 * 128];
  __shared__ float xs[32][64];
  int t = threadIdx.x;
  for (int j = t; j < 64 * 128; j += 256) Ws[j] = W[j];
  int r0 = blockIdx.x * 32;
  for (int j = t; j < 32 * 64; j += 256) {
    int r = j >> 6, k = j & 63;
    int gr = r0 + r;
    xs[r][k] = (gr < N) ? bf2f(xin[(size_t)gr * 64 + k]) : 0.f;
  }
  __syncthreads();
  int c = t & 63;
  int rb = (t >> 6) * 8;
  float a0[8], a1[8];
#pragma unroll
  for (int rr = 0; rr < 8; rr++) { a0[rr] = 0.f; a1[rr] = 0.f; }
  for (int k = 0; k < 64; k++) {
    float w0 = Ws[k * 128 + c];
    float w1 = Ws[k * 128 + c + 64];
#pragma unroll
    for (int rr = 0; rr < 8; rr++) {
      float xv = xs[rb + rr][k];
      a0[rr] = fmaf(xv, w0, a0[rr]);
      a1[rr] = fmaf(xv, w1, a1[rr]);
    }
  }
  float bb0 = b[c], bb1 = b[c + 64];
#pragma unroll
  for (int rr = 0; rr < 8; rr++) {
    int gr = r0 + rb + rr;
    if (gr < N) {
      hs[(size_t)gr * 128 + c] = f2bf(fmaxf(a0[rr] + bb0, 0.f));
      hs[(size_t)gr * 128 + c + 64] = f2bf(fmaxf(a1[rr] + bb1, 0.f));
    }
  }
}

// ---------------- combined B-operand pack: Bq (from xc2b), A1p, Bh ----------------
__global__ void k_pack_all(const unsigned short* __restrict__ xc2b, const float* __restrict__ A1,
                           const float* __restrict__ D1, const float* __restrict__ Wcls,
                           short* __restrict__ Bq, short* __restrict__ A1p, short* __restrict__ Bh) {
  int i = blockIdx.x * 256 + threadIdx.x;
  if (i < 512 * 128) {
    int e = i;
    int k = e >> 7, n = e & 127;
    int frag = (k >> 5) * 8 + (n >> 4);
    int l = (n & 15) | (((k >> 3) & 3) << 4);
    int j = k & 7;
    Bq[(size_t)frag * 512 + l * 8 + j] = (short)xc2b[e];
  } else if (i < 512 * 128 + 256 * 128) {
    int e = i - 512 * 128;
    int k = e >> 7, n = e & 127;
    int frag = (k >> 5) * 8 + (n >> 4);
    int l = (n & 15) | (((k >> 3) & 3) << 4);
    int j = k & 7;
    A1p[(size_t)frag * 512 + l * 8 + j] = (short)f2bf(A1[e]);
  } else if (i < 512 * 128 + 256 * 128 + 128 * 80) {
    int e = i - (512 * 128 + 256 * 128);
    int k = e / 80, n = e % 80;
    float v = 0.f;
    if (n < 64) v = D1[k * 64 + n];
    else if (n < 73) v = Wcls[k * 9 + (n - 64)];
    int frag = (k >> 5) * 5 + (n >> 4);
    int l = (n & 15) | (((k >> 3) & 3) << 4);
    int j = k & 7;
    Bh[(size_t)frag * 512 + l * 8 + j] = (short)f2bf(v);
  }
}

__device__ __forceinline__ short8 zero8() {
  short8 z;
#pragma unroll
  for (int j = 0; j < 8; j++) z[j] = 0;
  return z;
}

__device__ __forceinline__ short8 cvt8(float4 v0, float4 v1) {
  short8 r;
  r[0] = (short)f2bf(v0.x); r[1] = (short)f2bf(v0.y); r[2] = (short)f2bf(v0.z); r[3] = (short)f2bf(v0.w);
  r[4] = (short)f2bf(v1.x); r[5] = (short)f2bf(v1.y); r[6] = (short)f2bf(v1.z); r[7] = (short)f2bf(v1.w);
  return r;
}

__device__ __forceinline__ short8 load_a_f32(const float* p, bool ok) {
  if (!ok) return zero8();
  return cvt8(*(const float4*)p, *(const float4*)(p + 4));
}

// ---------------- gemm_q body (64 rows/block, 16 rows/wave, reg double-buffered) ----------------
__device__ __forceinline__ void gemm_q_body(int bid, int t, const float* __restrict__ Q,
                                            const short* __restrict__ Bp,
                                            unsigned short* __restrict__ outb, int M) {
  int lane = t & 63;
  int wid = t >> 6;
  int m0 = bid * 64 + wid * 16;
  int mrow = lane & 15;
  int kg = lane >> 4;
  f32x4 acc[8];
#pragma unroll
  for (int nf = 0; nf < 8; nf++) acc[nf] = (f32x4){0.f, 0.f, 0.f, 0.f};
  int r0 = m0 + mrow;
  bool ok = r0 < M;
  const float* ap = Q + (size_t)r0 * 512 + kg * 8;
  const short* bl = Bp + lane * 8;
  float4 z4 = {0.f, 0.f, 0.f, 0.f};
  float4 v0 = ok ? *(const float4*)ap : z4;
  float4 v1 = ok ? *(const float4*)(ap + 4) : z4;
  for (int ks = 0; ks < 16; ks++) {
    float4 n0 = z4, n1 = z4;
    if (ks < 15 && ok) {
      n0 = *(const float4*)(ap + (ks + 1) * 32);
      n1 = *(const float4*)(ap + (ks + 1) * 32 + 4);
    }
    short8 a = cvt8(v0, v1);
    const short* bb = bl + (ks << 12);
#pragma unroll
    for (int nf = 0; nf < 8; nf++) {
      short8 b = *(const short8*)(bb + (nf << 9));
      acc[nf] = __builtin_amdgcn_mfma_f32_16x16x32_bf16(a, b, acc[nf], 0, 0, 0);
    }
    v0 = n0;
    v1 = n1;
  }
  int col = lane & 15;
  int g = lane >> 4;
#pragma unroll
  for (int nf = 0; nf < 8; nf++)
#pragma unroll
    for (int r = 0; r < 4; r++) {
      int row = m0 + g * 4 + r;
      if (row < M) outb[(size_t)row * 128 + nf * 16 + col] = f2bf(acc[nf][r]);
    }
}

// ---------------- FAT kernels: gemm_q thirds ride along the sample pipeline ----------------
__global__ __launch_bounds__(256) void k_fatB(const float* __restrict__ Q, const short* __restrict__ Bq,
                                              unsigned short* __restrict__ xcdb, int M,
                                              const int* __restrict__ row, const int* __restrict__ col, int E,
                                              int* __restrict__ cursor, unsigned* __restrict__ edg) {
  int bid = blockIdx.x, t = threadIdx.x;
  if (bid < kG1) gemm_q_body(bid, t, Q, Bq, xcdb, M);
  else passB_body(bid - kG1, t, row, col, E, cursor, edg);
}

__global__ __launch_bounds__(256) void k_fatC(const float* __restrict__ Q, const short* __restrict__ Bq,
                                              unsigned short* __restrict__ xcdb, int M,
                                              const unsigned* __restrict__ edg, const int* __restrict__ bstarts,
                                              int* __restrict__ deg, int* __restrict__ nstarts,
                                              float* __restrict__ dis, int* __restrict__ srow,
                                              const float* __restrict__ xs, unsigned* __restrict__ zs) {
  int bid = blockIdx.x, t = threadIdx.x;
  if (bid < kG2) gemm_q_body(kG1 + bid, t, Q, Bq, xcdb, M);
  else passC_body(bid - kG2, t, edg, bstarts, deg, nstarts, dis, srow, xs, zs, M);
}

__global__ __launch_bounds__(256) void k_fatA(const float* __restrict__ Q, const short* __restrict__ Bq,
                                              unsigned short* __restrict__ xcdb,
                                              const unsigned short* __restrict__ ys,
                                              const int* __restrict__ starts, const int* __restrict__ cnt,
                                              const int* __restrict__ srow, const float* __restrict__ dis,
                                              unsigned short* __restrict__ gt, int M) {
  int bid = blockIdx.x, t = threadIdx.x;
  if (bid < kG3) gemm_q_body(kG1 + kG2 + bid, t, Q, Bq, xcdb, M);
  else agg64_body(bid - kG3, t, ys, starts, cnt, srow, dis, gt, M);
}

// ---------------- GEMM2 (MFMA) + gate epilogue (64 rows/block, 16 rows/wave) ----------------
__global__ __launch_bounds__(256) void k_gemm_fuse_mfma(const unsigned short* __restrict__ Xs,
                                                        const unsigned short* __restrict__ Xc,
                                                        const short* __restrict__ A1p, const float* __restrict__ ab1,
                                                        const float* __restrict__ A2, const float* __restrict__ ab2,
                                                        float* __restrict__ fused, int M) {
  int t = threadIdx.x;
  int lane = t & 63;
  int wid = t >> 6;
  int m0 = blockIdx.x * 64 + wid * 16;
  int mrow = lane & 15;
  int kg = lane >> 4;
  f32x4 acc[8];
#pragma unroll
  for (int nf = 0; nf < 8; nf++) acc[nf] = (f32x4){0.f, 0.f, 0.f, 0.f};
  int r0 = m0 + mrow;
  bool ok = r0 < M;
  const short* bl = A1p + lane * 8;
  short8 a = ok ? *(const short8*)(Xs + (size_t)r0 * 128 + kg * 8) : zero8();
  for (int ks = 0; ks < 8; ks++) {
    short8 an = zero8();
    if (ks < 7 && ok) {
      int ks1 = ks + 1;
      const unsigned short* src = (ks1 < 4) ? Xs : Xc;
      an = *(const short8*)(src + (size_t)r0 * 128 + (ks1 & 3) * 32 + kg * 8);
    }
    const short* bb = bl + (ks << 12);
#pragma unroll
    for (int nf = 0; nf < 8; nf++) {
      short8 b = *(const short8*)(bb + (nf << 9));
      acc[nf] = __builtin_amdgcn_mfma_f32_16x16x32_bf16(a, b, acc[nf], 0, 0, 0);
    }
    a = an;
  }
  int col16 = lane & 15;
  int g = lane >> 4;
  float bias[8], w20[8], w21[8];
#pragma unroll
  for (int nf = 0; nf < 8; nf++) {
    int cc = nf * 16 + col16;
    bias[nf] = ab1[cc];
    w20[nf] = A2[2 * cc];
    w21[nf] = A2[2 * cc + 1];
  }
  float b20 = ab2[0], b21 = ab2[1];
#pragma unroll
  for (int r = 0; r < 4; r++) {
    float u0 = 0.f, u1 = 0.f;
#pragma unroll
    for (int nf = 0; nf < 8; nf++) {
      float tv = fmaxf(acc[nf][r] + bias[nf], 0.f);
      u0 = fmaf(tv, w20[nf], u0);
      u1 = fmaf(tv, w21[nf], u1);
    }
#pragma unroll
    for (int off = 1; off < 16; off <<= 1) {
      u0 += __shfl_xor(u0, off);
      u1 += __shfl_xor(u1, off);
    }
    int row = m0 + g * 4 + r;
    if (row < M) {
      float ua = u0 + b20, ub = u1 + b21;
      float mx = fmaxf(ua, ub);
      float e0 = __expf(ua - mx), e1 = __expf(ub - mx);
      float inv = 1.f / (e0 + e1);
      float w0 = e0 * inv, w1 = e1 * inv;
      int p = col16;
      const unsigned short* xsp = Xs + (size_t)row * 128 + p * 8;
      const unsigned short* xcp = Xc + (size_t)row * 128 + p * 8;
      float* op = fused + (size_t)row * 128 + p * 8;
      float4 o0, o1;
      unsigned sx0 = *(const unsigned*)(xsp + 0), sx1 = *(const unsigned*)(xsp + 2);
      unsigned sx2 = *(const unsigned*)(xsp + 4), sx3 = *(const unsigned*)(xsp + 6);
      unsigned cx0 = *(const unsigned*)(xcp + 0), cx1 = *(const unsigned*)(xcp + 2);
      unsigned cx2 = *(const unsigned*)(xcp + 4), cx3 = *(const unsigned*)(xcp + 6);
      o0.x = w0 * bflo(sx0) + w1 * bflo(cx0);
      o0.y = w0 * bfhi(sx0) + w1 * bfhi(cx0);
      o0.z = w0 * bflo(sx1) + w1 * bflo(cx1);
      o0.w = w0 * bfhi(sx1) + w1 * bfhi(cx1);
      o1.x = w0 * bflo(sx2) + w1 * bflo(cx2);
      o1.y = w0 * bfhi(sx2) + w1 * bfhi(cx2);
      o1.z = w0 * bflo(sx3) + w1 * bflo(cx3);
      o1.w = w0 * bfhi(sx3) + w1 * bfhi(cx3);
      *(float4*)op = o0;
      *(float4*)(op + 4) = o1;
    }
  }
}

// ---------------- heads (MFMA): [class | domain] from fused[M,128] ----------------
__global__ __launch_bounds__(256) void k_final_mfma(const float* __restrict__ fused, const short* __restrict__ Bh,
                                                    const float* __restrict__ bcls, const float* __restrict__ db1,
                                                    const float* __restrict__ D2, const float* __restrict__ db2,
                                                    float* __restrict__ cls_out, float* __restrict__ dom_out, int M) {
  int t = threadIdx.x;
  int lane = t & 63;
  int wid = t >> 6;
  int m0 = blockIdx.x * 128 + wid * 32;
  int mrow = lane & 15;
  int kg = lane >> 4;
  f32x4 acc[2][5];
#pragma unroll
  for (int mi = 0; mi < 2; mi++)
#pragma unroll
    for (int nf = 0; nf < 5; nf++) acc[mi][nf] = (f32x4){0.f, 0.f, 0.f, 0.f};
  int r0 = m0 + mrow, r1 = m0 + 16 + mrow;
  bool ok0 = r0 < M, ok1 = r1 < M;
  const float* a0p = fused + (size_t)r0 * 128 + kg * 8;
  const float* a1p = fused + (size_t)r1 * 128 + kg * 8;
  const short* bl = Bh + lane * 8;
  for (int ks = 0; ks < 4; ks++) {
    short8 a0 = load_a_f32(a0p + ks * 32, ok0);
    short8 a1 = load_a_f32(a1p + ks * 32, ok1);
    const short* bb = bl + ks * 5 * 512;
#pragma unroll
    for (int nf = 0; nf < 5; nf++) {
      short8 b = *(const short8*)(bb + (nf << 9));
      acc[0][nf] = __builtin_amdgcn_mfma_f32_16x16x32_bf16(a0, b, acc[0][nf], 0, 0, 0);
      acc[1][nf] = __builtin_amdgcn_mfma_f32_16x16x32_bf16(a1, b, acc[1][nf], 0, 0, 0);
    }
  }
  int col16 = lane & 15;
  int g = lane >> 4;
  float bh[4], d20[4], d21[4];
#pragma unroll
  for (int nf = 0; nf < 4; nf++) {
    int h = col16 + 16 * nf;
    bh[nf] = db1[h];
    d20[nf] = D2[h * 2];
    d21[nf] = D2[h * 2 + 1];
  }
  float bc = (col16 < 9) ? bcls[col16] : 0.f;
  float b20 = db2[0], b21 = db2[1];
#pragma unroll
  for (int mi = 0; mi < 2; mi++) {
#pragma unroll
    for (int r = 0; r < 4; r++) {
      float p0 = 0.f, p1 = 0.f;
#pragma unroll
      for (int nf = 0; nf < 4; nf++) {
        float hv = fmaxf(acc[mi][nf][r] + bh[nf], 0.f);
        p0 = fmaf(hv, d20[nf], p0);
        p1 = fmaf(hv, d21[nf], p1);
      }
#pragma unroll
      for (int off = 1; off < 16; off <<= 1) {
        p0 += __shfl_xor(p0, off);
        p1 += __shfl_xor(p1, off);
      }
      int row = m0 + mi * 16 + g * 4 + r;
      if (row < M) {
        if (col16 < 9) cls_out[(size_t)row * 9 + col16] = acc[mi][4][r] + bc;
        if (col16 == 0) {
          dom_out[(size_t)row * 2 + 0] = p0 + b20;
          dom_out[(size_t)row * 2 + 1] = p1 + b21;
        }
      }
    }
  }
}

extern "C" void kernel_launch(void* const* d_in, const int* in_sizes, int n_in,
                              void* d_out, int out_size, void* d_ws, size_t ws_size,
                              hipStream_t stream) {
  const float* x_s = (const float*)d_in[0];
  const float* x_c = (const float*)d_in[1];
  const float* Q = (const float*)d_in[2];
  const int* eis = (const int*)d_in[3];
  const int* eic = (const int*)d_in[4];
  const float* W1s = (const float*)d_in[5];
  const float* b1s = (const float*)d_in[6];
  const float* W2s = (const float*)d_in[7];
  const float* b2s = (const float*)d_in[8];
  const float* W1c = (const float*)d_in[9];
  const float* b1c = (const float*)d_in[10];
  const float* W2c = (const float*)d_in[11];
  const float* b2c = (const float*)d_in[12];
  const float* A1 = (const float*)d_in[13];
  const float* ab1 = (const float*)d_in[14];
  const float* A2 = (const float*)d_in[15];
  const float* ab2 = (const float*)d_in[16];
  const float* Wcls = (const float*)d_in[17];
  const float* bcls = (const float*)d_in[18];
  const float* D1 = (const float*)d_in[19];
  const float* db1 = (const float*)d_in[20];
  const float* D2 = (const float*)d_in[21];
  const float* db2 = (const float*)d_in[22];

  float* out_cls = (float*)d_out;
  float* out_dom = out_cls + (size_t)kNS * 9;
  float* out_fus = out_dom + (size_t)kNS * 2;

  char* p = (char*)d_ws;
  auto alloc = [&](size_t bytes) -> void* {
    void* r = (void*)p;
    p += (bytes + 255) & ~(size_t)255;
    return r;
  };
  // sample graph
  int* deg_s = (int*)alloc((size_t)kNS * 4);
  float* dis_s = (float*)alloc((size_t)kNS * 4);
  int* nstarts_s = (int*)alloc((size_t)kNS * 4);
  int* counts_s = (int*)alloc((size_t)kNB8 * 4);
  int* bstarts_s = (int*)alloc((size_t)(kNB8 + 1) * 4);
  int* bcursor_s = (int*)alloc((size_t)kNB8 * 4);
  int* srow_s = (int*)alloc((size_t)kES * 4);
  unsigned* edg_s = (unsigned*)alloc((size_t)kES * 4);
  // cluster graph
  int* deg_c = (int*)alloc((size_t)kNC * 4);
  int* cstarts_c = (int*)alloc((size_t)(kNC + 1) * 4);
  int* cursor_c = (int*)alloc((size_t)kNC * 4);
  float* dis_c = (float*)alloc((size_t)kNC * 4);
  int* srow_c = (int*)alloc((size_t)kEC * 4);
  // sample feature buffers
  unsigned* zs = (unsigned*)alloc((size_t)kNS * 16);
  unsigned* a7s = (unsigned*)alloc((size_t)kNS * 16);
  unsigned short* ys = (unsigned short*)alloc((size_t)kNS * 64 * 2);
  unsigned short* gts = (unsigned short*)alloc((size_t)kNS * 64 * 2);
  unsigned short* xs2b = (unsigned short*)alloc((size_t)kNS * 128 * 2);
  unsigned short* xcdb = (unsigned short*)alloc((size_t)kNS * 128 * 2);
  // cluster feature buffers
  unsigned* zc = (unsigned*)alloc((size_t)kNC * 16);
  unsigned* a7c = (unsigned*)alloc((size_t)kNC * 16);
  unsigned short* yc = (unsigned short*)alloc((size_t)kNC * 64 * 2);
  unsigned short* gtc = (unsigned short*)alloc((size_t)kNC * 64 * 2);
  unsigned short* xc2b = (unsigned short*)alloc((size_t)kNC * 128 * 2);
  // packed B operands
  short* Bq = (short*)alloc((size_t)512 * 128 * 2);
  short* A1p = (short*)alloc((size_t)256 * 128 * 2);
  short* Bh = (short*)alloc((size_t)128 * 80 * 2);
  (void)ws_size; (void)in_sizes; (void)n_in; (void)out_size;

  hipMemsetAsync(counts_s, 0, (size_t)kNB8 * 4, stream);
  hipMemsetAsync(deg_c, 0, (size_t)kNC * 4, stream);

  // sample: bucket histogram + flat scan
  k_passA<<<kNBLK, 256, 0, stream>>>(eis + kES, kES, counts_s);
  k_scan_flat<<<1, 256, 0, stream>>>(counts_s, kNB8, bstarts_s, bcursor_s, nullptr);

  // cluster: CSR + aggregate-then-transform chain + operand pack
  k_hist<<<(kEC + 255) / 256, 256, 0, stream>>>(eic + kEC, kEC, deg_c);
  k_scan_flat<<<1, 256, 0, stream>>>(deg_c, kNC, cstarts_c, cursor_c, dis_c);
  k_scatter<<<(kEC + 255) / 256, 256, 0, stream>>>(eic, eic + kEC, kEC, cursor_c, srow_c);
  k_z<<<(kNC + 255) / 256, 256, 0, stream>>>(x_c, dis_c, zc, kNC);
  k_agg7<<<(kNC + 255) / 256, 256, 0, stream>>>(zc, cstarts_c, deg_c, srow_c, dis_c, a7c, kNC);
  k_lin7b<<<(kNC * 32 + 255) / 256, 256, 0, stream>>>(a7c, W1c, b1c, dis_c, yc, kNC);
  k_agg64<<<(kNC + 7) / 8, 256, 0, stream>>>(yc, cstarts_c, deg_c, srow_c, dis_c, gtc, kNC);
  k_lin64x128<<<(kNC + 31) / 32, 256, 0, stream>>>(gtc, W2c, b2c, xc2b, kNC);
  k_pack_all<<<(512 * 128 + 256 * 128 + 128 * 80 + 255) / 256, 256, 0, stream>>>(xc2b, A1, D1, Wcls, Bq, A1p, Bh);

  // fatB: gemm_q rows [0, 40000) || passB (bucket append)
  k_fatB<<<kG1 + kNBLK, 256, 0, stream>>>(Q, Bq, xcdb, kNS, eis, eis + kES, kES, bcursor_s, edg_s);
  // fatC: gemm_q rows [40000, 70016) || passC (per-node CSR + dis + z)
  k_fatC<<<kG2 + kNB, 256, 0, stream>>>(Q, Bq, xcdb, kNS, edg_s, bstarts_s, deg_s, nstarts_s, dis_s, srow_s, x_s, zs);

  // sample layer-1
  k_agg7<<<(kNS + 255) / 256, 256, 0, stream>>>(zs, nstarts_s, deg_s, srow_s, dis_s, a7s, kNS);
  k_lin7b<<<(kNS * 32 + 255) / 256, 256, 0, stream>>>(a7s, W1s, b1s, dis_s, ys, kNS);

  // fatA: gemm_q rows [70016, 100000) || agg64 (sample layer-2 aggregation)
  k_fatA<<<kG3 + kAgg64Blocks, 256, 0, stream>>>(Q, Bq, xcdb, ys, nstarts_s, deg_s, srow_s, dis_s, gts, kNS);

  k_lin64x128<<<(kNS + 31) / 32, 256, 0, stream>>>(gts, W2s, b2s, xs2b, kNS);

  // fusion gate + heads
  k_gemm_fuse_mfma<<<(kNS + 63) / 64, 256, 0, stream>>>(xs2b, xcdb, A1p, ab1, A2, ab2, out_fus, kNS);
  k_final_mfma<<<(kNS + 127) / 128, 256, 0, stream>>>(out_fus, Bh, bcls, db1, D2, db2, out_cls, out_dom, kNS);
}